// Round 3
// baseline (2126.044 us; speedup 1.0000x reference)
//
#include <hip/hip_runtime.h>
#include <hip/hip_bf16.h>
#include <math.h>

typedef __hip_bfloat16 bf16;

__device__ __forceinline__ float b2f(bf16 v){ return __bfloat162float(v); }
__device__ __forceinline__ bf16  f2b(float v){ return __float2bfloat16(v); }

// ---------------------------------------------------------------------------
// k0: per-batch b — pe, pe@W_PE, x, cand, s=softmax(x@W_assign), x_parent,
//     user_F, per-block partials for loss_reg(data) and loss_entropy.
// ---------------------------------------------------------------------------
__global__ __launch_bounds__(256) void k0(
    const float* __restrict__ emb, const float* __restrict__ Wpe, const float* __restrict__ Wassign,
    const int* __restrict__ history, const int* __restrict__ timestp,
    const int* __restrict__ pos_id, const int* __restrict__ neg_id, const int* __restrict__ stp,
    bf16* __restrict__ x_out, float* __restrict__ cand_out, float* __restrict__ xp_out,
    float* __restrict__ userF_out, float* __restrict__ reg_part, float* __restrict__ ent_part)
{
  const int b = blockIdx.x, tid = threadIdx.x;
  __shared__ float pes[51*64];
  __shared__ float wpe[64*64];
  __shared__ float pew[51*64];
  __shared__ float xs[50*64];
  __shared__ float wa[64*10];
  __shared__ float sb[50*10];
  __shared__ float xpl[10*64];
  __shared__ float red[256];
  __shared__ int hist[50];
  __shared__ int tvals[51];
  __shared__ int ids[5];

  if (tid < 50) hist[tid] = history[b*50+tid];
  if (tid >= 64 && tid < 114) tvals[tid-64] = timestp[b*50+(tid-64)];
  if (tid == 128) tvals[50] = stp[b];
  if (tid == 129) ids[0] = pos_id[b];
  if (tid >= 130 && tid < 134) ids[tid-129] = neg_id[b*4+(tid-130)];
  for (int i=tid;i<64*64;i+=256) wpe[i] = Wpe[i];
  for (int i=tid;i<640;i+=256)   wa[i]  = Wassign[i];
  __syncthreads();

  // pe rows for 50 timestp + 1 stp
  const float c0 = -logf(10000.f)/32.f;
  for (int i=tid;i<51*64;i+=256){
    int n=i>>6, d=i&63;
    float t=(float)tvals[n];
    float ang = t*expf((float)(d>>1)*c0);
    pes[i] = (d&1) ? cosf(ang) : sinf(ang);
  }
  __syncthreads();
  // pew = pe @ W_PE
  for (int i=tid;i<51*64;i+=256){
    int n=i>>6, d=i&63;
    float a=0.f; const float* pr=&pes[n<<6];
    #pragma unroll 8
    for(int j=0;j<64;j++) a += pr[j]*wpe[(j<<6)+d];
    pew[i]=a;
  }
  __syncthreads();
  // x, cand, reg partial
  float regp=0.f;
  for (int i=tid;i<3200;i+=256){
    int n=i>>6;
    float ev=emb[(size_t)hist[n]*64 + (i&63)];
    regp += ev*ev;
    float v = (hist[n]>0) ? (ev+pew[i]) : 0.f;
    xs[i]=v;
    x_out[(size_t)b*3200+i]=f2b(v);
  }
  for (int i=tid;i<320;i+=256){
    int c=i>>6, d=i&63;
    float ev=emb[(size_t)ids[c]*64+d];
    regp += ev*ev;
    cand_out[(size_t)b*320+i]=ev+pew[50*64+d];
  }
  __syncthreads();
  // logits = x @ W_assign
  for (int i=tid;i<500;i+=256){
    int n=i/10, k=i-n*10;
    float a=0.f;
    for(int d=0;d<64;d++) a += xs[(n<<6)+d]*wa[d*10+k];
    sb[i]=a;
  }
  __syncthreads();
  // softmax over k=10 + entropy partial
  float entp=0.f;
  if (tid<50){
    float mx=-1e30f;
    for(int k=0;k<10;k++) mx=fmaxf(mx, sb[tid*10+k]);
    float e[10], sm=0.f;
    for(int k=0;k<10;k++){ e[k]=expf(sb[tid*10+k]-mx); sm+=e[k]; }
    float inv=1.f/sm;
    for(int k=0;k<10;k++){ float sv=e[k]*inv; sb[tid*10+k]=sv; entp += sv*logf(sv); }
  }
  __syncthreads();
  // x_parent = s^T x
  for (int i=tid;i<640;i+=256){
    int k=i>>6, d=i&63;
    float a=0.f;
    for(int n=0;n<50;n++) a += sb[n*10+k]*xs[(n<<6)+d];
    xpl[i]=a;
    xp_out[(size_t)b*640+i]=a;
  }
  __syncthreads();
  if (tid<64){
    float a=0.f;
    for(int k=0;k<10;k++) a += xpl[(k<<6)+tid];
    userF_out[(size_t)b*64+tid]=a*0.1f;
  }
  // per-block reductions -> plain stores (no atomics)
  red[tid]=regp; __syncthreads();
  for(int s=128;s>0;s>>=1){ if(tid<s) red[tid]+=red[tid+s]; __syncthreads(); }
  if(tid==0) reg_part[b]=red[0];
  __syncthreads();
  red[tid]=entp; __syncthreads();
  for(int s=128;s>0;s>>=1){ if(tid<s) red[tid]+=red[tid+s]; __syncthreads(); }
  if(tid==0) ent_part[b]=red[0];
}

// ---------------------------------------------------------------------------
// k12: per-batch b — GAT (x_new_I, user_I) fused with aggregates, W_pred,
//      scores/softplus loss, top-k, ssl_topk terms. Per-block partials out.
// ---------------------------------------------------------------------------
__global__ __launch_bounds__(256) void k12(
    const bf16* __restrict__ x_in, const float* __restrict__ Wgat,
    const float* __restrict__ a_src, const float* __restrict__ a_dst,
    const float* __restrict__ Wo, const float* __restrict__ adj,
    const float* __restrict__ cand_in, const float* __restrict__ xp_in,
    const float* __restrict__ userF_in, const float* __restrict__ Wpred,
    float* __restrict__ loss_part, float* __restrict__ con_part)
{
  const int b=blockIdx.x, tid=threadIdx.x;
  const int wid=tid>>6, lane=tid&63;
  __shared__ bf16 xsb[3200];        // x[b] bf16
  __shared__ bf16 wg[4096];         // W_gat[h] tile
  __shared__ bf16 Whs[4*3200];      // Wh
  __shared__ float es_[200], ed_[200];
  __shared__ float asv[256], adv[256];
  __shared__ float Pb[4][64];
  __shared__ float orow[256];
  __shared__ float part[4][64];
  __shared__ float uacc[64];
  __shared__ bf16 xnl[3200];        // x_new_I
  __shared__ float cnd[320];
  __shared__ float xpl[640];
  __shared__ float uFvec[64];
  __shared__ float lF[50];
  __shared__ float lI[250];
  __shared__ float uFb[320], uIb[320], ub[320];
  __shared__ float sc[5], sIv[5], sFv[5], cn[5], un[2];

  for(int i=tid;i<3200;i+=256) xsb[i]=x_in[(size_t)b*3200+i];
  asv[tid]=a_src[tid]; adv[tid]=a_dst[tid];
  for(int i=tid;i<320;i+=256) cnd[i]=cand_in[(size_t)b*320+i];
  for(int i=tid;i<640;i+=256) xpl[i]=xp_in[(size_t)b*640+i];
  if(tid<64){ uFvec[tid]=userF_in[(size_t)b*64+tid]; uacc[tid]=0.f; }

  // Wh[h] = x @ W_gat[h]
  for(int h=0;h<4;h++){
    __syncthreads();
    for(int i=tid;i<4096;i+=256) wg[i]=f2b(Wgat[h*4096+i]);
    __syncthreads();
    for(int i=tid;i<3200;i+=256){
      int n=i>>6, k=i&63;
      float a=0.f;
      #pragma unroll 8
      for(int d=0;d<64;d++) a += b2f(xsb[(n<<6)+d])*b2f(wg[(d<<6)+k]);
      Whs[h*3200+i]=f2b(a);
    }
  }
  __syncthreads();
  // es/ed
  for(int i=tid;i<400;i+=256){
    int r=(i>=200)?1:0; int j=i-200*r; int h=j/50, n=j-h*50;
    const float* a = r? &adv[h<<6] : &asv[h<<6];
    float s=0.f;
    for(int k=0;k<64;k++) s += b2f(Whs[h*3200+(n<<6)+k])*a[k];
    if(r) ed_[j]=s; else es_[j]=s;
  }
  __syncthreads();
  // attention rows; wave wid = head
  for(int n=0;n<50;n++){
    float e=-1e9f;
    if(lane<50){
      float z=es_[wid*50+n]+ed_[wid*50+lane];
      float lr=(z>0.f)? z : 0.2f*z;
      e = (adj[(size_t)b*2500+n*50+lane]>0.f) ? lr : -1e9f;
    }
    float mx=e;
    for(int m=32;m>0;m>>=1) mx=fmaxf(mx,__shfl_xor(mx,m,64));
    float p=(lane<50)? expf(e-mx):0.f;
    float sm=p;
    for(int m=32;m>0;m>>=1) sm += __shfl_xor(sm,m,64);
    Pb[wid][lane]=p/sm;
    __syncthreads();
    float a=0.f;
    for(int m2=0;m2<50;m2++) a += Pb[wid][m2]*b2f(Whs[wid*3200+(m2<<6)+lane]);
    orow[tid]=a;   // out[h=wid, n, k=lane]
    __syncthreads();
    float pt=0.f;
    #pragma unroll 8
    for(int j=0;j<64;j++) pt += orow[(wid<<6)+j]*Wo[(size_t)((wid<<6)+j)*64+lane];
    part[wid][lane]=pt;
    __syncthreads();
    if(tid<64){
      float v=part[0][tid]+part[1][tid]+part[2][tid]+part[3][tid];
      v = (v>0.f)? v : expm1f(v);   // elu
      xnl[(n<<6)+tid]=f2b(v);
      uacc[tid]+=v;
    }
    __syncthreads();
  }
  if(tid<64) uacc[tid]*=0.02f;   // user_I = mean over 50
  __syncthreads();

  // aggregate logits
  if(tid<50){
    int c=tid/10, k=tid-(tid/10)*10;
    float a=0.f;
    for(int d=0;d<64;d++) a += xpl[(k<<6)+d]*cnd[(c<<6)+d];
    lF[tid]=a;
  }
  for(int i=tid;i<250;i+=256){
    int c=i/50, n2=i-c*50;
    float a=0.f;
    for(int d=0;d<64;d++) a += b2f(xnl[(n2<<6)+d])*cnd[(c<<6)+d];
    lI[i]=a;
  }
  __syncthreads();
  if(tid<5){
    float mx=-1e30f;
    for(int k=0;k<10;k++) mx=fmaxf(mx,lF[tid*10+k]);
    float s=0.f;
    for(int k=0;k<10;k++){ float e2=expf(lF[tid*10+k]-mx); lF[tid*10+k]=e2; s+=e2; }
    float inv=1.f/s;
    for(int k=0;k<10;k++) lF[tid*10+k]*=inv;
    mx=-1e30f;
    for(int n2=0;n2<50;n2++) mx=fmaxf(mx,lI[tid*50+n2]);
    s=0.f;
    for(int n2=0;n2<50;n2++){ float e2=expf(lI[tid*50+n2]-mx); lI[tid*50+n2]=e2; s+=e2; }
    inv=1.f/s;
    for(int n2=0;n2<50;n2++) lI[tid*50+n2]*=inv;
  }
  __syncthreads();
  for(int i=tid;i<320;i+=256){
    int c=i>>6, d=i&63;
    float a=0.f;
    for(int k=0;k<10;k++) a += lF[c*10+k]*xpl[(k<<6)+d];
    uFb[i]=a;
    float a2=0.f;
    for(int n2=0;n2<50;n2++) a2 += lI[c*50+n2]*b2f(xnl[(n2<<6)+d]);
    uIb[i]=a2;
  }
  __syncthreads();
  // u = [u_F, u_I] @ W_pred
  for(int i=tid;i<320;i+=256){
    int c=i>>6, d=i&63;
    float a=0.f;
    #pragma unroll 8
    for(int j=0;j<64;j++) a += uFb[(c<<6)+j]*Wpred[(j<<6)+d];
    #pragma unroll 8
    for(int j=0;j<64;j++) a += uIb[(c<<6)+j]*Wpred[((64+j)<<6)+d];
    ub[i]=a;
  }
  __syncthreads();
  if(tid<5){
    float a=0.f; for(int d=0;d<64;d++) a += ub[(tid<<6)+d]*cnd[(tid<<6)+d];
    sc[tid]=a;
  } else if(tid>=8&&tid<13){
    int c=tid-8; float a=0.f; for(int d=0;d<64;d++) a += cnd[(c<<6)+d]*uacc[d];
    sIv[c]=a;
  } else if(tid>=16&&tid<21){
    int c=tid-16; float a=0.f; for(int d=0;d<64;d++) a += cnd[(c<<6)+d]*uFvec[d];
    sFv[c]=a;
  } else if(tid>=24&&tid<29){
    int c=tid-24; float a=0.f; for(int d=0;d<64;d++){ float v=cnd[(c<<6)+d]; a+=v*v; }
    cn[c]=sqrtf(a);
  } else if(tid==32){
    float a=0.f; for(int d=0;d<64;d++) a+=uacc[d]*uacc[d]; un[0]=sqrtf(a);
  } else if(tid==33){
    float a=0.f; for(int d=0;d<64;d++) a+=uFvec[d]*uFvec[d]; un[1]=sqrtf(a);
  }
  __syncthreads();
  if(tid==0){
    float lp=0.f;
    for(int c=1;c<5;c++){
      float z=sc[c]-sc[0];
      lp += fmaxf(z,0.f)+log1pf(expf(-fabsf(z)));   // softplus(neg-pos)
    }
    // stable descending top-k (ties -> lower index first), like jax.lax.top_k
    int indF[5], indI[5];
    { bool used[5]={0,0,0,0,0};
      for(int p=0;p<5;p++){ int best=0; float bv=-3e38f;
        for(int c=0;c<5;c++) if(!used[c]&&sFv[c]>bv){bv=sFv[c];best=c;}
        used[best]=true; indF[p]=best; } }
    { bool used[5]={0,0,0,0,0};
      for(int p=0;p<5;p++){ int best=0; float bv=-3e38f;
        for(int c=0;c<5;c++) if(!used[c]&&sIv[c]>bv){bv=sIv[c];best=c;}
        used[best]=true; indI[p]=best; } }
    float t1,t2;
    { // ssl_topk(user_I, cand[indF[0:2]], cand[indF[2:4]])
      float inv=2.f/un[0];
      float ps=expf(sIv[indF[0]]/cn[indF[0]]*inv)+expf(sIv[indF[1]]/cn[indF[1]]*inv);
      float ns=expf(sIv[indF[2]]/cn[indF[2]]*inv)+expf(sIv[indF[3]]/cn[indF[3]]*inv);
      t1=log1pf(ns/ps);
    }
    { // ssl_topk(user_F, cand[indI[0:2]], cand[indI[2:4]])
      float inv=2.f/un[1];
      float ps=expf(sFv[indI[0]]/cn[indI[0]]*inv)+expf(sFv[indI[1]]/cn[indI[1]]*inv);
      float ns=expf(sFv[indI[2]]/cn[indI[2]]*inv)+expf(sFv[indI[3]]/cn[indI[3]]*inv);
      t2=log1pf(ns/ps);
    }
    loss_part[b]=lp;
    con_part[b]=t1+t2;
  }
}

// ---------------------------------------------------------------------------
// k3: reduce 4096-element partials + weight reg terms -> 4 float32 outputs
// ---------------------------------------------------------------------------
__global__ __launch_bounds__(256) void k3(
    const float* __restrict__ Wpred, const float* __restrict__ Wpe,
    const float* __restrict__ reg_part, const float* __restrict__ ent_part,
    const float* __restrict__ loss_part, const float* __restrict__ con_part,
    float* __restrict__ out)
{
  __shared__ float red[256];
  const int tid=threadIdx.x;

  float sw=0.f;
  for (int i=tid;i<128*64;i+=256){ float v=Wpred[i]; sw+=v*v; }
  for (int i=tid;i<64*64;i+=256){ float v=Wpe[i]; sw+=v*v; }
  float sreg=0.f, sent=0.f, sloss=0.f, scon=0.f;
  for (int i=tid;i<4096;i+=256){
    sreg+=reg_part[i]; sent+=ent_part[i]; sloss+=loss_part[i]; scon+=con_part[i];
  }

  float vals[5]={sloss,sreg,sent,scon,sw};
  float tot[5];
  for(int t=0;t<5;t++){
    red[tid]=vals[t]; __syncthreads();
    for(int s=128;s>0;s>>=1){ if(tid<s) red[tid]+=red[tid+s]; __syncthreads(); }
    tot[t]=red[0]; __syncthreads();
  }
  if(tid==0){
    out[0]=tot[0]/(4096.f*4.f);          // loss
    out[1]=tot[1]/4096.f + tot[4];       // loss_reg
    out[2]=-tot[2]/(50.f*4096.f);        // loss_entropy
    out[3]=tot[3]/4096.f;                // loss_con
  }
}

extern "C" void kernel_launch(void* const* d_in, const int* in_sizes, int n_in,
                              void* d_out, int out_size, void* d_ws, size_t ws_size,
                              hipStream_t stream)
{
  const float* emb     =(const float*)d_in[0];
  const float* Wpe     =(const float*)d_in[1];
  const float* Wpred   =(const float*)d_in[2];
  const float* Wgat    =(const float*)d_in[3];
  const float* a_src   =(const float*)d_in[4];
  const float* a_dst   =(const float*)d_in[5];
  const float* Wo      =(const float*)d_in[6];
  const float* Wassign =(const float*)d_in[7];
  const float* adj     =(const float*)d_in[8];
  const int* history  =(const int*)d_in[9];
  const int* timestp  =(const int*)d_in[10];
  const int* pos_id   =(const int*)d_in[11];
  const int* neg_id   =(const int*)d_in[12];
  const int* stp      =(const int*)d_in[13];
  float* out=(float*)d_out;

  char* ws=(char*)d_ws;
  size_t off=0;
  float* reg_part =(float*)(ws+off); off+=4096*4;
  float* ent_part =(float*)(ws+off); off+=4096*4;
  float* loss_part=(float*)(ws+off); off+=4096*4;
  float* con_part =(float*)(ws+off); off+=4096*4;
  bf16* x    =(bf16*)(ws+off);  off+=(size_t)4096*3200*2;
  float* cand=(float*)(ws+off); off+=(size_t)4096*320*4;
  float* xp  =(float*)(ws+off); off+=(size_t)4096*640*4;
  float* uF  =(float*)(ws+off); off+=(size_t)4096*64*4;

  k0<<<4096,256,0,stream>>>(emb,Wpe,Wassign,history,timestp,pos_id,neg_id,stp,x,cand,xp,uF,reg_part,ent_part);
  k12<<<4096,256,0,stream>>>(x,Wgat,a_src,a_dst,Wo,adj,cand,xp,uF,Wpred,loss_part,con_part);
  k3<<<1,256,0,stream>>>(Wpred,Wpe,reg_part,ent_part,loss_part,con_part,out);
}

// Round 4
// 1465.933 us; speedup vs baseline: 1.4503x; 1.4503x over previous
//
#include <hip/hip_runtime.h>
#include <hip/hip_bf16.h>
#include <math.h>

typedef __hip_bfloat16 bf16;

__device__ __forceinline__ float b2f(bf16 v){ return __bfloat162float(v); }
__device__ __forceinline__ bf16  f2b(float v){ return __float2bfloat16(v); }
__device__ __forceinline__ float rl(float v, int l){
  return __int_as_float(__builtin_amdgcn_readlane(__float_as_int(v), l));
}

// ---------------------------------------------------------------------------
// k0: per-batch b — pe, pe@W_PE, x, cand, s=softmax(x@W_assign), x_parent,
//     user_F, per-block partials for loss_reg(data) and loss_entropy.
// ---------------------------------------------------------------------------
__global__ __launch_bounds__(256) void k0(
    const float* __restrict__ emb, const float* __restrict__ Wpe, const float* __restrict__ Wassign,
    const int* __restrict__ history, const int* __restrict__ timestp,
    const int* __restrict__ pos_id, const int* __restrict__ neg_id, const int* __restrict__ stp,
    bf16* __restrict__ x_out, float* __restrict__ cand_out, float* __restrict__ xp_out,
    float* __restrict__ userF_out, float* __restrict__ reg_part, float* __restrict__ ent_part)
{
  const int b = blockIdx.x, tid = threadIdx.x;
  __shared__ float pes[51*64];
  __shared__ float wpe[64*64];
  __shared__ float pew[51*64];
  __shared__ float xs[50*64];
  __shared__ float wa[64*10];
  __shared__ float sb[50*10];
  __shared__ float xpl[10*64];
  __shared__ float red[256];
  __shared__ int hist[50];
  __shared__ int tvals[51];
  __shared__ int ids[5];

  if (tid < 50) hist[tid] = history[b*50+tid];
  if (tid >= 64 && tid < 114) tvals[tid-64] = timestp[b*50+(tid-64)];
  if (tid == 128) tvals[50] = stp[b];
  if (tid == 129) ids[0] = pos_id[b];
  if (tid >= 130 && tid < 134) ids[tid-129] = neg_id[b*4+(tid-130)];
  for (int i=tid;i<64*64;i+=256) wpe[i] = Wpe[i];
  for (int i=tid;i<640;i+=256)   wa[i]  = Wassign[i];
  __syncthreads();

  const float c0 = -logf(10000.f)/32.f;
  for (int i=tid;i<51*64;i+=256){
    int n=i>>6, d=i&63;
    float t=(float)tvals[n];
    float ang = t*expf((float)(d>>1)*c0);
    pes[i] = (d&1) ? cosf(ang) : sinf(ang);
  }
  __syncthreads();
  for (int i=tid;i<51*64;i+=256){
    int n=i>>6, d=i&63;
    float a=0.f; const float* pr=&pes[n<<6];
    #pragma unroll 8
    for(int j=0;j<64;j++) a += pr[j]*wpe[(j<<6)+d];
    pew[i]=a;
  }
  __syncthreads();
  float regp=0.f;
  for (int i=tid;i<3200;i+=256){
    int n=i>>6;
    float ev=emb[(size_t)hist[n]*64 + (i&63)];
    regp += ev*ev;
    float v = (hist[n]>0) ? (ev+pew[i]) : 0.f;
    xs[i]=v;
    x_out[(size_t)b*3200+i]=f2b(v);
  }
  for (int i=tid;i<320;i+=256){
    int c=i>>6, d=i&63;
    float ev=emb[(size_t)ids[c]*64+d];
    regp += ev*ev;
    cand_out[(size_t)b*320+i]=ev+pew[50*64+d];
  }
  __syncthreads();
  for (int i=tid;i<500;i+=256){
    int n=i/10, k=i-n*10;
    float a=0.f;
    for(int d=0;d<64;d++) a += xs[(n<<6)+d]*wa[d*10+k];
    sb[i]=a;
  }
  __syncthreads();
  float entp=0.f;
  if (tid<50){
    float mx=-1e30f;
    for(int k=0;k<10;k++) mx=fmaxf(mx, sb[tid*10+k]);
    float e[10], sm=0.f;
    for(int k=0;k<10;k++){ e[k]=expf(sb[tid*10+k]-mx); sm+=e[k]; }
    float inv=1.f/sm;
    for(int k=0;k<10;k++){ float sv=e[k]*inv; sb[tid*10+k]=sv; entp += sv*logf(sv); }
  }
  __syncthreads();
  for (int i=tid;i<640;i+=256){
    int k=i>>6, d=i&63;
    float a=0.f;
    for(int n=0;n<50;n++) a += sb[n*10+k]*xs[(n<<6)+d];
    xpl[i]=a;
    xp_out[(size_t)b*640+i]=a;
  }
  __syncthreads();
  if (tid<64){
    float a=0.f;
    for(int k=0;k<10;k++) a += xpl[(k<<6)+tid];
    userF_out[(size_t)b*64+tid]=a*0.1f;
  }
  red[tid]=regp; __syncthreads();
  for(int s=128;s>0;s>>=1){ if(tid<s) red[tid]+=red[tid+s]; __syncthreads(); }
  if(tid==0) reg_part[b]=red[0];
  __syncthreads();
  red[tid]=entp; __syncthreads();
  for(int s=128;s>0;s>>=1){ if(tid<s) red[tid]+=red[tid+s]; __syncthreads(); }
  if(tid==0) ent_part[b]=red[0];
}

// ---------------------------------------------------------------------------
// k12: register-resident GAT. wave = head; lane k holds Wh[n][k] (f32) for all
// 50 n. Cross-lane access via v_readlane (no shared-LDS-pipe contention).
// Single LDS round-trip for the cross-head concat (out @ W_o).
// ---------------------------------------------------------------------------
__global__ __launch_bounds__(256) void k12(
    const bf16* __restrict__ x_in, const float* __restrict__ Wgat,
    const float* __restrict__ a_src, const float* __restrict__ a_dst,
    const float* __restrict__ Wo, const float* __restrict__ adj,
    const float* __restrict__ cand_in, const float* __restrict__ xp_in,
    const float* __restrict__ userF_in, const float* __restrict__ Wpred,
    float* __restrict__ loss_part, float* __restrict__ con_part)
{
  const int b=blockIdx.x, tid=threadIdx.x;
  const int wid=tid>>6, lane=tid&63;
  const int h=wid;

  __shared__ __align__(16) char smem_out[50*256*2];  // outh bf16[50][256] -> xnl f32[50][64]
  bf16*  outh=(bf16*)smem_out;
  float* xnl =(float*)smem_out;
  __shared__ float es_[200];
  __shared__ float cnd[320];
  __shared__ float xpl[640];
  __shared__ float uFvec[64];
  __shared__ float uacc[64];
  __shared__ float part[4][64];
  __shared__ float lF[50];
  __shared__ float lI[250];
  __shared__ float uFb[320], uIb[320], ub[320];
  __shared__ float sc[5], sIv[5], sFv[5], cn[5], un[2];

  // setup small loads (visibility covered by barrier 3)
  for(int i=tid;i<320;i+=256) cnd[i]=cand_in[(size_t)b*320+i];
  for(int i=tid;i<640;i+=256) xpl[i]=xp_in[(size_t)b*640+i];
  if(tid<64) uFvec[tid]=userF_in[(size_t)b*64+tid];

  // ---- stage 1: Wh[h][n][lane] into whv[50] (f32 accumulate)
  float whv[50];
  {
    const float* wgh = Wgat + h*4096;
    #pragma unroll
    for(int p=0;p<2;p++){
      float xv[25], acc[25];
      #pragma unroll
      for(int r=0;r<25;r++){
        xv[r]=b2f(x_in[(size_t)b*3200 + (p*25+r)*64 + lane]);
        acc[r]=0.f;
      }
      for(int dc=0;dc<4;dc++){
        float wv[16];
        #pragma unroll
        for(int dd=0;dd<16;dd++) wv[dd]=wgh[(dc*16+dd)*64 + lane];
        #pragma unroll
        for(int r=0;r<25;r++){
          #pragma unroll
          for(int dd=0;dd<16;dd++)
            acc[r] += rl(xv[r], dc*16+dd)*wv[dd];
        }
      }
      #pragma unroll
      for(int r=0;r<25;r++) whv[p*25+r]=acc[r];
    }
  }

  // ---- stage 2: es[n], ed[lane] via shuffle butterflies (same wave only)
  float asr=a_src[h*64+lane], adr=a_dst[h*64+lane];
  float ed_l=0.f;
  #pragma unroll
  for(int n=0;n<50;n++){
    float t1=whv[n]*asr, t2=whv[n]*adr;
    #pragma unroll
    for(int m=32;m>0;m>>=1){ t1+=__shfl_xor(t1,m,64); t2+=__shfl_xor(t2,m,64); }
    if(lane==0) es_[h*50+n]=t1;
    if(lane==n) ed_l=t2;
  }

  // ---- stage 3: masked leaky-relu softmax rows -> pv[n]=P[h][n][lane]
  float pv[50];
  const float* adjb = adj + (size_t)b*2500;
  #pragma unroll
  for(int n=0;n<50;n++){
    float av = (lane<50)? adjb[n*50+lane] : 0.f;
    float z = es_[h*50+n] + ed_l;
    float lr = (z>0.f)? z : 0.2f*z;
    float e = (lane<50 && av>0.f)? lr : -1e9f;
    float mx=e;
    #pragma unroll
    for(int m=32;m>0;m>>=1) mx=fmaxf(mx,__shfl_xor(mx,m,64));
    float p=(lane<50)? expf(e-mx):0.f;
    float sm=p;
    #pragma unroll
    for(int m=32;m>0;m>>=1) sm+=__shfl_xor(sm,m,64);
    pv[n]=p/sm;
  }

  // ---- stage 4: out[h][n][lane] = sum_m P[n][m]*Wh[m][lane]  (readlane only)
  #pragma unroll
  for(int n=0;n<50;n++){
    float t=0.f;
    #pragma unroll
    for(int m=0;m<50;m++) t += rl(pv[n],m)*whv[m];
    outh[n*256 + h*64 + lane] = f2b(t);
  }
  __syncthreads();                              // barrier 1: outh complete

  // ---- stage 5: x_new = elu(out @ Wo); rows n = wid+4t
  float ov[4][13];
  #pragma unroll
  for(int c=0;c<4;c++){
    #pragma unroll
    for(int t=0;t<13;t++){
      int n = wid + 4*t;
      ov[c][t] = (n<50)? b2f(outh[n*256 + c*64 + lane]) : 0.f;
    }
  }
  __syncthreads();                              // barrier 2: outh free -> xnl overlay

  float acc5[13];
  #pragma unroll
  for(int t=0;t<13;t++) acc5[t]=0.f;
  #pragma unroll
  for(int c=0;c<4;c++){
    for(int cc=0;cc<4;cc++){
      float wo16[16];
      #pragma unroll
      for(int dd=0;dd<16;dd++) wo16[dd]=Wo[(size_t)(c*64+cc*16+dd)*64 + lane];
      #pragma unroll
      for(int t=0;t<13;t++){
        #pragma unroll
        for(int dd=0;dd<16;dd++)
          acc5[t] += rl(ov[c][t], cc*16+dd)*wo16[dd];
      }
    }
  }
  float up=0.f;
  #pragma unroll
  for(int t=0;t<13;t++){
    int n = wid + 4*t;
    if(n<50){
      float v=acc5[t];
      v = (v>0.f)? v : expm1f(v);               // elu
      xnl[n*64+lane]=v;
      up += v;
    }
  }
  part[wid][lane]=up;
  __syncthreads();                              // barrier 3
  if(tid<64) uacc[tid]=(part[0][tid]+part[1][tid]+part[2][tid]+part[3][tid])*0.02f;
  __syncthreads();                              // barrier 4

  // ---- stage 6: aggregates + losses (small)
  if(tid<50){
    int c=tid/10, k=tid-(tid/10)*10;
    float a=0.f;
    for(int d=0;d<64;d++) a += xpl[(k<<6)+d]*cnd[(c<<6)+d];
    lF[tid]=a;
  }
  for(int i=tid;i<250;i+=256){
    int c=i/50, n2=i-c*50;
    float a=0.f;
    for(int d=0;d<64;d++) a += xnl[(n2<<6)+d]*cnd[(c<<6)+d];
    lI[i]=a;
  }
  __syncthreads();
  if(tid<5){
    float mx=-1e30f;
    for(int k=0;k<10;k++) mx=fmaxf(mx,lF[tid*10+k]);
    float s=0.f;
    for(int k=0;k<10;k++){ float e2=expf(lF[tid*10+k]-mx); lF[tid*10+k]=e2; s+=e2; }
    float inv=1.f/s;
    for(int k=0;k<10;k++) lF[tid*10+k]*=inv;
    mx=-1e30f;
    for(int n2=0;n2<50;n2++) mx=fmaxf(mx,lI[tid*50+n2]);
    s=0.f;
    for(int n2=0;n2<50;n2++){ float e2=expf(lI[tid*50+n2]-mx); lI[tid*50+n2]=e2; s+=e2; }
    inv=1.f/s;
    for(int n2=0;n2<50;n2++) lI[tid*50+n2]*=inv;
  }
  __syncthreads();
  for(int i=tid;i<320;i+=256){
    int c=i>>6, d=i&63;
    float a=0.f;
    for(int k=0;k<10;k++) a += lF[c*10+k]*xpl[(k<<6)+d];
    uFb[i]=a;
    float a2=0.f;
    for(int n2=0;n2<50;n2++) a2 += lI[c*50+n2]*xnl[(n2<<6)+d];
    uIb[i]=a2;
  }
  __syncthreads();
  for(int i=tid;i<320;i+=256){
    int c=i>>6, d=i&63;
    float a=0.f;
    #pragma unroll 8
    for(int j=0;j<64;j++) a += uFb[(c<<6)+j]*Wpred[(j<<6)+d];
    #pragma unroll 8
    for(int j=0;j<64;j++) a += uIb[(c<<6)+j]*Wpred[((64+j)<<6)+d];
    ub[i]=a;
  }
  __syncthreads();
  if(tid<5){
    float a=0.f; for(int d=0;d<64;d++) a += ub[(tid<<6)+d]*cnd[(tid<<6)+d];
    sc[tid]=a;
  } else if(tid>=8&&tid<13){
    int c=tid-8; float a=0.f; for(int d=0;d<64;d++) a += cnd[(c<<6)+d]*uacc[d];
    sIv[c]=a;
  } else if(tid>=16&&tid<21){
    int c=tid-16; float a=0.f; for(int d=0;d<64;d++) a += cnd[(c<<6)+d]*uFvec[d];
    sFv[c]=a;
  } else if(tid>=24&&tid<29){
    int c=tid-24; float a=0.f; for(int d=0;d<64;d++){ float v=cnd[(c<<6)+d]; a+=v*v; }
    cn[c]=sqrtf(a);
  } else if(tid==32){
    float a=0.f; for(int d=0;d<64;d++) a+=uacc[d]*uacc[d]; un[0]=sqrtf(a);
  } else if(tid==33){
    float a=0.f; for(int d=0;d<64;d++) a+=uFvec[d]*uFvec[d]; un[1]=sqrtf(a);
  }
  __syncthreads();
  if(tid==0){
    float lp=0.f;
    for(int c=1;c<5;c++){
      float z=sc[c]-sc[0];
      lp += fmaxf(z,0.f)+log1pf(expf(-fabsf(z)));
    }
    int indF[5], indI[5];
    { bool used[5]={0,0,0,0,0};
      for(int p=0;p<5;p++){ int best=0; float bv=-3e38f;
        for(int c=0;c<5;c++) if(!used[c]&&sFv[c]>bv){bv=sFv[c];best=c;}
        used[best]=true; indF[p]=best; } }
    { bool used[5]={0,0,0,0,0};
      for(int p=0;p<5;p++){ int best=0; float bv=-3e38f;
        for(int c=0;c<5;c++) if(!used[c]&&sIv[c]>bv){bv=sIv[c];best=c;}
        used[best]=true; indI[p]=best; } }
    float t1,t2;
    {
      float inv=2.f/un[0];
      float ps=expf(sIv[indF[0]]/cn[indF[0]]*inv)+expf(sIv[indF[1]]/cn[indF[1]]*inv);
      float ns=expf(sIv[indF[2]]/cn[indF[2]]*inv)+expf(sIv[indF[3]]/cn[indF[3]]*inv);
      t1=log1pf(ns/ps);
    }
    {
      float inv=2.f/un[1];
      float ps=expf(sFv[indI[0]]/cn[indI[0]]*inv)+expf(sFv[indI[1]]/cn[indI[1]]*inv);
      float ns=expf(sFv[indI[2]]/cn[indI[2]]*inv)+expf(sFv[indI[3]]/cn[indI[3]]*inv);
      t2=log1pf(ns/ps);
    }
    loss_part[b]=lp;
    con_part[b]=t1+t2;
  }
}

// ---------------------------------------------------------------------------
// k3: reduce 4096-element partials + weight reg terms -> 4 float32 outputs
// ---------------------------------------------------------------------------
__global__ __launch_bounds__(256) void k3(
    const float* __restrict__ Wpred, const float* __restrict__ Wpe,
    const float* __restrict__ reg_part, const float* __restrict__ ent_part,
    const float* __restrict__ loss_part, const float* __restrict__ con_part,
    float* __restrict__ out)
{
  __shared__ float red[256];
  const int tid=threadIdx.x;

  float sw=0.f;
  for (int i=tid;i<128*64;i+=256){ float v=Wpred[i]; sw+=v*v; }
  for (int i=tid;i<64*64;i+=256){ float v=Wpe[i]; sw+=v*v; }
  float sreg=0.f, sent=0.f, sloss=0.f, scon=0.f;
  for (int i=tid;i<4096;i+=256){
    sreg+=reg_part[i]; sent+=ent_part[i]; sloss+=loss_part[i]; scon+=con_part[i];
  }

  float vals[5]={sloss,sreg,sent,scon,sw};
  float tot[5];
  for(int t=0;t<5;t++){
    red[tid]=vals[t]; __syncthreads();
    for(int s=128;s>0;s>>=1){ if(tid<s) red[tid]+=red[tid+s]; __syncthreads(); }
    tot[t]=red[0]; __syncthreads();
  }
  if(tid==0){
    out[0]=tot[0]/(4096.f*4.f);
    out[1]=tot[1]/4096.f + tot[4];
    out[2]=-tot[2]/(50.f*4096.f);
    out[3]=tot[3]/4096.f;
  }
}

extern "C" void kernel_launch(void* const* d_in, const int* in_sizes, int n_in,
                              void* d_out, int out_size, void* d_ws, size_t ws_size,
                              hipStream_t stream)
{
  const float* emb     =(const float*)d_in[0];
  const float* Wpe     =(const float*)d_in[1];
  const float* Wpred   =(const float*)d_in[2];
  const float* Wgat    =(const float*)d_in[3];
  const float* a_src   =(const float*)d_in[4];
  const float* a_dst   =(const float*)d_in[5];
  const float* Wo      =(const float*)d_in[6];
  const float* Wassign =(const float*)d_in[7];
  const float* adj     =(const float*)d_in[8];
  const int* history  =(const int*)d_in[9];
  const int* timestp  =(const int*)d_in[10];
  const int* pos_id   =(const int*)d_in[11];
  const int* neg_id   =(const int*)d_in[12];
  const int* stp      =(const int*)d_in[13];
  float* out=(float*)d_out;

  char* ws=(char*)d_ws;
  size_t off=0;
  float* reg_part =(float*)(ws+off); off+=4096*4;
  float* ent_part =(float*)(ws+off); off+=4096*4;
  float* loss_part=(float*)(ws+off); off+=4096*4;
  float* con_part =(float*)(ws+off); off+=4096*4;
  bf16* x    =(bf16*)(ws+off);  off+=(size_t)4096*3200*2;
  float* cand=(float*)(ws+off); off+=(size_t)4096*320*4;
  float* xp  =(float*)(ws+off); off+=(size_t)4096*640*4;
  float* uF  =(float*)(ws+off); off+=(size_t)4096*64*4;

  k0<<<4096,256,0,stream>>>(emb,Wpe,Wassign,history,timestp,pos_id,neg_id,stp,x,cand,xp,uF,reg_part,ent_part);
  k12<<<4096,256,0,stream>>>(x,Wgat,a_src,a_dst,Wo,adj,cand,xp,uF,Wpred,loss_part,con_part);
  k3<<<1,256,0,stream>>>(Wpred,Wpe,reg_part,ent_part,loss_part,con_part,out);
}

// Round 5
// 754.849 us; speedup vs baseline: 2.8165x; 1.9420x over previous
//
#include <hip/hip_runtime.h>
#include <hip/hip_bf16.h>
#include <math.h>

typedef __hip_bfloat16 bf16;
typedef __attribute__((ext_vector_type(8))) short sv8;   // 8 bf16 = 4 VGPR (MFMA A/B frag)
typedef __attribute__((ext_vector_type(4))) short sv4;   // 4 bf16 = 2 VGPR
typedef __attribute__((ext_vector_type(4))) float fv4;   // MFMA C/D frag

__device__ __forceinline__ float b2f(bf16 v){ return __bfloat162float(v); }
__device__ __forceinline__ bf16  f2b(float v){ return __float2bfloat16(v); }
__device__ __forceinline__ short f2bs(float v){ bf16 h=__float2bfloat16(v); short s; __builtin_memcpy(&s,&h,2); return s; }
__device__ __forceinline__ float bs2f(short s){ bf16 h; __builtin_memcpy(&h,&s,2); return __bfloat162float(h); }
__device__ __forceinline__ fv4 MFMA(sv8 a, sv8 b, fv4 c){
  return __builtin_amdgcn_mfma_f32_16x16x32_bf16(a,b,c,0,0,0);
}

// ---------------------------------------------------------------------------
// k_pe: pew_table[t][d] = (pe[t] @ W_PE)[d] for all 512 timestamps. 1 block/t.
// ---------------------------------------------------------------------------
__global__ __launch_bounds__(64) void k_pe(const float* __restrict__ Wpe, float* __restrict__ pewt)
{
  const int t=blockIdx.x, d=threadIdx.x;
  __shared__ float pr[64];
  const float c0 = -logf(10000.f)/32.f;
  float ang = (float)t * expf((float)(d>>1)*c0);
  pr[d] = (d&1)? cosf(ang) : sinf(ang);
  __syncthreads();
  float a=0.f;
  #pragma unroll 8
  for(int j=0;j<64;j++) a += pr[j]*Wpe[j*64+d];
  pewt[t*64+d]=a;
}

// ---------------------------------------------------------------------------
// k0: gathers + mask -> x; s=softmax(x@W_assign); x_parent; user_F; partials.
// ---------------------------------------------------------------------------
__global__ __launch_bounds__(256) void k0(
    const float* __restrict__ emb, const float* __restrict__ Wassign, const float* __restrict__ pewt,
    const int* __restrict__ history, const int* __restrict__ timestp,
    const int* __restrict__ pos_id, const int* __restrict__ neg_id, const int* __restrict__ stp,
    bf16* __restrict__ x_out, float* __restrict__ cand_out, float* __restrict__ xp_out,
    float* __restrict__ userF_out, float* __restrict__ reg_part, float* __restrict__ ent_part)
{
  const int b = blockIdx.x, tid = threadIdx.x;
  __shared__ float xs[3200];
  __shared__ float wa[640];
  __shared__ float sb[500];
  __shared__ float xpl[640];
  __shared__ float red[256];
  __shared__ int hist[50];
  __shared__ int tvals[50];
  __shared__ int ids[5];
  __shared__ int stv[1];

  if (tid < 50) hist[tid] = history[b*50+tid];
  if (tid >= 64 && tid < 114) tvals[tid-64] = timestp[b*50+(tid-64)];
  if (tid == 128) stv[0] = stp[b];
  if (tid == 129) ids[0] = pos_id[b];
  if (tid >= 130 && tid < 134) ids[tid-129] = neg_id[b*4+(tid-130)];
  for (int i=tid;i<640;i+=256) wa[i] = Wassign[i];
  __syncthreads();

  float regp=0.f;
  for (int i=tid;i<3200;i+=256){
    int n=i>>6, d=i&63;
    float ev=emb[(size_t)hist[n]*64 + d];
    regp += ev*ev;
    float v = (hist[n]>0) ? (ev + pewt[tvals[n]*64+d]) : 0.f;
    xs[i]=v;
    x_out[(size_t)b*3200+i]=f2b(v);
  }
  for (int i=tid;i<320;i+=256){
    int cc=i>>6, d=i&63;
    float ev=emb[(size_t)ids[cc]*64+d];
    regp += ev*ev;
    cand_out[(size_t)b*320+i]=ev + pewt[stv[0]*64+d];
  }
  __syncthreads();
  for (int i=tid;i<500;i+=256){
    int n=i/10, k=i-n*10;
    float a=0.f;
    for(int d=0;d<64;d++) a += xs[(n<<6)+d]*wa[d*10+k];
    sb[i]=a;
  }
  __syncthreads();
  float entp=0.f;
  if (tid<50){
    float mx=-1e30f;
    for(int k=0;k<10;k++) mx=fmaxf(mx, sb[tid*10+k]);
    float e[10], sm=0.f;
    for(int k=0;k<10;k++){ e[k]=expf(sb[tid*10+k]-mx); sm+=e[k]; }
    float inv=1.f/sm;
    for(int k=0;k<10;k++){ float sv=e[k]*inv; sb[tid*10+k]=sv; entp += sv*logf(sv); }
  }
  __syncthreads();
  for (int i=tid;i<640;i+=256){
    int k=i>>6, d=i&63;
    float a=0.f;
    for(int n=0;n<50;n++) a += sb[n*10+k]*xs[(n<<6)+d];
    xpl[i]=a;
    xp_out[(size_t)b*640+i]=a;
  }
  __syncthreads();
  if (tid<64){
    float a=0.f;
    for(int k=0;k<10;k++) a += xpl[(k<<6)+tid];
    userF_out[(size_t)b*64+tid]=a*0.1f;
  }
  red[tid]=regp; __syncthreads();
  for(int s=128;s>0;s>>=1){ if(tid<s) red[tid]+=red[tid+s]; __syncthreads(); }
  if(tid==0) reg_part[b]=red[0];
  __syncthreads();
  red[tid]=entp; __syncthreads();
  for(int s=128;s>0;s>>=1){ if(tid<s) red[tid]+=red[tid+s]; __syncthreads(); }
  if(tid==0) ent_part[b]=red[0];
}

// ---------------------------------------------------------------------------
// k12: MFMA GAT. wave = head. Three 16x16x32-bf16 GEMM chains per head:
//   Wh = X@Wg  ->  O = P@Wh  ->  partial = O@Wo_h ; cross-head sum + losses.
// LDS arena (76608 B, 2 blocks/CU):
//   [0      ..36864) whT[h][col][row] bf16 stride 72   (later: stage-6 overlay)
//   [36864  ..73728) pp/op[h][row][col] bf16 stride 72
//   [73728  ..75328) es_[200], ed_[200] f32
//   [75328  ..76608) part[256], uacc[64] f32
// ---------------------------------------------------------------------------
__global__ __launch_bounds__(256,2) void k12(
    const bf16* __restrict__ x_in, const float* __restrict__ Wgat,
    const float* __restrict__ a_src, const float* __restrict__ a_dst,
    const float* __restrict__ Wo, const float* __restrict__ adj,
    const float* __restrict__ cand_in, const float* __restrict__ xp_in,
    const float* __restrict__ userF_in, const float* __restrict__ Wpred,
    float* __restrict__ loss_part, float* __restrict__ con_part)
{
  const int b=blockIdx.x, tid=threadIdx.x;
  const int h=tid>>6, lane=tid&63;
  const int c=lane&15, q=lane>>4;

  __shared__ __align__(16) char arena[76608];
  char* WH = arena + h*9216;
  char* PP = arena + 36864 + h*9216;
  float* es_ = (float*)(arena+73728);
  float* ed_ = (float*)(arena+74528);
  float* part = (float*)(arena+75328);
  float* uacc = (float*)(arena+76352);

  // ---- matmul1: Wh_h = X(50x64,pad64) @ Wg_h(64x64) ----
  sv8 af[4][2];
  const short* xb = (const short*)(x_in + (size_t)b*3200);
  #pragma unroll
  for(int mt=0;mt<4;mt++){
    int r = mt*16 + c; if(r>=50) r=0;      // clamp pad rows (finite garbage ok)
    #pragma unroll
    for(int ks=0;ks<2;ks++)
      af[mt][ks] = *(const sv8*)(xb + r*64 + ks*32 + q*8);
  }
  float esp[16], edp[16];
  #pragma unroll
  for(int i=0;i<16;i++){ esp[i]=0.f; edp[i]=0.f; }
  float asv[4], adv[4];
  #pragma unroll
  for(int nt=0;nt<4;nt++){ asv[nt]=a_src[h*64+nt*16+c]; adv[nt]=a_dst[h*64+nt*16+c]; }

  const float* wg = Wgat + h*4096;
  #pragma unroll
  for(int nt=0;nt<4;nt++){
    sv8 bfr[2];
    #pragma unroll
    for(int ks=0;ks<2;ks++){
      sv8 t;
      #pragma unroll
      for(int j=0;j<8;j++) t[j]=f2bs(wg[(ks*32+q*8+j)*64 + nt*16 + c]);
      bfr[ks]=t;
    }
    #pragma unroll
    for(int mt=0;mt<4;mt++){
      fv4 acc={0.f,0.f,0.f,0.f};
      acc = MFMA(af[mt][0], bfr[0], acc);
      acc = MFMA(af[mt][1], bfr[1], acc);
      sv4 w;
      #pragma unroll
      for(int reg=0;reg<4;reg++){
        esp[mt*4+reg] += acc[reg]*asv[nt];
        edp[mt*4+reg] += acc[reg]*adv[nt];
        w[reg]=f2bs(acc[reg]);
      }
      *(sv4*)(WH + (nt*16+c)*144 + (mt*16+4*q)*2) = w;   // whT[col][row..row+3]
    }
  }
  // reduce es/ed over the 16 column-lanes of each quad group
  #pragma unroll
  for(int i=0;i<16;i++){
    float e1=esp[i], e2=edp[i];
    #pragma unroll
    for(int m=1;m<16;m<<=1){ e1+=__shfl_xor(e1,m,64); e2+=__shfl_xor(e2,m,64); }
    esp[i]=e1; edp[i]=e2;
  }
  if(c==0){
    #pragma unroll
    for(int mt=0;mt<4;mt++)
      #pragma unroll
      for(int reg=0;reg<4;reg++){
        int m=mt*16+4*q+reg;
        if(m<50){ es_[h*50+m]=esp[mt*4+reg]; ed_[h*50+m]=edp[mt*4+reg]; }
      }
  }

  // ---- softmax rows -> P into PP (A-layout: [row n][col m2]) ----
  const float* adjb = adj + (size_t)b*2500;
  float ed_l = (lane<50)? ed_[h*50+lane] : 0.f;
  for(int n=0;n<50;n++){
    float av=(lane<50)? adjb[n*50+lane] : 0.f;
    float z = es_[h*50+n] + ed_l;
    float lr = (z>0.f)? z : 0.2f*z;
    float e = (lane<50 && av>0.f)? lr : -1e9f;
    float mx=e;
    #pragma unroll
    for(int m=32;m>0;m>>=1) mx=fmaxf(mx,__shfl_xor(mx,m,64));
    float p=(lane<50)? expf(e-mx):0.f;
    float sm=p;
    #pragma unroll
    for(int m=32;m>0;m>>=1) sm+=__shfl_xor(sm,m,64);
    *(short*)(PP + n*144 + lane*2) = f2bs(p/sm);
  }

  // ---- matmul2: O_h = P(50x64pad-k, zeros k>=50) @ Wh(64x64) ----
  {
    sv8 ap[4][2];
    #pragma unroll
    for(int mt=0;mt<4;mt++)
      #pragma unroll
      for(int ks=0;ks<2;ks++)
        ap[mt][ks] = *(const sv8*)(PP + (mt*16+c)*144 + (ks*32+q*8)*2);
    #pragma unroll
    for(int nt=0;nt<4;nt++){
      sv8 bfr[2];
      #pragma unroll
      for(int ks=0;ks<2;ks++)
        bfr[ks] = *(const sv8*)(WH + (nt*16+c)*144 + (ks*32+q*8)*2);
      #pragma unroll
      for(int mt=0;mt<4;mt++){
        fv4 acc={0.f,0.f,0.f,0.f};
        acc = MFMA(ap[mt][0], bfr[0], acc);
        acc = MFMA(ap[mt][1], bfr[1], acc);
        #pragma unroll
        for(int reg=0;reg<4;reg++)
          *(short*)(PP + (mt*16+4*q+reg)*144 + (nt*16+c)*2) = f2bs(acc[reg]); // O row-major
      }
    }
  }

  // ---- matmul3: partial_h = O_h(50x64) @ Wo[h*64..h*64+63][:] ----
  {
    sv8 ao[4][2];
    #pragma unroll
    for(int mt=0;mt<4;mt++)
      #pragma unroll
      for(int ks=0;ks<2;ks++)
        ao[mt][ks] = *(const sv8*)(PP + (mt*16+c)*144 + (ks*32+q*8)*2);
    const float* wo = Wo + (size_t)h*64*64;
    #pragma unroll
    for(int nt=0;nt<4;nt++){
      sv8 bfr[2];
      #pragma unroll
      for(int ks=0;ks<2;ks++){
        sv8 t;
        #pragma unroll
        for(int j=0;j<8;j++) t[j]=f2bs(wo[(ks*32+q*8+j)*64 + nt*16 + c]);
        bfr[ks]=t;
      }
      #pragma unroll
      for(int mt=0;mt<4;mt++){
        fv4 acc={0.f,0.f,0.f,0.f};
        acc = MFMA(ao[mt][0], bfr[0], acc);
        acc = MFMA(ao[mt][1], bfr[1], acc);
        #pragma unroll
        for(int reg=0;reg<4;reg++)
          *(short*)(PP + (mt*16+4*q+reg)*144 + (nt*16+c)*2) = f2bs(acc[reg]); // partial row-major
      }
    }
  }
  __syncthreads();                              // barrier 1: partials published

  // ---- stage 6 overlays on whT arena ----
  float* xnl  =(float*)arena;
  float* cnd  =(float*)(arena+12800);
  float* xpl  =(float*)(arena+14080);
  float* uFvec=(float*)(arena+16640);
  float* lF   =(float*)(arena+16896);
  float* lI   =(float*)(arena+17096);
  float* uFb  =(float*)(arena+18096);
  float* uIb  =(float*)(arena+19376);
  float* ub   =(float*)(arena+20656);
  float* sc   =(float*)(arena+21936);
  float* sIv  =(float*)(arena+21956);
  float* sFv  =(float*)(arena+21976);
  float* cnv  =(float*)(arena+21996);
  float* un   =(float*)(arena+22016);

  float up=0.f;
  for(int i=tid;i<3200;i+=256){
    int n=i>>6, d=i&63;
    float v=0.f;
    #pragma unroll
    for(int hh=0;hh<4;hh++) v += bs2f(*(const short*)(arena+36864+hh*9216 + n*144 + d*2));
    v = (v>0.f)? v : expm1f(v);                 // elu
    xnl[i]=v;
    up += v;
  }
  part[tid]=up;
  for(int i=tid;i<320;i+=256) cnd[i]=cand_in[(size_t)b*320+i];
  for(int i=tid;i<640;i+=256) xpl[i]=xp_in[(size_t)b*640+i];
  if(tid<64) uFvec[tid]=userF_in[(size_t)b*64+tid];
  __syncthreads();                              // barrier 2
  if(tid<64) uacc[tid]=(part[tid]+part[64+tid]+part[128+tid]+part[192+tid])*0.02f;

  if(tid<50){
    int cc=tid/10, k=tid-(tid/10)*10;
    float a=0.f;
    for(int d=0;d<64;d++) a += xpl[(k<<6)+d]*cnd[(cc<<6)+d];
    lF[tid]=a;
  }
  for(int i=tid;i<250;i+=256){
    int cc=i/50, n2=i-cc*50;
    float a=0.f;
    for(int d=0;d<64;d++) a += xnl[(n2<<6)+d]*cnd[(cc<<6)+d];
    lI[i]=a;
  }
  __syncthreads();                              // barrier 3
  if(tid<5){
    float mx=-1e30f;
    for(int k=0;k<10;k++) mx=fmaxf(mx,lF[tid*10+k]);
    float s=0.f;
    for(int k=0;k<10;k++){ float e2=expf(lF[tid*10+k]-mx); lF[tid*10+k]=e2; s+=e2; }
    float inv=1.f/s;
    for(int k=0;k<10;k++) lF[tid*10+k]*=inv;
    mx=-1e30f;
    for(int n2=0;n2<50;n2++) mx=fmaxf(mx,lI[tid*50+n2]);
    s=0.f;
    for(int n2=0;n2<50;n2++){ float e2=expf(lI[tid*50+n2]-mx); lI[tid*50+n2]=e2; s+=e2; }
    inv=1.f/s;
    for(int n2=0;n2<50;n2++) lI[tid*50+n2]*=inv;
  }
  __syncthreads();                              // barrier 4
  for(int i=tid;i<320;i+=256){
    int cc=i>>6, d=i&63;
    float a=0.f;
    for(int k=0;k<10;k++) a += lF[cc*10+k]*xpl[(k<<6)+d];
    uFb[i]=a;
    float a2=0.f;
    for(int n2=0;n2<50;n2++) a2 += lI[cc*50+n2]*xnl[(n2<<6)+d];
    uIb[i]=a2;
  }
  __syncthreads();                              // barrier 5
  for(int i=tid;i<320;i+=256){
    int cc=i>>6, d=i&63;
    float a=0.f;
    #pragma unroll 8
    for(int j=0;j<64;j++) a += uFb[(cc<<6)+j]*Wpred[(j<<6)+d];
    #pragma unroll 8
    for(int j=0;j<64;j++) a += uIb[(cc<<6)+j]*Wpred[((64+j)<<6)+d];
    ub[i]=a;
  }
  __syncthreads();                              // barrier 6
  if(tid<5){
    float a=0.f; for(int d=0;d<64;d++) a += ub[(tid<<6)+d]*cnd[(tid<<6)+d];
    sc[tid]=a;
  } else if(tid>=8&&tid<13){
    int cc=tid-8; float a=0.f; for(int d=0;d<64;d++) a += cnd[(cc<<6)+d]*uacc[d];
    sIv[cc]=a;
  } else if(tid>=16&&tid<21){
    int cc=tid-16; float a=0.f; for(int d=0;d<64;d++) a += cnd[(cc<<6)+d]*uFvec[d];
    sFv[cc]=a;
  } else if(tid>=24&&tid<29){
    int cc=tid-24; float a=0.f; for(int d=0;d<64;d++){ float v=cnd[(cc<<6)+d]; a+=v*v; }
    cnv[cc]=sqrtf(a);
  } else if(tid==32){
    float a=0.f; for(int d=0;d<64;d++) a+=uacc[d]*uacc[d]; un[0]=sqrtf(a);
  } else if(tid==33){
    float a=0.f; for(int d=0;d<64;d++) a+=uFvec[d]*uFvec[d]; un[1]=sqrtf(a);
  }
  __syncthreads();                              // barrier 7
  if(tid==0){
    float lp=0.f;
    for(int cc=1;cc<5;cc++){
      float z=sc[cc]-sc[0];
      lp += fmaxf(z,0.f)+log1pf(expf(-fabsf(z)));
    }
    int indF[5], indI[5];
    { bool used[5]={0,0,0,0,0};
      for(int p=0;p<5;p++){ int best=0; float bv=-3e38f;
        for(int cc=0;cc<5;cc++) if(!used[cc]&&sFv[cc]>bv){bv=sFv[cc];best=cc;}
        used[best]=true; indF[p]=best; } }
    { bool used[5]={0,0,0,0,0};
      for(int p=0;p<5;p++){ int best=0; float bv=-3e38f;
        for(int cc=0;cc<5;cc++) if(!used[cc]&&sIv[cc]>bv){bv=sIv[cc];best=cc;}
        used[best]=true; indI[p]=best; } }
    float t1,t2;
    {
      float inv=2.f/un[0];
      float ps=expf(sIv[indF[0]]/cnv[indF[0]]*inv)+expf(sIv[indF[1]]/cnv[indF[1]]*inv);
      float ns=expf(sIv[indF[2]]/cnv[indF[2]]*inv)+expf(sIv[indF[3]]/cnv[indF[3]]*inv);
      t1=log1pf(ns/ps);
    }
    {
      float inv=2.f/un[1];
      float ps=expf(sFv[indI[0]]/cnv[indI[0]]*inv)+expf(sFv[indI[1]]/cnv[indI[1]]*inv);
      float ns=expf(sFv[indI[2]]/cnv[indI[2]]*inv)+expf(sFv[indI[3]]/cnv[indI[3]]*inv);
      t2=log1pf(ns/ps);
    }
    loss_part[b]=lp;
    con_part[b]=t1+t2;
  }
}

// ---------------------------------------------------------------------------
// k3a (16 blocks): partial sums of the 4096-elem arrays; block0 adds weights.
// k3b (1 block): finalize -> 4 f32 outputs.
// ---------------------------------------------------------------------------
__global__ __launch_bounds__(256) void k3a(
    const float* __restrict__ Wpred, const float* __restrict__ Wpe,
    const float* __restrict__ reg_part, const float* __restrict__ ent_part,
    const float* __restrict__ loss_part, const float* __restrict__ con_part,
    float* __restrict__ acc4, float* __restrict__ accW)
{
  const int blk=blockIdx.x, tid=threadIdx.x;
  const int base=blk*256+tid;
  __shared__ float r4[4][4];
  __shared__ float rw[4];
  float v[4]={reg_part[base],ent_part[base],loss_part[base],con_part[base]};
  #pragma unroll
  for(int t2=0;t2<4;t2++){
    float s=v[t2];
    #pragma unroll
    for(int m=1;m<64;m<<=1) s+=__shfl_xor(s,m,64);
    if((tid&63)==0) r4[t2][tid>>6]=s;
  }
  float sw=0.f;
  if(blk==0){
    for(int i=tid;i<8192;i+=256){ float w=Wpred[i]; sw+=w*w; }
    for(int i=tid;i<4096;i+=256){ float w=Wpe[i]; sw+=w*w; }
    #pragma unroll
    for(int m=1;m<64;m<<=1) sw+=__shfl_xor(sw,m,64);
  }
  if((tid&63)==0) rw[tid>>6]=sw;
  __syncthreads();
  if(tid==0){
    for(int t2=0;t2<4;t2++) acc4[blk*4+t2]=r4[t2][0]+r4[t2][1]+r4[t2][2]+r4[t2][3];
    if(blk==0) accW[0]=rw[0]+rw[1]+rw[2]+rw[3];
  }
}

__global__ __launch_bounds__(64) void k3b(
    const float* __restrict__ acc4, const float* __restrict__ accW, float* __restrict__ out)
{
  const int t=threadIdx.x;
  const int cdx=t>>4, i=t&15;
  __shared__ float tot[4];
  float v=acc4[i*4+cdx];
  #pragma unroll
  for(int m=1;m<16;m<<=1) v+=__shfl_xor(v,m,64);
  if(i==0) tot[cdx]=v;
  __syncthreads();
  if(t==0){
    out[0]=tot[2]/(4096.f*4.f);          // loss
    out[1]=tot[0]/4096.f + accW[0];      // loss_reg
    out[2]=-tot[1]/(50.f*4096.f);        // loss_entropy
    out[3]=tot[3]/4096.f;                // loss_con
  }
}

extern "C" void kernel_launch(void* const* d_in, const int* in_sizes, int n_in,
                              void* d_out, int out_size, void* d_ws, size_t ws_size,
                              hipStream_t stream)
{
  const float* emb     =(const float*)d_in[0];
  const float* Wpe     =(const float*)d_in[1];
  const float* Wpred   =(const float*)d_in[2];
  const float* Wgat    =(const float*)d_in[3];
  const float* a_src   =(const float*)d_in[4];
  const float* a_dst   =(const float*)d_in[5];
  const float* Wo      =(const float*)d_in[6];
  const float* Wassign =(const float*)d_in[7];
  const float* adj     =(const float*)d_in[8];
  const int* history  =(const int*)d_in[9];
  const int* timestp  =(const int*)d_in[10];
  const int* pos_id   =(const int*)d_in[11];
  const int* neg_id   =(const int*)d_in[12];
  const int* stp      =(const int*)d_in[13];
  float* out=(float*)d_out;

  char* ws=(char*)d_ws;
  float* reg_part =(float*)(ws+0);
  float* ent_part =(float*)(ws+16384);
  float* loss_part=(float*)(ws+32768);
  float* con_part =(float*)(ws+49152);
  float* acc4     =(float*)(ws+65536);
  float* accW     =(float*)(ws+65792);
  float* pewt     =(float*)(ws+66048);                 // 512*64 f32
  bf16*  x        =(bf16*)(ws+197120);                 // 4096*3200 bf16
  float* cand     =(float*)(ws+197120+26214400);       // 4096*320 f32
  float* xp       =(float*)(ws+197120+26214400+5242880);
  float* uF       =(float*)(ws+197120+26214400+5242880+10485760);

  k_pe<<<512,64,0,stream>>>(Wpe,pewt);
  k0<<<4096,256,0,stream>>>(emb,Wassign,pewt,history,timestp,pos_id,neg_id,stp,x,cand,xp,uF,reg_part,ent_part);
  k12<<<4096,256,0,stream>>>(x,Wgat,a_src,a_dst,Wo,adj,cand,xp,uF,Wpred,loss_part,con_part);
  k3a<<<16,256,0,stream>>>(Wpred,Wpe,reg_part,ent_part,loss_part,con_part,acc4,accW);
  k3b<<<1,64,0,stream>>>(acc4,accW,out);
}

// Round 6
// 750.173 us; speedup vs baseline: 2.8341x; 1.0062x over previous
//
#include <hip/hip_runtime.h>
#include <hip/hip_bf16.h>
#include <math.h>

typedef __hip_bfloat16 bf16;
typedef __attribute__((ext_vector_type(8))) short sv8;   // 8 bf16 = 4 VGPR (MFMA A/B frag)
typedef __attribute__((ext_vector_type(4))) short sv4;   // 4 bf16 = 2 VGPR
typedef __attribute__((ext_vector_type(4))) float fv4;   // MFMA C/D frag

__device__ __forceinline__ float b2f(bf16 v){ return __bfloat162float(v); }
__device__ __forceinline__ bf16  f2b(float v){ return __float2bfloat16(v); }
__device__ __forceinline__ short f2bs(float v){ bf16 h=__float2bfloat16(v); short s; __builtin_memcpy(&s,&h,2); return s; }
__device__ __forceinline__ float bs2f(short s){ bf16 h; __builtin_memcpy(&h,&s,2); return __bfloat162float(h); }
__device__ __forceinline__ fv4 MFMA(sv8 a, sv8 b, fv4 c){
  return __builtin_amdgcn_mfma_f32_16x16x32_bf16(a,b,c,0,0,0);
}

// ---------------------------------------------------------------------------
// k_pe: pew_table[t][d] = (pe[t] @ W_PE)[d] for all 512 timestamps.
// ---------------------------------------------------------------------------
__global__ __launch_bounds__(64) void k_pe(const float* __restrict__ Wpe, float* __restrict__ pewt)
{
  const int t=blockIdx.x, d=threadIdx.x;
  __shared__ float pr[64];
  const float c0 = -logf(10000.f)/32.f;
  float ang = (float)t * expf((float)(d>>1)*c0);
  pr[d] = (d&1)? cosf(ang) : sinf(ang);
  __syncthreads();
  float a=0.f;
  #pragma unroll 8
  for(int j=0;j<64;j++) a += pr[j]*Wpe[j*64+d];
  pewt[t*64+d]=a;
}

// ---------------------------------------------------------------------------
// k_prep: pre-pack Wgat / Wo / a_src,a_dst into bf16 MFMA B-frag layout.
// frag index: (((h*4+nt)*2+ks)*64 + lane)*8 + j ; element = W[k][16nt+c],
// k = ks*32+(lane>>4)*8+j, c = lane&15.   asb: col0=a_src, col1=a_dst.
// ---------------------------------------------------------------------------
__global__ __launch_bounds__(256) void k_prep(
    const float* __restrict__ Wg, const float* __restrict__ Wo,
    const float* __restrict__ as_, const float* __restrict__ ad_,
    short* __restrict__ wgb, short* __restrict__ wob, short* __restrict__ asb)
{
  int i = blockIdx.x*256+threadIdx.x;           // 0..16383
  int j=i&7, lane=(i>>3)&63, ks=(i>>9)&1, nt=(i>>10)&3, h=(i>>12)&3;
  int c=lane&15, q=lane>>4;
  int k=ks*32+q*8+j;
  wgb[i] = f2bs(Wg[h*4096 + k*64 + nt*16 + c]);
  wob[i] = f2bs(Wo[(size_t)(h*64 + k)*64 + nt*16 + c]);
  if(i<4096){
    int j2=i&7, lane2=(i>>3)&63, ks2=(i>>9)&1, h2=(i>>10)&3;
    int c2=lane2&15, q2=lane2>>4; int k2=ks2*32+q2*8+j2;
    float v = (c2==0)? as_[h2*64+k2] : (c2==1? ad_[h2*64+k2] : 0.f);
    asb[i]=f2bs(v);
  }
}

// ---------------------------------------------------------------------------
// k0: gathers + mask -> x; s=softmax(x@W_assign); x_parent; user_F; partials.
// ---------------------------------------------------------------------------
__global__ __launch_bounds__(256) void k0(
    const float* __restrict__ emb, const float* __restrict__ Wassign, const float* __restrict__ pewt,
    const int* __restrict__ history, const int* __restrict__ timestp,
    const int* __restrict__ pos_id, const int* __restrict__ neg_id, const int* __restrict__ stp,
    bf16* __restrict__ x_out, float* __restrict__ cand_out, float* __restrict__ xp_out,
    float* __restrict__ userF_out, float* __restrict__ reg_part, float* __restrict__ ent_part)
{
  const int b = blockIdx.x, tid = threadIdx.x;
  const int w = tid>>6, lane = tid&63;
  __shared__ float xs[3200];
  __shared__ float wat[640];      // transposed W_assign: wat[k*64+d]
  __shared__ float sb[500];
  __shared__ float xpl[640];
  __shared__ float red[256];
  __shared__ int hist[50];
  __shared__ int tvals[50];
  __shared__ int ids[5];
  __shared__ int stv[1];

  if (tid < 50) hist[tid] = history[b*50+tid];
  if (tid >= 64 && tid < 114) tvals[tid-64] = timestp[b*50+(tid-64)];
  if (tid == 128) stv[0] = stp[b];
  if (tid == 129) ids[0] = pos_id[b];
  if (tid >= 130 && tid < 134) ids[tid-129] = neg_id[b*4+(tid-130)];
  for (int i=tid;i<640;i+=256){ int k=i>>6, d=i&63; wat[i] = Wassign[d*10+k]; }
  __syncthreads();

  float regp=0.f;
  for (int i=tid;i<3200;i+=256){
    int n=i>>6, d=i&63;
    float ev=emb[(size_t)hist[n]*64 + d];
    regp += ev*ev;
    float v = (hist[n]>0) ? (ev + pewt[tvals[n]*64+d]) : 0.f;
    xs[i]=v;
    x_out[(size_t)b*3200+i]=f2b(v);
  }
  for (int i=tid;i<320;i+=256){
    int cc=i>>6, d=i&63;
    float ev=emb[(size_t)ids[cc]*64+d];
    regp += ev*ev;
    cand_out[(size_t)b*320+i]=ev + pewt[stv[0]*64+d];
  }
  __syncthreads();
  // logits = x @ W_assign : 500 wave-dots (conflict-free, shuffle-reduced)
  for (int idx=w; idx<500; idx+=4){
    int n=idx/10, k=idx-n*10;
    float s = xs[(n<<6)+lane]*wat[(k<<6)+lane];
    #pragma unroll
    for(int m=32;m>0;m>>=1) s += __shfl_xor(s,m,64);
    if(lane==0) sb[n*10+k]=s;
  }
  __syncthreads();
  float entp=0.f;
  if (tid<50){
    float mx=-1e30f;
    for(int k=0;k<10;k++) mx=fmaxf(mx, sb[tid*10+k]);
    float e[10], sm=0.f;
    for(int k=0;k<10;k++){ e[k]=expf(sb[tid*10+k]-mx); sm+=e[k]; }
    float inv=1.f/sm;
    for(int k=0;k<10;k++){ float sv=e[k]*inv; sb[tid*10+k]=sv; entp += sv*logf(sv); }
  }
  __syncthreads();
  for (int i=tid;i<640;i+=256){
    int k=i>>6, d=i&63;
    float a=0.f;
    for(int n=0;n<50;n++) a += sb[n*10+k]*xs[(n<<6)+d];
    xpl[i]=a;
    xp_out[(size_t)b*640+i]=a;
  }
  __syncthreads();
  if (tid<64){
    float a=0.f;
    for(int k=0;k<10;k++) a += xpl[(k<<6)+tid];
    userF_out[(size_t)b*64+tid]=a*0.1f;
  }
  red[tid]=regp; __syncthreads();
  for(int s=128;s>0;s>>=1){ if(tid<s) red[tid]+=red[tid+s]; __syncthreads(); }
  if(tid==0) reg_part[b]=red[0];
  __syncthreads();
  red[tid]=entp; __syncthreads();
  for(int s=128;s>0;s>>=1){ if(tid<s) red[tid]+=red[tid+s]; __syncthreads(); }
  if(tid==0) ent_part[b]=red[0];
}

// ---------------------------------------------------------------------------
// k12: MFMA GAT, barrier-free per-head chain. wave = head.
// ---------------------------------------------------------------------------
__global__ __launch_bounds__(256,2) void k12(
    bf16* xbuf, const float* __restrict__ adj,
    const short* __restrict__ wgb, const short* __restrict__ wob, const short* __restrict__ asb,
    float* __restrict__ uacc_out)
{
  const int b=blockIdx.x, tid=threadIdx.x;
  const int h=tid>>6, lane=tid&63;
  const int c=lane&15, q=lane>>4;

  __shared__ __align__(16) char arena[77824];
  char* base = arena + h*19200;
  char* WH = base;
  char* PP = base + 9216;
  float* es_f = (float*)(base+18432);
  float* ed_f = (float*)(base+18688);
  float* inv_f= (float*)(base+18944);
  float* part = (float*)(arena+76800);

  // ---- A-frags of X ----
  sv8 af[4][2];
  const short* xb = (const short*)(xbuf + (size_t)b*3200);
  #pragma unroll
  for(int mt=0;mt<4;mt++){
    int r = mt*16 + c; if(r>=50) r=0;
    #pragma unroll
    for(int ks=0;ks<2;ks++)
      af[mt][ks] = *(const sv8*)(xb + r*64 + ks*32 + q*8);
  }

  // ---- matmul1: Wh = X@Wg ----
  #pragma unroll
  for(int nt=0;nt<4;nt++){
    sv8 b0 = *(const sv8*)(wgb + (((h*4+nt)*2+0)*64 + lane)*8);
    sv8 b1 = *(const sv8*)(wgb + (((h*4+nt)*2+1)*64 + lane)*8);
    #pragma unroll
    for(int mt=0;mt<4;mt++){
      fv4 acc={0.f,0.f,0.f,0.f};
      acc = MFMA(af[mt][0], b0, acc);
      acc = MFMA(af[mt][1], b1, acc);
      sv4 wv;
      #pragma unroll
      for(int reg=0;reg<4;reg++) wv[reg]=f2bs(acc[reg]);
      *(sv4*)(WH + (nt*16+c)*144 + (mt*16+4*q)*2) = wv;   // whT[col][row]
    }
  }
  // ---- fused es/ed tile (B cols: 0=a_src, 1=a_dst) ----
  {
    sv8 a5b0 = *(const sv8*)(asb + ((h*2+0)*64 + lane)*8);
    sv8 a5b1 = *(const sv8*)(asb + ((h*2+1)*64 + lane)*8);
    #pragma unroll
    for(int mt=0;mt<4;mt++){
      fv4 acc={0.f,0.f,0.f,0.f};
      acc = MFMA(af[mt][0], a5b0, acc);
      acc = MFMA(af[mt][1], a5b1, acc);
      if(c==0){
        #pragma unroll
        for(int reg=0;reg<4;reg++) es_f[mt*16+4*q+reg]=acc[reg];
      } else if(c==1){
        #pragma unroll
        for(int reg=0;reg<4;reg++) ed_f[mt*16+4*q+reg]=acc[reg];
      }
    }
  }

  // ---- adj bitmask: lane n holds mask of row n ----
  unsigned long long mymask=0ULL;
  const float* adjb = adj + (size_t)b*2500;
  for(int n=0;n<50;n++){
    float av = (lane<50)? adjb[n*50+lane] : 0.f;
    unsigned long long mk = __ballot(av>0.f);
    if(lane==n) mymask = mk;
  }

  // ---- per-lane softmax: raw exp into PP row lane; invsum saved ----
  {
    float es_n = es_f[lane];
    float mx=-1e9f;
    #pragma unroll
    for(int m=0;m<50;m++){
      float z = es_n + ed_f[m];
      float lr = (z>0.f)? z : 0.2f*z;
      float e = ((mymask>>m)&1ULL)? lr : -1e9f;
      mx = fmaxf(mx,e);
    }
    float sum=0.f;
    #pragma unroll
    for(int mb=0;mb<48;mb+=4){
      sv4 wv;
      #pragma unroll
      for(int jj=0;jj<4;jj++){
        int m=mb+jj;
        float z = es_n + ed_f[m];
        float lr = (z>0.f)? z : 0.2f*z;
        float e = ((mymask>>m)&1ULL)? lr : -1e9f;
        float p = (lane<50)? expf(e-mx) : 0.f;
        wv[jj]=f2bs(p); sum+=p;
      }
      *(sv4*)(PP + lane*144 + mb*2) = wv;
    }
    {
      sv4 wv={0,0,0,0};
      #pragma unroll
      for(int jj=0;jj<2;jj++){
        int m=48+jj;
        float z = es_n + ed_f[m];
        float lr = (z>0.f)? z : 0.2f*z;
        float e = ((mymask>>m)&1ULL)? lr : -1e9f;
        float p = (lane<50)? expf(e-mx) : 0.f;
        wv[jj]=f2bs(p); sum+=p;
      }
      *(sv4*)(PP + lane*144 + 48*2) = wv;         // m 48,49 + zero 50,51
    }
    sv4 zz={0,0,0,0};
    *(sv4*)(PP + lane*144 + 52*2) = zz;           // m 52..55
    *(sv4*)(PP + lane*144 + 56*2) = zz;           // m 56..59
    *(sv4*)(PP + lane*144 + 60*2) = zz;           // m 60..63
    inv_f[lane] = (lane<50)? 1.f/sum : 0.f;
  }

  // ---- matmul2: O = Praw @ Wh, scaled by invsum[row] ----
  {
    sv8 ap[4][2];
    #pragma unroll
    for(int mt=0;mt<4;mt++)
      #pragma unroll
      for(int ks=0;ks<2;ks++)
        ap[mt][ks] = *(const sv8*)(PP + (mt*16+c)*144 + (ks*32+q*8)*2);
    float invr[16];
    #pragma unroll
    for(int mt=0;mt<4;mt++)
      #pragma unroll
      for(int reg=0;reg<4;reg++) invr[mt*4+reg]=inv_f[mt*16+4*q+reg];
    #pragma unroll
    for(int nt=0;nt<4;nt++){
      sv8 bfr[2];
      #pragma unroll
      for(int ks=0;ks<2;ks++)
        bfr[ks] = *(const sv8*)(WH + (nt*16+c)*144 + (ks*32+q*8)*2);
      #pragma unroll
      for(int mt=0;mt<4;mt++){
        fv4 acc={0.f,0.f,0.f,0.f};
        acc = MFMA(ap[mt][0], bfr[0], acc);
        acc = MFMA(ap[mt][1], bfr[1], acc);
        #pragma unroll
        for(int reg=0;reg<4;reg++)
          *(short*)(PP + (mt*16+4*q+reg)*144 + (nt*16+c)*2) = f2bs(acc[reg]*invr[mt*4+reg]);
      }
    }
  }

  // ---- matmul3: partial = O @ Wo_h ----
  {
    sv8 ao[4][2];
    #pragma unroll
    for(int mt=0;mt<4;mt++)
      #pragma unroll
      for(int ks=0;ks<2;ks++)
        ao[mt][ks] = *(const sv8*)(PP + (mt*16+c)*144 + (ks*32+q*8)*2);
    #pragma unroll
    for(int nt=0;nt<4;nt++){
      sv8 bfr[2];
      #pragma unroll
      for(int ks=0;ks<2;ks++)
        bfr[ks] = *(const sv8*)(wob + (((h*4+nt)*2+ks)*64 + lane)*8);
      #pragma unroll
      for(int mt=0;mt<4;mt++){
        fv4 acc={0.f,0.f,0.f,0.f};
        acc = MFMA(ao[mt][0], bfr[0], acc);
        acc = MFMA(ao[mt][1], bfr[1], acc);
        #pragma unroll
        for(int reg=0;reg<4;reg++)
          *(short*)(PP + (mt*16+4*q+reg)*144 + (nt*16+c)*2) = f2bs(acc[reg]);
      }
    }
  }
  __syncthreads();                              // barrier 1

  // ---- cross-head sum -> elu -> xnl (in-place over xbuf) + uacc ----
  float up=0.f;
  for(int i=tid;i<3200;i+=256){
    int n=i>>6, d=i&63;
    float v=0.f;
    #pragma unroll
    for(int hh=0;hh<4;hh++)
      v += bs2f(*(const short*)(arena + hh*19200 + 9216 + n*144 + d*2));
    v = (v>0.f)? v : expm1f(v);
    xbuf[(size_t)b*3200+i] = f2b(v);
    up += v;
  }
  part[tid]=up;
  __syncthreads();                              // barrier 2
  if(tid<64) uacc_out[(size_t)b*64+tid] = (part[tid]+part[64+tid]+part[128+tid]+part[192+tid])*0.02f;
}

// ---------------------------------------------------------------------------
// k6: aggregates + W_pred + losses. Small LDS, wave-shuffle dots.
// ---------------------------------------------------------------------------
__global__ __launch_bounds__(256) void k6(
    const bf16* __restrict__ xnl_in, const float* __restrict__ cand_in,
    const float* __restrict__ xp_in, const float* __restrict__ userF_in,
    const float* __restrict__ uacc_in, const float* __restrict__ Wpred,
    float* __restrict__ loss_part, float* __restrict__ con_part)
{
  const int b=blockIdx.x, tid=threadIdx.x;
  const int w=tid>>6, lane=tid&63;
  __shared__ float xnl[3200];
  __shared__ float cnd[320];
  __shared__ float xpl[640];
  __shared__ float uFvec[64], uacc[64];
  __shared__ float lF[50];
  __shared__ float lI[250];
  __shared__ float uFb[320], uIb[320], ub[320];
  __shared__ float sc[5], sIv[5], sFv[5], cnv[5], un[2];

  for(int i=tid;i<3200;i+=256) xnl[i]=b2f(xnl_in[(size_t)b*3200+i]);
  for(int i=tid;i<320;i+=256) cnd[i]=cand_in[(size_t)b*320+i];
  for(int i=tid;i<640;i+=256) xpl[i]=xp_in[(size_t)b*640+i];
  if(tid<64){ uFvec[tid]=userF_in[(size_t)b*64+tid]; uacc[tid]=uacc_in[(size_t)b*64+tid]; }
  __syncthreads();

  for(int idx=w; idx<300; idx+=4){
    float s;
    if(idx<50){
      int k=idx%10, cc=idx/10;
      s = xpl[(k<<6)+lane]*cnd[(cc<<6)+lane];
    } else {
      int t=idx-50; int cc=t/50, n2=t-cc*50;
      s = xnl[(n2<<6)+lane]*cnd[(cc<<6)+lane];
    }
    #pragma unroll
    for(int m=32;m>0;m>>=1) s += __shfl_xor(s,m,64);
    if(lane==0){ if(idx<50) lF[idx]=s; else lI[idx-50]=s; }
  }
  __syncthreads();
  if(tid<5){
    float mx=-1e30f;
    for(int k=0;k<10;k++) mx=fmaxf(mx,lF[tid*10+k]);
    float s=0.f;
    for(int k=0;k<10;k++){ float e2=expf(lF[tid*10+k]-mx); lF[tid*10+k]=e2; s+=e2; }
    float inv=1.f/s;
    for(int k=0;k<10;k++) lF[tid*10+k]*=inv;
    mx=-1e30f;
    for(int n2=0;n2<50;n2++) mx=fmaxf(mx,lI[tid*50+n2]);
    s=0.f;
    for(int n2=0;n2<50;n2++){ float e2=expf(lI[tid*50+n2]-mx); lI[tid*50+n2]=e2; s+=e2; }
    inv=1.f/s;
    for(int n2=0;n2<50;n2++) lI[tid*50+n2]*=inv;
  }
  __syncthreads();
  for(int i=tid;i<320;i+=256){
    int cc=i>>6, d=i&63;
    float a=0.f;
    for(int k=0;k<10;k++) a += lF[cc*10+k]*xpl[(k<<6)+d];
    uFb[i]=a;
    float a2=0.f;
    for(int n2=0;n2<50;n2++) a2 += lI[cc*50+n2]*xnl[(n2<<6)+d];
    uIb[i]=a2;
  }
  __syncthreads();
  for(int i=tid;i<320;i+=256){
    int cc=i>>6, d=i&63;
    float a=0.f;
    #pragma unroll 8
    for(int j=0;j<64;j++) a += uFb[(cc<<6)+j]*Wpred[(j<<6)+d];
    #pragma unroll 8
    for(int j=0;j<64;j++) a += uIb[(cc<<6)+j]*Wpred[((64+j)<<6)+d];
    ub[i]=a;
  }
  __syncthreads();
  for(int idx=w; idx<22; idx+=4){
    float va, vb;
    if(idx<5){ va=ub[(idx<<6)+lane]; vb=cnd[(idx<<6)+lane]; }
    else if(idx<10){ int cc=idx-5; va=cnd[(cc<<6)+lane]; vb=uacc[lane]; }
    else if(idx<15){ int cc=idx-10; va=cnd[(cc<<6)+lane]; vb=uFvec[lane]; }
    else if(idx<20){ int cc=idx-15; va=cnd[(cc<<6)+lane]; vb=va; }
    else if(idx==20){ va=uacc[lane]; vb=va; }
    else { va=uFvec[lane]; vb=va; }
    float s=va*vb;
    #pragma unroll
    for(int m=32;m>0;m>>=1) s += __shfl_xor(s,m,64);
    if(lane==0){
      if(idx<5) sc[idx]=s;
      else if(idx<10) sIv[idx-5]=s;
      else if(idx<15) sFv[idx-10]=s;
      else if(idx<20) cnv[idx-15]=sqrtf(s);
      else un[idx-20]=sqrtf(s);
    }
  }
  __syncthreads();
  if(tid==0){
    float lp=0.f;
    for(int cc=1;cc<5;cc++){
      float z=sc[cc]-sc[0];
      lp += fmaxf(z,0.f)+log1pf(expf(-fabsf(z)));
    }
    int indF[5], indI[5];
    { bool used[5]={0,0,0,0,0};
      for(int p=0;p<5;p++){ int best=0; float bv=-3e38f;
        for(int cc=0;cc<5;cc++) if(!used[cc]&&sFv[cc]>bv){bv=sFv[cc];best=cc;}
        used[best]=true; indF[p]=best; } }
    { bool used[5]={0,0,0,0,0};
      for(int p=0;p<5;p++){ int best=0; float bv=-3e38f;
        for(int cc=0;cc<5;cc++) if(!used[cc]&&sIv[cc]>bv){bv=sIv[cc];best=cc;}
        used[best]=true; indI[p]=best; } }
    float t1,t2;
    {
      float inv=2.f/un[0];
      float ps=expf(sIv[indF[0]]/cnv[indF[0]]*inv)+expf(sIv[indF[1]]/cnv[indF[1]]*inv);
      float ns=expf(sIv[indF[2]]/cnv[indF[2]]*inv)+expf(sIv[indF[3]]/cnv[indF[3]]*inv);
      t1=log1pf(ns/ps);
    }
    {
      float inv=2.f/un[1];
      float ps=expf(sFv[indI[0]]/cnv[indI[0]]*inv)+expf(sFv[indI[1]]/cnv[indI[1]]*inv);
      float ns=expf(sFv[indI[2]]/cnv[indI[2]]*inv)+expf(sFv[indI[3]]/cnv[indI[3]]*inv);
      t2=log1pf(ns/ps);
    }
    loss_part[b]=lp;
    con_part[b]=t1+t2;
  }
}

// ---------------------------------------------------------------------------
// k3a/k3b: final reductions -> 4 f32 outputs
// ---------------------------------------------------------------------------
__global__ __launch_bounds__(256) void k3a(
    const float* __restrict__ Wpred, const float* __restrict__ Wpe,
    const float* __restrict__ reg_part, const float* __restrict__ ent_part,
    const float* __restrict__ loss_part, const float* __restrict__ con_part,
    float* __restrict__ acc4, float* __restrict__ accW)
{
  const int blk=blockIdx.x, tid=threadIdx.x;
  const int base=blk*256+tid;
  __shared__ float r4[4][4];
  __shared__ float rw[4];
  float v[4]={reg_part[base],ent_part[base],loss_part[base],con_part[base]};
  #pragma unroll
  for(int t2=0;t2<4;t2++){
    float s=v[t2];
    #pragma unroll
    for(int m=1;m<64;m<<=1) s+=__shfl_xor(s,m,64);
    if((tid&63)==0) r4[t2][tid>>6]=s;
  }
  float sw=0.f;
  if(blk==0){
    for(int i=tid;i<8192;i+=256){ float w=Wpred[i]; sw+=w*w; }
    for(int i=tid;i<4096;i+=256){ float w=Wpe[i]; sw+=w*w; }
    #pragma unroll
    for(int m=1;m<64;m<<=1) sw+=__shfl_xor(sw,m,64);
  }
  if((tid&63)==0) rw[tid>>6]=sw;
  __syncthreads();
  if(tid==0){
    for(int t2=0;t2<4;t2++) acc4[blk*4+t2]=r4[t2][0]+r4[t2][1]+r4[t2][2]+r4[t2][3];
    if(blk==0) accW[0]=rw[0]+rw[1]+rw[2]+rw[3];
  }
}

__global__ __launch_bounds__(64) void k3b(
    const float* __restrict__ acc4, const float* __restrict__ accW, float* __restrict__ out)
{
  const int t=threadIdx.x;
  const int cdx=t>>4, i=t&15;
  __shared__ float tot[4];
  float v=acc4[i*4+cdx];
  #pragma unroll
  for(int m=1;m<16;m<<=1) v+=__shfl_xor(v,m,64);
  if(i==0) tot[cdx]=v;
  __syncthreads();
  if(t==0){
    out[0]=tot[2]/(4096.f*4.f);          // loss
    out[1]=tot[0]/4096.f + accW[0];      // loss_reg
    out[2]=-tot[1]/(50.f*4096.f);        // loss_entropy
    out[3]=tot[3]/4096.f;                // loss_con
  }
}

extern "C" void kernel_launch(void* const* d_in, const int* in_sizes, int n_in,
                              void* d_out, int out_size, void* d_ws, size_t ws_size,
                              hipStream_t stream)
{
  const float* emb     =(const float*)d_in[0];
  const float* Wpe     =(const float*)d_in[1];
  const float* Wpred   =(const float*)d_in[2];
  const float* Wgat    =(const float*)d_in[3];
  const float* a_src   =(const float*)d_in[4];
  const float* a_dst   =(const float*)d_in[5];
  const float* Wo      =(const float*)d_in[6];
  const float* Wassign =(const float*)d_in[7];
  const float* adj     =(const float*)d_in[8];
  const int* history  =(const int*)d_in[9];
  const int* timestp  =(const int*)d_in[10];
  const int* pos_id   =(const int*)d_in[11];
  const int* neg_id   =(const int*)d_in[12];
  const int* stp      =(const int*)d_in[13];
  float* out=(float*)d_out;

  char* ws=(char*)d_ws;
  float* reg_part =(float*)(ws+0);
  float* ent_part =(float*)(ws+16384);
  float* loss_part=(float*)(ws+32768);
  float* con_part =(float*)(ws+49152);
  float* acc4     =(float*)(ws+65536);
  float* accW     =(float*)(ws+65792);
  float* pewt     =(float*)(ws+66048);           // 512*64 f32 -> ends 197120
  short* wgb      =(short*)(ws+197120);          // 32768 B
  short* wob      =(short*)(ws+229888);          // 32768 B
  short* asb      =(short*)(ws+262656);          // 8192 B -> ends 270848
  bf16*  x        =(bf16*)(ws+270848);           // xnl in-place after k12
  float* cand     =(float*)(ws+270848+26214400);
  float* xp       =(float*)(ws+270848+26214400+5242880);
  float* uF       =(float*)(ws+270848+26214400+5242880+10485760);
  float* uaccw    =(float*)(ws+270848+26214400+5242880+10485760+1048576);

  k_pe<<<512,64,0,stream>>>(Wpe,pewt);
  k_prep<<<64,256,0,stream>>>(Wgat,Wo,a_src,a_dst,wgb,wob,asb);
  k0<<<4096,256,0,stream>>>(emb,Wassign,pewt,history,timestp,pos_id,neg_id,stp,x,cand,xp,uF,reg_part,ent_part);
  k12<<<4096,256,0,stream>>>(x,adj,wgb,wob,asb,uaccw);
  k6<<<4096,256,0,stream>>>(x,cand,xp,uF,uaccw,Wpred,loss_part,con_part);
  k3a<<<16,256,0,stream>>>(Wpred,Wpe,reg_part,ent_part,loss_part,con_part,acc4,accW);
  k3b<<<1,64,0,stream>>>(acc4,accW,out);
}

// Round 7
// 741.067 us; speedup vs baseline: 2.8689x; 1.0123x over previous
//
#include <hip/hip_runtime.h>
#include <hip/hip_bf16.h>
#include <math.h>

typedef __hip_bfloat16 bf16;
typedef __attribute__((ext_vector_type(8))) short sv8;   // 8 bf16 = 4 VGPR (MFMA A/B frag)
typedef __attribute__((ext_vector_type(4))) short sv4;   // 4 bf16 = 2 VGPR
typedef __attribute__((ext_vector_type(4))) float fv4;   // MFMA C/D frag

__device__ __forceinline__ float b2f(bf16 v){ return __bfloat162float(v); }
__device__ __forceinline__ bf16  f2b(float v){ return __float2bfloat16(v); }
__device__ __forceinline__ short f2bs(float v){ bf16 h=__float2bfloat16(v); short s; __builtin_memcpy(&s,&h,2); return s; }
__device__ __forceinline__ float bs2f(short s){ bf16 h; __builtin_memcpy(&h,&s,2); return __bfloat162float(h); }
__device__ __forceinline__ fv4 MFMA(sv8 a, sv8 b, fv4 c){
  return __builtin_amdgcn_mfma_f32_16x16x32_bf16(a,b,c,0,0,0);
}
__device__ __forceinline__ int pk2(float a, float b){
  unsigned sa=(unsigned short)f2bs(a);
  unsigned sb=((unsigned)(unsigned short)f2bs(b))<<16;
  return (int)(sa|sb);
}
union U8 { int i[4]; sv8 v; };

// ---------------------------------------------------------------------------
// k_pe: pew_table[t][d] = (pe[t] @ W_PE)[d] for all 512 timestamps.
// ---------------------------------------------------------------------------
__global__ __launch_bounds__(64) void k_pe(const float* __restrict__ Wpe, float* __restrict__ pewt)
{
  const int t=blockIdx.x, d=threadIdx.x;
  __shared__ float pr[64];
  const float c0 = -logf(10000.f)/32.f;
  float ang = (float)t * expf((float)(d>>1)*c0);
  pr[d] = (d&1)? cosf(ang) : sinf(ang);
  __syncthreads();
  float a=0.f;
  #pragma unroll 8
  for(int j=0;j<64;j++) a += pr[j]*Wpe[j*64+d];
  pewt[t*64+d]=a;
}

// ---------------------------------------------------------------------------
// k_prep: pre-pack Wgat / Wo / a_src,a_dst into bf16 MFMA B-frag layout.
// ---------------------------------------------------------------------------
__global__ __launch_bounds__(256) void k_prep(
    const float* __restrict__ Wg, const float* __restrict__ Wo,
    const float* __restrict__ as_, const float* __restrict__ ad_,
    short* __restrict__ wgb, short* __restrict__ wob, short* __restrict__ asb)
{
  int i = blockIdx.x*256+threadIdx.x;           // 0..16383
  int j=i&7, lane=(i>>3)&63, ks=(i>>9)&1, nt=(i>>10)&3, h=(i>>12)&3;
  int c=lane&15, q=lane>>4;
  int k=ks*32+q*8+j;
  wgb[i] = f2bs(Wg[h*4096 + k*64 + nt*16 + c]);
  wob[i] = f2bs(Wo[(size_t)(h*64 + k)*64 + nt*16 + c]);
  if(i<4096){
    int j2=i&7, lane2=(i>>3)&63, ks2=(i>>9)&1, h2=(i>>10)&3;
    int c2=lane2&15, q2=lane2>>4; int k2=ks2*32+q2*8+j2;
    float v = (c2==0)? as_[h2*64+k2] : (c2==1? ad_[h2*64+k2] : 0.f);
    asb[i]=f2bs(v);
  }
}

// ---------------------------------------------------------------------------
// k0: gathers + mask -> x; s=softmax(x@W_assign); x_parent; user_F; partials.
// ---------------------------------------------------------------------------
__global__ __launch_bounds__(256) void k0(
    const float* __restrict__ emb, const float* __restrict__ Wassign, const float* __restrict__ pewt,
    const int* __restrict__ history, const int* __restrict__ timestp,
    const int* __restrict__ pos_id, const int* __restrict__ neg_id, const int* __restrict__ stp,
    bf16* __restrict__ x_out, float* __restrict__ cand_out, float* __restrict__ xp_out,
    float* __restrict__ userF_out, float* __restrict__ reg_part, float* __restrict__ ent_part)
{
  const int b = blockIdx.x, tid = threadIdx.x;
  const int w = tid>>6, lane = tid&63;
  __shared__ float xs[3200];
  __shared__ float wat[640];      // transposed W_assign: wat[k*64+d]
  __shared__ float sb[500];
  __shared__ float xpl[640];
  __shared__ float red[256];
  __shared__ int hist[50];
  __shared__ int tvals[50];
  __shared__ int ids[5];
  __shared__ int stv[1];

  if (tid < 50) hist[tid] = history[b*50+tid];
  if (tid >= 64 && tid < 114) tvals[tid-64] = timestp[b*50+(tid-64)];
  if (tid == 128) stv[0] = stp[b];
  if (tid == 129) ids[0] = pos_id[b];
  if (tid >= 130 && tid < 134) ids[tid-129] = neg_id[b*4+(tid-130)];
  for (int i=tid;i<640;i+=256){ int k=i>>6, d=i&63; wat[i] = Wassign[d*10+k]; }
  __syncthreads();

  float regp=0.f;
  for (int i=tid;i<3200;i+=256){
    int n=i>>6, d=i&63;
    float ev=emb[(size_t)hist[n]*64 + d];
    regp += ev*ev;
    float v = (hist[n]>0) ? (ev + pewt[tvals[n]*64+d]) : 0.f;
    xs[i]=v;
    x_out[(size_t)b*3200+i]=f2b(v);
  }
  for (int i=tid;i<320;i+=256){
    int cc=i>>6, d=i&63;
    float ev=emb[(size_t)ids[cc]*64+d];
    regp += ev*ev;
    cand_out[(size_t)b*320+i]=ev + pewt[stv[0]*64+d];
  }
  __syncthreads();
  for (int idx=w; idx<500; idx+=4){
    int n=idx/10, k=idx-n*10;
    float s = xs[(n<<6)+lane]*wat[(k<<6)+lane];
    #pragma unroll
    for(int m=32;m>0;m>>=1) s += __shfl_xor(s,m,64);
    if(lane==0) sb[n*10+k]=s;
  }
  __syncthreads();
  float entp=0.f;
  if (tid<50){
    float mx=-1e30f;
    for(int k=0;k<10;k++) mx=fmaxf(mx, sb[tid*10+k]);
    float e[10], sm=0.f;
    for(int k=0;k<10;k++){ e[k]=expf(sb[tid*10+k]-mx); sm+=e[k]; }
    float inv=1.f/sm;
    for(int k=0;k<10;k++){ float sv=e[k]*inv; sb[tid*10+k]=sv; entp += sv*logf(sv); }
  }
  __syncthreads();
  for (int i=tid;i<640;i+=256){
    int k=i>>6, d=i&63;
    float a=0.f;
    for(int n=0;n<50;n++) a += sb[n*10+k]*xs[(n<<6)+d];
    xpl[i]=a;
    xp_out[(size_t)b*640+i]=a;
  }
  __syncthreads();
  if (tid<64){
    float a=0.f;
    for(int k=0;k<10;k++) a += xpl[(k<<6)+tid];
    userF_out[(size_t)b*64+tid]=a*0.1f;
  }
  red[tid]=regp; __syncthreads();
  for(int s=128;s>0;s>>=1){ if(tid<s) red[tid]+=red[tid+s]; __syncthreads(); }
  if(tid==0) reg_part[b]=red[0];
  __syncthreads();
  red[tid]=entp; __syncthreads();
  for(int s=128;s>0;s>>=1){ if(tid<s) red[tid]+=red[tid+s]; __syncthreads(); }
  if(tid==0) ent_part[b]=red[0];
}

// ---------------------------------------------------------------------------
// k12: MFMA GAT (Wh register-resident, shuffle-transposed) + fused losses.
// LDS arena 41984 B:
//   [0..36864)      PP[h] stride 9216 (P -> O -> partial; later k6 overlay)
//   [36864..40960)  es/ed/inv per head (1024 B each)
//   [40960..41984)  part[256] f32
// ---------------------------------------------------------------------------
__global__ __launch_bounds__(256,3) void k12(
    const bf16* __restrict__ x_in, const float* __restrict__ adj,
    const short* __restrict__ wgb, const short* __restrict__ wob, const short* __restrict__ asb,
    const float* __restrict__ cand_in, const float* __restrict__ xp_in,
    const float* __restrict__ userF_in, const float* __restrict__ Wpred,
    float* __restrict__ loss_part, float* __restrict__ con_part)
{
  const int b=blockIdx.x, tid=threadIdx.x;
  const int h=tid>>6, lane=tid&63;
  const int c=lane&15, q=lane>>4;

  __shared__ __align__(16) char arena[41984];
  char* PP = arena + h*9216;
  float* es_f = (float*)(arena+36864 + h*1024);
  float* ed_f = es_f + 64;
  float* inv_f= es_f + 128;
  float* part = (float*)(arena+40960);

  // ---- A-frags of X ----
  sv8 af[4][2];
  const short* xb = (const short*)(x_in + (size_t)b*3200);
  #pragma unroll
  for(int mt=0;mt<4;mt++){
    int r = mt*16 + c; if(r>=50) r=0;
    #pragma unroll
    for(int ks=0;ks<2;ks++)
      af[mt][ks] = *(const sv8*)(xb + r*64 + ks*32 + q*8);
  }

  // ---- matmul1: Wh = X@Wg, kept in registers as packed D-tiles ----
  int wh_pk[4][4][2];
  #pragma unroll
  for(int nt=0;nt<4;nt++){
    sv8 b0 = *(const sv8*)(wgb + (((h*4+nt)*2+0)*64 + lane)*8);
    sv8 b1 = *(const sv8*)(wgb + (((h*4+nt)*2+1)*64 + lane)*8);
    #pragma unroll
    for(int mt=0;mt<4;mt++){
      fv4 acc={0.f,0.f,0.f,0.f};
      acc = MFMA(af[mt][0], b0, acc);
      acc = MFMA(af[mt][1], b1, acc);
      wh_pk[mt][nt][0]=pk2(acc[0],acc[1]);
      wh_pk[mt][nt][1]=pk2(acc[2],acc[3]);
    }
  }
  // ---- fused es/ed tile (B cols: 0=a_src, 1=a_dst) ----
  {
    sv8 a5b0 = *(const sv8*)(asb + ((h*2+0)*64 + lane)*8);
    sv8 a5b1 = *(const sv8*)(asb + ((h*2+1)*64 + lane)*8);
    #pragma unroll
    for(int mt=0;mt<4;mt++){
      fv4 acc={0.f,0.f,0.f,0.f};
      acc = MFMA(af[mt][0], a5b0, acc);
      acc = MFMA(af[mt][1], a5b1, acc);
      if(c==0){
        #pragma unroll
        for(int reg=0;reg<4;reg++) es_f[mt*16+4*q+reg]=acc[reg];
      } else if(c==1){
        #pragma unroll
        for(int reg=0;reg<4;reg++) ed_f[mt*16+4*q+reg]=acc[reg];
      }
    }
  }

  // ---- adj bitmask: lane n holds mask of row n ----
  unsigned long long mymask=0ULL;
  const float* adjb = adj + (size_t)b*2500;
  for(int n=0;n<50;n++){
    float av = (lane<50)? adjb[n*50+lane] : 0.f;
    unsigned long long mk = __ballot(av>0.f);
    if(lane==n) mymask = mk;
  }

  // ---- per-lane softmax: raw exp into PP row=lane; invsum saved ----
  {
    float es_n = es_f[lane];
    float mx=-1e9f;
    #pragma unroll
    for(int m=0;m<50;m++){
      float z = es_n + ed_f[m];
      float lr = (z>0.f)? z : 0.2f*z;
      float e = ((mymask>>m)&1ULL)? lr : -1e9f;
      mx = fmaxf(mx,e);
    }
    float sum=0.f;
    #pragma unroll
    for(int mb=0;mb<48;mb+=4){
      sv4 wv;
      #pragma unroll
      for(int jj=0;jj<4;jj++){
        int m=mb+jj;
        float z = es_n + ed_f[m];
        float lr = (z>0.f)? z : 0.2f*z;
        float e = ((mymask>>m)&1ULL)? lr : -1e9f;
        float p = (lane<50)? expf(e-mx) : 0.f;
        wv[jj]=f2bs(p); sum+=p;
      }
      *(sv4*)(PP + lane*144 + mb*2) = wv;
    }
    {
      sv4 wv={0,0,0,0};
      #pragma unroll
      for(int jj=0;jj<2;jj++){
        int m=48+jj;
        float z = es_n + ed_f[m];
        float lr = (z>0.f)? z : 0.2f*z;
        float e = ((mymask>>m)&1ULL)? lr : -1e9f;
        float p = (lane<50)? expf(e-mx) : 0.f;
        wv[jj]=f2bs(p); sum+=p;
      }
      *(sv4*)(PP + lane*144 + 48*2) = wv;         // m 48,49 + zero 50,51
    }
    sv4 zz={0,0,0,0};
    *(sv4*)(PP + lane*144 + 52*2) = zz;
    *(sv4*)(PP + lane*144 + 56*2) = zz;
    *(sv4*)(PP + lane*144 + 60*2) = zz;
    inv_f[lane] = (lane<50)? 1.f/sum : 0.f;
  }

  // ---- matmul2: O = Praw @ Wh (Wh B-frags via shuffle transpose) ----
  {
    sv8 ap[4][2];
    #pragma unroll
    for(int mt=0;mt<4;mt++)
      #pragma unroll
      for(int ks=0;ks<2;ks++)
        ap[mt][ks] = *(const sv8*)(PP + (mt*16+c)*144 + (ks*32+q*8)*2);
    float invr[16];
    #pragma unroll
    for(int mt=0;mt<4;mt++)
      #pragma unroll
      for(int reg=0;reg<4;reg++) invr[mt*4+reg]=inv_f[mt*16+4*q+reg];

    const int L = c + ((q&1)<<5);
    const bool hi = (q>>1)!=0;
    #pragma unroll
    for(int nt=0;nt<4;nt++){
      sv8 bfr[2];
      #pragma unroll
      for(int ks=0;ks<2;ks++){
        int a0=__shfl(wh_pk[2*ks+0][nt][0],L,64), b0=__shfl(wh_pk[2*ks+1][nt][0],L,64);
        int a1=__shfl(wh_pk[2*ks+0][nt][1],L,64), b1=__shfl(wh_pk[2*ks+1][nt][1],L,64);
        int a2=__shfl(wh_pk[2*ks+0][nt][0],L+16,64), b2=__shfl(wh_pk[2*ks+1][nt][0],L+16,64);
        int a3=__shfl(wh_pk[2*ks+0][nt][1],L+16,64), b3=__shfl(wh_pk[2*ks+1][nt][1],L+16,64);
        U8 u;
        u.i[0]=hi?b0:a0; u.i[1]=hi?b1:a1; u.i[2]=hi?b2:a2; u.i[3]=hi?b3:a3;
        bfr[ks]=u.v;
      }
      #pragma unroll
      for(int mt=0;mt<4;mt++){
        fv4 acc={0.f,0.f,0.f,0.f};
        acc = MFMA(ap[mt][0], bfr[0], acc);
        acc = MFMA(ap[mt][1], bfr[1], acc);
        #pragma unroll
        for(int reg=0;reg<4;reg++)
          *(short*)(PP + (mt*16+4*q+reg)*144 + (nt*16+c)*2) = f2bs(acc[reg]*invr[mt*4+reg]);
      }
    }
  }

  // ---- matmul3: partial = O @ Wo_h ----
  {
    sv8 ao[4][2];
    #pragma unroll
    for(int mt=0;mt<4;mt++)
      #pragma unroll
      for(int ks=0;ks<2;ks++)
        ao[mt][ks] = *(const sv8*)(PP + (mt*16+c)*144 + (ks*32+q*8)*2);
    #pragma unroll
    for(int nt=0;nt<4;nt++){
      sv8 bfr[2];
      #pragma unroll
      for(int ks=0;ks<2;ks++)
        bfr[ks] = *(const sv8*)(wob + (((h*4+nt)*2+ks)*64 + lane)*8);
      #pragma unroll
      for(int mt=0;mt<4;mt++){
        fv4 acc={0.f,0.f,0.f,0.f};
        acc = MFMA(ao[mt][0], bfr[0], acc);
        acc = MFMA(ao[mt][1], bfr[1], acc);
        #pragma unroll
        for(int reg=0;reg<4;reg++)
          *(short*)(PP + (mt*16+4*q+reg)*144 + (nt*16+c)*2) = f2bs(acc[reg]);
      }
    }
  }
  __syncthreads();                              // barrier 1: partials ready

  // ---- cross-head sum -> elu in registers; prefetch small tensors ----
  float ve[13];
  float up=0.f;
  {
    int ii=0;
    for(int i=tid;i<3200;i+=256,ii++){
      int n=i>>6, d=i&63;
      float v=0.f;
      #pragma unroll
      for(int hh=0;hh<4;hh++)
        v += bs2f(*(const short*)(arena + hh*9216 + n*144 + d*2));
      v = (v>0.f)? v : expm1f(v);
      ve[ii]=v; up+=v;
    }
  }
  part[tid]=up;
  float cndr0 = cand_in[(size_t)b*320 + tid%320];
  float cndr1 = (tid<64)? cand_in[(size_t)b*320 + 256 + tid] : 0.f;
  float xplr0 = xp_in[(size_t)b*640 + tid];
  float xplr1 = xp_in[(size_t)b*640 + 256 + tid];
  float xplr2 = (tid<128)? xp_in[(size_t)b*640 + 512 + tid] : 0.f;
  float uFr   = (tid<64)? userF_in[(size_t)b*64 + tid] : 0.f;
  __syncthreads();                              // barrier 2: PP reads done

  // ---- overlay writes (over PP region) ----
  float* xnl  =(float*)arena;
  float* cnd  =(float*)(arena+12800);
  float* xpl  =(float*)(arena+14080);
  float* uFvec=(float*)(arena+16640);
  float* uacc =(float*)(arena+16896);
  float* lF   =(float*)(arena+17152);
  float* lI   =(float*)(arena+17352);
  float* uFb  =(float*)(arena+18352);
  float* uIb  =(float*)(arena+19632);
  float* ub   =(float*)(arena+20912);
  float* sc   =(float*)(arena+22192);
  float* sIv  =(float*)(arena+22212);
  float* sFv  =(float*)(arena+22232);
  float* cnv  =(float*)(arena+22252);
  float* un   =(float*)(arena+22272);

  {
    int ii=0;
    for(int i=tid;i<3200;i+=256,ii++) xnl[i]=ve[ii];
  }
  if(tid<320) cnd[tid]=cndr0;
  if(tid<64)  cnd[256+tid]=cndr1;
  xpl[tid]=xplr0; xpl[256+tid]=xplr1;
  if(tid<128) xpl[512+tid]=xplr2;
  if(tid<64){
    uFvec[tid]=uFr;
    uacc[tid]=(part[tid]+part[64+tid]+part[128+tid]+part[192+tid])*0.02f;
  }
  __syncthreads();                              // barrier 3

  // ---- losses (former k6 body) ----
  const int w=h;
  for(int idx=w; idx<300; idx+=4){
    float s;
    if(idx<50){
      int k=idx%10, cc=idx/10;
      s = xpl[(k<<6)+lane]*cnd[(cc<<6)+lane];
    } else {
      int t=idx-50; int cc=t/50, n2=t-cc*50;
      s = xnl[(n2<<6)+lane]*cnd[(cc<<6)+lane];
    }
    #pragma unroll
    for(int m=32;m>0;m>>=1) s += __shfl_xor(s,m,64);
    if(lane==0){ if(idx<50) lF[idx]=s; else lI[idx-50]=s; }
  }
  __syncthreads();
  if(tid<5){
    float mx=-1e30f;
    for(int k=0;k<10;k++) mx=fmaxf(mx,lF[tid*10+k]);
    float s=0.f;
    for(int k=0;k<10;k++){ float e2=expf(lF[tid*10+k]-mx); lF[tid*10+k]=e2; s+=e2; }
    float inv=1.f/s;
    for(int k=0;k<10;k++) lF[tid*10+k]*=inv;
    mx=-1e30f;
    for(int n2=0;n2<50;n2++) mx=fmaxf(mx,lI[tid*50+n2]);
    s=0.f;
    for(int n2=0;n2<50;n2++){ float e2=expf(lI[tid*50+n2]-mx); lI[tid*50+n2]=e2; s+=e2; }
    inv=1.f/s;
    for(int n2=0;n2<50;n2++) lI[tid*50+n2]*=inv;
  }
  __syncthreads();
  for(int i=tid;i<320;i+=256){
    int cc=i>>6, d=i&63;
    float a=0.f;
    for(int k=0;k<10;k++) a += lF[cc*10+k]*xpl[(k<<6)+d];
    uFb[i]=a;
    float a2=0.f;
    for(int n2=0;n2<50;n2++) a2 += lI[cc*50+n2]*xnl[(n2<<6)+d];
    uIb[i]=a2;
  }
  __syncthreads();
  for(int i=tid;i<320;i+=256){
    int cc=i>>6, d=i&63;
    float a=0.f;
    #pragma unroll 8
    for(int j=0;j<64;j++) a += uFb[(cc<<6)+j]*Wpred[(j<<6)+d];
    #pragma unroll 8
    for(int j=0;j<64;j++) a += uIb[(cc<<6)+j]*Wpred[((64+j)<<6)+d];
    ub[i]=a;
  }
  __syncthreads();
  for(int idx=w; idx<22; idx+=4){
    float va, vb;
    if(idx<5){ va=ub[(idx<<6)+lane]; vb=cnd[(idx<<6)+lane]; }
    else if(idx<10){ int cc=idx-5; va=cnd[(cc<<6)+lane]; vb=uacc[lane]; }
    else if(idx<15){ int cc=idx-10; va=cnd[(cc<<6)+lane]; vb=uFvec[lane]; }
    else if(idx<20){ int cc=idx-15; va=cnd[(cc<<6)+lane]; vb=va; }
    else if(idx==20){ va=uacc[lane]; vb=va; }
    else { va=uFvec[lane]; vb=va; }
    float s=va*vb;
    #pragma unroll
    for(int m=32;m>0;m>>=1) s += __shfl_xor(s,m,64);
    if(lane==0){
      if(idx<5) sc[idx]=s;
      else if(idx<10) sIv[idx-5]=s;
      else if(idx<15) sFv[idx-10]=s;
      else if(idx<20) cnv[idx-15]=sqrtf(s);
      else un[idx-20]=sqrtf(s);
    }
  }
  __syncthreads();
  if(tid==0){
    float lp=0.f;
    for(int cc=1;cc<5;cc++){
      float z=sc[cc]-sc[0];
      lp += fmaxf(z,0.f)+log1pf(expf(-fabsf(z)));
    }
    int indF[5], indI[5];
    { bool used[5]={0,0,0,0,0};
      for(int p=0;p<5;p++){ int best=0; float bv=-3e38f;
        for(int cc=0;cc<5;cc++) if(!used[cc]&&sFv[cc]>bv){bv=sFv[cc];best=cc;}
        used[best]=true; indF[p]=best; } }
    { bool used[5]={0,0,0,0,0};
      for(int p=0;p<5;p++){ int best=0; float bv=-3e38f;
        for(int cc=0;cc<5;cc++) if(!used[cc]&&sIv[cc]>bv){bv=sIv[cc];best=cc;}
        used[best]=true; indI[p]=best; } }
    float t1,t2;
    {
      float inv=2.f/un[0];
      float ps=expf(sIv[indF[0]]/cnv[indF[0]]*inv)+expf(sIv[indF[1]]/cnv[indF[1]]*inv);
      float ns=expf(sIv[indF[2]]/cnv[indF[2]]*inv)+expf(sIv[indF[3]]/cnv[indF[3]]*inv);
      t1=log1pf(ns/ps);
    }
    {
      float inv=2.f/un[1];
      float ps=expf(sFv[indI[0]]/cnv[indI[0]]*inv)+expf(sFv[indI[1]]/cnv[indI[1]]*inv);
      float ns=expf(sFv[indI[2]]/cnv[indI[2]]*inv)+expf(sFv[indI[3]]/cnv[indI[3]]*inv);
      t2=log1pf(ns/ps);
    }
    loss_part[b]=lp;
    con_part[b]=t1+t2;
  }
}

// ---------------------------------------------------------------------------
// k3a/k3b: final reductions -> 4 f32 outputs
// ---------------------------------------------------------------------------
__global__ __launch_bounds__(256) void k3a(
    const float* __restrict__ Wpred, const float* __restrict__ Wpe,
    const float* __restrict__ reg_part, const float* __restrict__ ent_part,
    const float* __restrict__ loss_part, const float* __restrict__ con_part,
    float* __restrict__ acc4, float* __restrict__ accW)
{
  const int blk=blockIdx.x, tid=threadIdx.x;
  const int base=blk*256+tid;
  __shared__ float r4[4][4];
  __shared__ float rw[4];
  float v[4]={reg_part[base],ent_part[base],loss_part[base],con_part[base]};
  #pragma unroll
  for(int t2=0;t2<4;t2++){
    float s=v[t2];
    #pragma unroll
    for(int m=1;m<64;m<<=1) s+=__shfl_xor(s,m,64);
    if((tid&63)==0) r4[t2][tid>>6]=s;
  }
  float sw=0.f;
  if(blk==0){
    for(int i=tid;i<8192;i+=256){ float w=Wpred[i]; sw+=w*w; }
    for(int i=tid;i<4096;i+=256){ float w=Wpe[i]; sw+=w*w; }
    #pragma unroll
    for(int m=1;m<64;m<<=1) sw+=__shfl_xor(sw,m,64);
  }
  if((tid&63)==0) rw[tid>>6]=sw;
  __syncthreads();
  if(tid==0){
    for(int t2=0;t2<4;t2++) acc4[blk*4+t2]=r4[t2][0]+r4[t2][1]+r4[t2][2]+r4[t2][3];
    if(blk==0) accW[0]=rw[0]+rw[1]+rw[2]+rw[3];
  }
}

__global__ __launch_bounds__(64) void k3b(
    const float* __restrict__ acc4, const float* __restrict__ accW, float* __restrict__ out)
{
  const int t=threadIdx.x;
  const int cdx=t>>4, i=t&15;
  __shared__ float tot[4];
  float v=acc4[i*4+cdx];
  #pragma unroll
  for(int m=1;m<16;m<<=1) v+=__shfl_xor(v,m,64);
  if(i==0) tot[cdx]=v;
  __syncthreads();
  if(t==0){
    out[0]=tot[2]/(4096.f*4.f);          // loss
    out[1]=tot[0]/4096.f + accW[0];      // loss_reg
    out[2]=-tot[1]/(50.f*4096.f);        // loss_entropy
    out[3]=tot[3]/4096.f;                // loss_con
  }
}

extern "C" void kernel_launch(void* const* d_in, const int* in_sizes, int n_in,
                              void* d_out, int out_size, void* d_ws, size_t ws_size,
                              hipStream_t stream)
{
  const float* emb     =(const float*)d_in[0];
  const float* Wpe     =(const float*)d_in[1];
  const float* Wpred   =(const float*)d_in[2];
  const float* Wgat    =(const float*)d_in[3];
  const float* a_src   =(const float*)d_in[4];
  const float* a_dst   =(const float*)d_in[5];
  const float* Wo      =(const float*)d_in[6];
  const float* Wassign =(const float*)d_in[7];
  const float* adj     =(const float*)d_in[8];
  const int* history  =(const int*)d_in[9];
  const int* timestp  =(const int*)d_in[10];
  const int* pos_id   =(const int*)d_in[11];
  const int* neg_id   =(const int*)d_in[12];
  const int* stp      =(const int*)d_in[13];
  float* out=(float*)d_out;

  char* ws=(char*)d_ws;
  float* reg_part =(float*)(ws+0);
  float* ent_part =(float*)(ws+16384);
  float* loss_part=(float*)(ws+32768);
  float* con_part =(float*)(ws+49152);
  float* acc4     =(float*)(ws+65536);
  float* accW     =(float*)(ws+65792);
  float* pewt     =(float*)(ws+66048);           // 512*64 f32 -> ends 197120
  short* wgb      =(short*)(ws+197120);          // 32768 B
  short* wob      =(short*)(ws+229888);          // 32768 B
  short* asb      =(short*)(ws+262656);          // 8192 B -> ends 270848
  bf16*  x        =(bf16*)(ws+270848);
  float* cand     =(float*)(ws+270848+26214400);
  float* xp       =(float*)(ws+270848+26214400+5242880);
  float* uF       =(float*)(ws+270848+26214400+5242880+10485760);

  k_pe<<<512,64,0,stream>>>(Wpe,pewt);
  k_prep<<<64,256,0,stream>>>(Wgat,Wo,a_src,a_dst,wgb,wob,asb);
  k0<<<4096,256,0,stream>>>(emb,Wassign,pewt,history,timestp,pos_id,neg_id,stp,x,cand,xp,uF,reg_part,ent_part);
  k12<<<4096,256,0,stream>>>(x,adj,wgb,wob,asb,cand,xp,uF,Wpred,loss_part,con_part);
  k3a<<<16,256,0,stream>>>(Wpred,Wpe,reg_part,ent_part,loss_part,con_part,acc4,accW);
  k3b<<<1,64,0,stream>>>(acc4,accW,out);
}

// Round 8
// 595.924 us; speedup vs baseline: 3.5676x; 1.2436x over previous
//
#include <hip/hip_runtime.h>
#include <hip/hip_bf16.h>
#include <math.h>

typedef __hip_bfloat16 bf16;
typedef __attribute__((ext_vector_type(8))) short sv8;   // 8 bf16 = 4 VGPR (MFMA A/B frag)
typedef __attribute__((ext_vector_type(4))) short sv4;   // 4 bf16 = 2 VGPR
typedef __attribute__((ext_vector_type(4))) float fv4;   // MFMA C/D frag

__device__ __forceinline__ float b2f(bf16 v){ return __bfloat162float(v); }
__device__ __forceinline__ bf16  f2b(float v){ return __float2bfloat16(v); }
__device__ __forceinline__ short f2bs(float v){ bf16 h=__float2bfloat16(v); short s; __builtin_memcpy(&s,&h,2); return s; }
__device__ __forceinline__ float bs2f(short s){ bf16 h; __builtin_memcpy(&h,&s,2); return __bfloat162float(h); }
__device__ __forceinline__ fv4 MFMA(sv8 a, sv8 b, fv4 c){
  return __builtin_amdgcn_mfma_f32_16x16x32_bf16(a,b,c,0,0,0);
}
__device__ __forceinline__ int pk2(float a, float b){
  unsigned sa=(unsigned short)f2bs(a);
  unsigned sb=((unsigned)(unsigned short)f2bs(b))<<16;
  return (int)(sa|sb);
}
__device__ __forceinline__ int pk2s(short a, short b){
  return (int)(((unsigned short)a) | (((unsigned)(unsigned short)b)<<16));
}
union U8 { int i[4]; sv8 v; };

// ---------------------------------------------------------------------------
// k_pe: pew_table[t][d] = (pe[t] @ W_PE)[d] for all 512 timestamps.
// ---------------------------------------------------------------------------
__global__ __launch_bounds__(64) void k_pe(const float* __restrict__ Wpe, float* __restrict__ pewt)
{
  const int t=blockIdx.x, d=threadIdx.x;
  __shared__ float pr[64];
  const float c0 = -logf(10000.f)/32.f;
  float ang = (float)t * expf((float)(d>>1)*c0);
  pr[d] = (d&1)? cosf(ang) : sinf(ang);
  __syncthreads();
  float a=0.f;
  #pragma unroll 8
  for(int j=0;j<64;j++) a += pr[j]*Wpe[j*64+d];
  pewt[t*64+d]=a;
}

// ---------------------------------------------------------------------------
// k_prep: pre-pack Wgat / Wo / a_src,a_dst / Wassign / Wpred into bf16
// MFMA B-frag layouts.
// ---------------------------------------------------------------------------
__global__ __launch_bounds__(256) void k_prep(
    const float* __restrict__ Wg, const float* __restrict__ Wo,
    const float* __restrict__ as_, const float* __restrict__ ad_,
    const float* __restrict__ Wassign, const float* __restrict__ Wpred,
    short* __restrict__ wgb, short* __restrict__ wob, short* __restrict__ asb,
    short* __restrict__ wab, short* __restrict__ wpb)
{
  int i = blockIdx.x*256+threadIdx.x;           // 0..16383
  {
    int j=i&7, lane=(i>>3)&63, ks=(i>>9)&1, nt=(i>>10)&3, h=(i>>12)&3;
    int c=lane&15, q=lane>>4;
    int k=ks*32+q*8+j;
    wgb[i] = f2bs(Wg[h*4096 + k*64 + nt*16 + c]);
    wob[i] = f2bs(Wo[(size_t)(h*64 + k)*64 + nt*16 + c]);
  }
  if(i<4096){
    int j=i&7, lane=(i>>3)&63, ks=(i>>9)&1, h=(i>>10)&3;
    int c=lane&15, q=lane>>4; int k=ks*32+q*8+j;
    float v = (c==0)? as_[h*64+k] : (c==1? ad_[h*64+k] : 0.f);
    asb[i]=f2bs(v);
  }
  if(i<1024){   // W_assign B-frag: 64x10 (cols padded to 16)
    int j=i&7, lane=(i>>3)&63, ks=(i>>9)&1;
    int c=lane&15, q=lane>>4; int k=ks*32+q*8+j;
    wab[i] = (c<10)? f2bs(Wassign[k*10+c]) : (short)0;
  }
  if(i<8192){   // W_pred B-frag: 128x64, [nt][ks=0..3][lane][8]
    int j=i&7, lane=(i>>3)&63, ks=(i>>9)&3, nt=(i>>11)&3;
    int c=lane&15, q=lane>>4; int k=ks*32+q*8+j;
    wpb[i] = f2bs(Wpred[k*64 + nt*16 + c]);
  }
}

// ---------------------------------------------------------------------------
// kmain: whole per-batch chain.  wave = head.
// LDS arena 53248 B:
//  [0..36864)     PP[4] stride 9216 (sbF 2000B overlay pre-GAT; xnl/lF/lI overlay post)
//  [36864..44064) xs bf16 50 rows x stride 72 shorts (ubA 16x272B overlay in loss phase)
//  [44064..47136) es/ed/inv per head (768 each)
//  [47136..48160) part[256]
//  [48160..49440) cnd f32[320]
//  [49440..52000) xpl f32[640]
//  [52000..52256) uFvec[64]   [52256..52512) uacc[64]
//  [52512..53024) ints + sc/sIv/sFv/cnv/un
// ---------------------------------------------------------------------------
__global__ __launch_bounds__(256,3) void kmain(
    const float* __restrict__ emb, const float* __restrict__ pewt,
    const int* __restrict__ history, const int* __restrict__ timestp,
    const int* __restrict__ pos_id, const int* __restrict__ neg_id, const int* __restrict__ stp,
    const float* __restrict__ adj,
    const short* __restrict__ wgb, const short* __restrict__ wob, const short* __restrict__ asb,
    const short* __restrict__ wab, const short* __restrict__ wpb,
    float* __restrict__ reg_part, float* __restrict__ ent_part,
    float* __restrict__ loss_part, float* __restrict__ con_part)
{
  const int b=blockIdx.x, tid=threadIdx.x;
  const int h=tid>>6, lane=tid&63;
  const int c=lane&15, q=lane>>4;

  __shared__ __align__(16) char arena[53248];
  char*  PP    = arena + h*9216;
  short* xs_s  = (short*)(arena+36864);
  float* es_f  = (float*)(arena+44064 + h*768);
  float* ed_f  = es_f + 64;
  float* inv_f = es_f + 128;
  float* part  = (float*)(arena+47136);
  float* cndF  = (float*)(arena+48160);
  float* xplF  = (float*)(arena+49440);
  float* uFvec = (float*)(arena+52000);
  float* uacc  = (float*)(arena+52256);
  int*   hist  = (int*)(arena+52512);
  int*   tvals = (int*)(arena+52712);
  int*   ids   = (int*)(arena+52912);
  int*   stv   = (int*)(arena+52932);
  float* scF   = (float*)(arena+52936);
  float* sIv   = scF+5;
  float* sFv   = scF+10;
  float* cnv   = scF+15;
  float* un    = scF+20;
  float* sbF   = (float*)arena;            // 500 f32, overlays PP head0 pre-GAT

  // ---- P0: int loads + adj ballot masks (latency-tolerant, all waves) ----
  if (tid < 50) hist[tid] = history[b*50+tid];
  if (tid >= 64 && tid < 114) tvals[tid-64] = timestp[b*50+(tid-64)];
  if (tid == 128) stv[0] = stp[b];
  if (tid == 129) ids[0] = pos_id[b];
  if (tid >= 130 && tid < 134) ids[tid-129] = neg_id[b*4+(tid-130)];

  unsigned long long mymask=0ULL;
  {
    const float* adjb = adj + (size_t)b*2500;
    for(int n=0;n<50;n++){
      float av = (lane<50)? adjb[n*50+lane] : 0.f;
      unsigned long long mk = __ballot(av>0.f);
      if(lane==n) mymask = mk;
    }
  }
  __syncthreads();                               // A0: ints ready

  // ---- P1: gather -> xs bf16 (stride 72), cnd f32; reg partial ----
  float regp=0.f;
  for (int i=tid;i<3200;i+=256){
    int n=i>>6, d=i&63;
    float ev=emb[(size_t)hist[n]*64 + d];
    regp += ev*ev;
    float v = (hist[n]>0) ? (ev + pewt[tvals[n]*64+d]) : 0.f;
    xs_s[n*72+d]=f2bs(v);
  }
  for (int i=tid;i<320;i+=256){
    int cc=i>>6, d=i&63;
    float ev=emb[(size_t)ids[cc]*64+d];
    regp += ev*ev;
    cndF[i]=ev + pewt[stv[0]*64+d];
  }
  #pragma unroll
  for(int m=1;m<64;m<<=1) regp += __shfl_xor(regp,m,64);
  if(lane==0) part[h]=regp;
  __syncthreads();                               // A: xs/cnd ready

  // ---- P2: A-frags of X + logits MFMA (wave h -> row tile h) ----
  sv8 af[4][2];
  #pragma unroll
  for(int mt=0;mt<4;mt++){
    int r = mt*16 + c; if(r>=50) r=0;
    #pragma unroll
    for(int ks=0;ks<2;ks++)
      af[mt][ks] = *(const sv8*)(xs_s + r*72 + ks*32 + q*8);
  }
  {
    sv8 wa0 = *(const sv8*)(wab + (0*64+lane)*8);
    sv8 wa1 = *(const sv8*)(wab + (1*64+lane)*8);
    fv4 acc={0.f,0.f,0.f,0.f};
    acc = MFMA(af[h][0], wa0, acc);
    acc = MFMA(af[h][1], wa1, acc);
    #pragma unroll
    for(int reg=0;reg<4;reg++){
      int n=16*h+4*q+reg;
      if(n<50 && c<10) sbF[n*10+c]=acc[reg];
    }
  }
  __syncthreads();                               // B: sbF ready
  if(tid==0) reg_part[b]=part[0]+part[1]+part[2]+part[3];

  // ---- P3a: softmax s (k=10) + entropy (wave 0) ----
  float entp=0.f;
  if (tid<50){
    float mx=-1e30f;
    for(int k=0;k<10;k++) mx=fmaxf(mx, sbF[tid*10+k]);
    float e[10], sm=0.f;
    for(int k=0;k<10;k++){ e[k]=expf(sbF[tid*10+k]-mx); sm+=e[k]; }
    float inv=1.f/sm;
    for(int k=0;k<10;k++){ float sv=e[k]*inv; sbF[tid*10+k]=sv; entp += sv*logf(sv); }
  }
  if(h==0){
    #pragma unroll
    for(int m=1;m<64;m<<=1) entp += __shfl_xor(entp,m,64);
    if(lane==0) ent_part[b]=entp;
  }
  __syncthreads();                               // C: s normalized

  // ---- P3b: x_parent MFMA (wave h -> col tile h) ----
  {
    sv8 sa[2], sxb[2];
    #pragma unroll
    for(int ks=0;ks<2;ks++){
      U8 ua, ub_;
      #pragma unroll
      for(int t2=0;t2<4;t2++){
        int n0=32*ks+8*q+2*t2, n1=n0+1;
        short lo=(n0<50 && c<10)? f2bs(sbF[n0*10+c]) : (short)0;
        short hi=(n1<50 && c<10)? f2bs(sbF[n1*10+c]) : (short)0;
        ua.i[t2]=pk2s(lo,hi);
        short lo2=(n0<50)? xs_s[n0*72+16*h+c] : (short)0;
        short hi2=(n1<50)? xs_s[n1*72+16*h+c] : (short)0;
        ub_.i[t2]=pk2s(lo2,hi2);
      }
      sa[ks]=ua.v; sxb[ks]=ub_.v;
    }
    fv4 acc={0.f,0.f,0.f,0.f};
    acc = MFMA(sa[0], sxb[0], acc);
    acc = MFMA(sa[1], sxb[1], acc);
    #pragma unroll
    for(int reg=0;reg<4;reg++){
      int k=4*q+reg;
      if(k<10) xplF[k*64+16*h+c]=acc[reg];
    }
  }
  __syncthreads();                               // D: xpl ready, sbF dead
  if(tid<64){
    float a=0.f;
    for(int k=0;k<10;k++) a += xplF[(k<<6)+tid];
    uFvec[tid]=a*0.1f;
  }

  // ---- P4: GAT (same as R7, af from LDS) ----
  int wh_pk[4][4][2];
  #pragma unroll
  for(int nt=0;nt<4;nt++){
    sv8 b0 = *(const sv8*)(wgb + (((h*4+nt)*2+0)*64 + lane)*8);
    sv8 b1 = *(const sv8*)(wgb + (((h*4+nt)*2+1)*64 + lane)*8);
    #pragma unroll
    for(int mt=0;mt<4;mt++){
      fv4 acc={0.f,0.f,0.f,0.f};
      acc = MFMA(af[mt][0], b0, acc);
      acc = MFMA(af[mt][1], b1, acc);
      wh_pk[mt][nt][0]=pk2(acc[0],acc[1]);
      wh_pk[mt][nt][1]=pk2(acc[2],acc[3]);
    }
  }
  {
    sv8 a5b0 = *(const sv8*)(asb + ((h*2+0)*64 + lane)*8);
    sv8 a5b1 = *(const sv8*)(asb + ((h*2+1)*64 + lane)*8);
    #pragma unroll
    for(int mt=0;mt<4;mt++){
      fv4 acc={0.f,0.f,0.f,0.f};
      acc = MFMA(af[mt][0], a5b0, acc);
      acc = MFMA(af[mt][1], a5b1, acc);
      if(c==0){
        #pragma unroll
        for(int reg=0;reg<4;reg++) es_f[mt*16+4*q+reg]=acc[reg];
      } else if(c==1){
        #pragma unroll
        for(int reg=0;reg<4;reg++) ed_f[mt*16+4*q+reg]=acc[reg];
      }
    }
  }
  // per-lane softmax into PP
  {
    float es_n = es_f[lane];
    float mx=-1e9f;
    #pragma unroll
    for(int m=0;m<50;m++){
      float z = es_n + ed_f[m];
      float lr = (z>0.f)? z : 0.2f*z;
      float e = ((mymask>>m)&1ULL)? lr : -1e9f;
      mx = fmaxf(mx,e);
    }
    float sum=0.f;
    #pragma unroll
    for(int mb=0;mb<48;mb+=4){
      sv4 wv;
      #pragma unroll
      for(int jj=0;jj<4;jj++){
        int m=mb+jj;
        float z = es_n + ed_f[m];
        float lr = (z>0.f)? z : 0.2f*z;
        float e = ((mymask>>m)&1ULL)? lr : -1e9f;
        float p = (lane<50)? expf(e-mx) : 0.f;
        wv[jj]=f2bs(p); sum+=p;
      }
      *(sv4*)(PP + lane*144 + mb*2) = wv;
    }
    {
      sv4 wv={0,0,0,0};
      #pragma unroll
      for(int jj=0;jj<2;jj++){
        int m=48+jj;
        float z = es_n + ed_f[m];
        float lr = (z>0.f)? z : 0.2f*z;
        float e = ((mymask>>m)&1ULL)? lr : -1e9f;
        float p = (lane<50)? expf(e-mx) : 0.f;
        wv[jj]=f2bs(p); sum+=p;
      }
      *(sv4*)(PP + lane*144 + 48*2) = wv;
    }
    sv4 zz={0,0,0,0};
    *(sv4*)(PP + lane*144 + 52*2) = zz;
    *(sv4*)(PP + lane*144 + 56*2) = zz;
    *(sv4*)(PP + lane*144 + 60*2) = zz;
    inv_f[lane] = (lane<50)? 1.f/sum : 0.f;
  }
  // matmul2: O = Praw @ Wh (shuffle-transposed Wh B-frags)
  {
    sv8 ap[4][2];
    #pragma unroll
    for(int mt=0;mt<4;mt++)
      #pragma unroll
      for(int ks=0;ks<2;ks++)
        ap[mt][ks] = *(const sv8*)(PP + (mt*16+c)*144 + (ks*32+q*8)*2);
    float invr[16];
    #pragma unroll
    for(int mt=0;mt<4;mt++)
      #pragma unroll
      for(int reg=0;reg<4;reg++) invr[mt*4+reg]=inv_f[mt*16+4*q+reg];

    const int L = c + ((q&1)<<5);
    const bool hi = (q>>1)!=0;
    #pragma unroll
    for(int nt=0;nt<4;nt++){
      sv8 bfr[2];
      #pragma unroll
      for(int ks=0;ks<2;ks++){
        int a0=__shfl(wh_pk[2*ks+0][nt][0],L,64), b0=__shfl(wh_pk[2*ks+1][nt][0],L,64);
        int a1=__shfl(wh_pk[2*ks+0][nt][1],L,64), b1=__shfl(wh_pk[2*ks+1][nt][1],L,64);
        int a2=__shfl(wh_pk[2*ks+0][nt][0],L+16,64), b2=__shfl(wh_pk[2*ks+1][nt][0],L+16,64);
        int a3=__shfl(wh_pk[2*ks+0][nt][1],L+16,64), b3=__shfl(wh_pk[2*ks+1][nt][1],L+16,64);
        U8 u;
        u.i[0]=hi?b0:a0; u.i[1]=hi?b1:a1; u.i[2]=hi?b2:a2; u.i[3]=hi?b3:a3;
        bfr[ks]=u.v;
      }
      #pragma unroll
      for(int mt=0;mt<4;mt++){
        fv4 acc={0.f,0.f,0.f,0.f};
        acc = MFMA(ap[mt][0], bfr[0], acc);
        acc = MFMA(ap[mt][1], bfr[1], acc);
        #pragma unroll
        for(int reg=0;reg<4;reg++)
          *(short*)(PP + (mt*16+4*q+reg)*144 + (nt*16+c)*2) = f2bs(acc[reg]*invr[mt*4+reg]);
      }
    }
  }
  // matmul3: partial = O @ Wo_h
  {
    sv8 ao[4][2];
    #pragma unroll
    for(int mt=0;mt<4;mt++)
      #pragma unroll
      for(int ks=0;ks<2;ks++)
        ao[mt][ks] = *(const sv8*)(PP + (mt*16+c)*144 + (ks*32+q*8)*2);
    #pragma unroll
    for(int nt=0;nt<4;nt++){
      sv8 bfr[2];
      #pragma unroll
      for(int ks=0;ks<2;ks++)
        bfr[ks] = *(const sv8*)(wob + (((h*4+nt)*2+ks)*64 + lane)*8);
      #pragma unroll
      for(int mt=0;mt<4;mt++){
        fv4 acc={0.f,0.f,0.f,0.f};
        acc = MFMA(ao[mt][0], bfr[0], acc);
        acc = MFMA(ao[mt][1], bfr[1], acc);
        #pragma unroll
        for(int reg=0;reg<4;reg++)
          *(short*)(PP + (mt*16+4*q+reg)*144 + (nt*16+c)*2) = f2bs(acc[reg]);
      }
    }
  }
  __syncthreads();                               // E: partials ready

  // ---- P5: cross-head sum -> elu (regs) ----
  float ve[13];
  float up=0.f;
  {
    int ii=0;
    for(int i=tid;i<3200;i+=256,ii++){
      int n=i>>6, d=i&63;
      float v=0.f;
      #pragma unroll
      for(int hh=0;hh<4;hh++)
        v += bs2f(*(const short*)(arena + hh*9216 + n*144 + d*2));
      v = (v>0.f)? v : expm1f(v);
      ve[ii]=v; up+=v;
    }
  }
  part[tid]=up;
  __syncthreads();                               // F: PP reads done

  // ---- loss overlays ----
  float* xnl =(float*)arena;                     // 3200 f32
  float* lF  =(float*)(arena+12800);             // 50
  float* lI  =(float*)(arena+13000);             // 250
  short* ubA =(short*)(arena+36864);             // 16 rows x 136 shorts (272B stride)

  {
    int ii=0;
    for(int i=tid;i<3200;i+=256,ii++) xnl[i]=ve[ii];
  }
  if(tid<64) uacc[tid]=(part[tid]+part[64+tid]+part[128+tid]+part[192+tid])*0.02f;
  __syncthreads();                               // G: xnl/uacc ready

  // 300 wave-dots -> lF/lI
  for(int idx=h; idx<300; idx+=4){
    float s;
    if(idx<50){
      int k=idx%10, cc=idx/10;
      s = xplF[(k<<6)+lane]*cndF[(cc<<6)+lane];
    } else {
      int t2=idx-50; int cc=t2/50, n2=t2-cc*50;
      s = xnl[(n2<<6)+lane]*cndF[(cc<<6)+lane];
    }
    #pragma unroll
    for(int m=32;m>0;m>>=1) s += __shfl_xor(s,m,64);
    if(lane==0){ if(idx<50) lF[idx]=s; else lI[idx-50]=s; }
  }
  __syncthreads();                               // H: logits ready

  // wave-parallel softmax of lF/lI rows
  for(int cc=h; cc<5; cc+=4){
    float v = (lane<50)? lI[cc*50+lane] : -1e30f;
    float mx=v;
    #pragma unroll
    for(int m=32;m>0;m>>=1) mx=fmaxf(mx,__shfl_xor(mx,m,64));
    float e=(lane<50)? expf(v-mx):0.f;
    float sm=e;
    #pragma unroll
    for(int m=32;m>0;m>>=1) sm+=__shfl_xor(sm,m,64);
    if(lane<50) lI[cc*50+lane]=e/sm;
    float v2=(lane<10)? lF[cc*10+lane] : -1e30f;
    float mx2=v2;
    #pragma unroll
    for(int m=32;m>0;m>>=1) mx2=fmaxf(mx2,__shfl_xor(mx2,m,64));
    float e2=(lane<10)? expf(v2-mx2):0.f;
    float sm2=e2;
    #pragma unroll
    for(int m=32;m>0;m>>=1) sm2+=__shfl_xor(sm2,m,64);
    if(lane<10) lF[cc*10+lane]=e2/sm2;
  }
  __syncthreads();                               // I: attn normalized

  // uF/uI aggregate -> ubA (bf16 A-layout rows cc, K=128)
  for(int i=tid;i<320;i+=256){
    int cc=i>>6, d=i&63;
    float a=0.f;
    for(int k=0;k<10;k++) a += lF[cc*10+k]*xplF[(k<<6)+d];
    float a2=0.f;
    for(int n2=0;n2<50;n2++) a2 += lI[cc*50+n2]*xnl[(n2<<6)+d];
    ubA[cc*136+d]=f2bs(a);
    ubA[cc*136+64+d]=f2bs(a2);
  }
  for(int i=tid;i<1496;i+=256){                   // zero rows 5..15
    int row=5+i/136, col=i-136*(i/136);
    ubA[row*136+col]=0;
  }
  __syncthreads();                               // J: ubA ready

  // wave0: ub = [uF|uI] @ Wpred via MFMA, scores sc direct from D-layout
  if(h==0){
    sv8 ua[4];
    #pragma unroll
    for(int ks=0;ks<4;ks++)
      ua[ks] = *(const sv8*)(ubA + c*136 + ks*32 + q*8);
    float pr[4]={0.f,0.f,0.f,0.f};
    #pragma unroll
    for(int nt=0;nt<4;nt++){
      fv4 acc={0.f,0.f,0.f,0.f};
      #pragma unroll
      for(int ks=0;ks<4;ks++)
        acc = MFMA(ua[ks], *(const sv8*)(wpb + ((nt*4+ks)*64+lane)*8), acc);
      #pragma unroll
      for(int reg=0;reg<4;reg++){
        int cc=4*q+reg;
        if(cc<5) pr[reg] += acc[reg]*cndF[cc*64+16*nt+c];
      }
    }
    #pragma unroll
    for(int reg=0;reg<4;reg++){
      #pragma unroll
      for(int m=1;m<16;m<<=1) pr[reg]+=__shfl_xor(pr[reg],m,64);
    }
    if(c==0){
      #pragma unroll
      for(int reg=0;reg<4;reg++){
        int cc=4*q+reg;
        if(cc<5) scF[cc]=pr[reg];
      }
    }
  } else {
    // waves 1-3: the 17 small dots
    for(int idx=4+h; idx<22; idx+=3){
      float va, vb;
      if(idx<10){ int cc=idx-5; va=cndF[(cc<<6)+lane]; vb=uacc[lane]; }
      else if(idx<15){ int cc=idx-10; va=cndF[(cc<<6)+lane]; vb=uFvec[lane]; }
      else if(idx<20){ int cc=idx-15; va=cndF[(cc<<6)+lane]; vb=va; }
      else if(idx==20){ va=uacc[lane]; vb=va; }
      else { va=uFvec[lane]; vb=va; }
      float s=va*vb;
      #pragma unroll
      for(int m=32;m>0;m>>=1) s += __shfl_xor(s,m,64);
      if(lane==0){
        if(idx<10) sIv[idx-5]=s;
        else if(idx<15) sFv[idx-10]=s;
        else if(idx<20) cnv[idx-15]=sqrtf(s);
        else un[idx-20]=sqrtf(s);
      }
    }
  }
  __syncthreads();                               // K

  if(tid==0){
    float lp=0.f;
    for(int cc=1;cc<5;cc++){
      float z=scF[cc]-scF[0];
      lp += fmaxf(z,0.f)+log1pf(expf(-fabsf(z)));
    }
    int indF[5], indI[5];
    { bool used[5]={0,0,0,0,0};
      for(int p=0;p<5;p++){ int best=0; float bv=-3e38f;
        for(int cc=0;cc<5;cc++) if(!used[cc]&&sFv[cc]>bv){bv=sFv[cc];best=cc;}
        used[best]=true; indF[p]=best; } }
    { bool used[5]={0,0,0,0,0};
      for(int p=0;p<5;p++){ int best=0; float bv=-3e38f;
        for(int cc=0;cc<5;cc++) if(!used[cc]&&sIv[cc]>bv){bv=sIv[cc];best=cc;}
        used[best]=true; indI[p]=best; } }
    float t1,t2;
    {
      float inv=2.f/un[0];
      float ps=expf(sIv[indF[0]]/cnv[indF[0]]*inv)+expf(sIv[indF[1]]/cnv[indF[1]]*inv);
      float ns=expf(sIv[indF[2]]/cnv[indF[2]]*inv)+expf(sIv[indF[3]]/cnv[indF[3]]*inv);
      t1=log1pf(ns/ps);
    }
    {
      float inv=2.f/un[1];
      float ps=expf(sFv[indI[0]]/cnv[indI[0]]*inv)+expf(sFv[indI[1]]/cnv[indI[1]]*inv);
      float ns=expf(sFv[indI[2]]/cnv[indI[2]]*inv)+expf(sFv[indI[3]]/cnv[indI[3]]*inv);
      t2=log1pf(ns/ps);
    }
    loss_part[b]=lp;
    con_part[b]=t1+t2;
  }
}

// ---------------------------------------------------------------------------
// k3a/k3b: final reductions -> 4 f32 outputs
// ---------------------------------------------------------------------------
__global__ __launch_bounds__(256) void k3a(
    const float* __restrict__ Wpred, const float* __restrict__ Wpe,
    const float* __restrict__ reg_part, const float* __restrict__ ent_part,
    const float* __restrict__ loss_part, const float* __restrict__ con_part,
    float* __restrict__ acc4, float* __restrict__ accW)
{
  const int blk=blockIdx.x, tid=threadIdx.x;
  const int base=blk*256+tid;
  __shared__ float r4[4][4];
  __shared__ float rw[4];
  float v[4]={reg_part[base],ent_part[base],loss_part[base],con_part[base]};
  #pragma unroll
  for(int t2=0;t2<4;t2++){
    float s=v[t2];
    #pragma unroll
    for(int m=1;m<64;m<<=1) s+=__shfl_xor(s,m,64);
    if((tid&63)==0) r4[t2][tid>>6]=s;
  }
  float sw=0.f;
  if(blk==0){
    for(int i=tid;i<8192;i+=256){ float w=Wpred[i]; sw+=w*w; }
    for(int i=tid;i<4096;i+=256){ float w=Wpe[i]; sw+=w*w; }
    #pragma unroll
    for(int m=1;m<64;m<<=1) sw+=__shfl_xor(sw,m,64);
  }
  if((tid&63)==0) rw[tid>>6]=sw;
  __syncthreads();
  if(tid==0){
    for(int t2=0;t2<4;t2++) acc4[blk*4+t2]=r4[t2][0]+r4[t2][1]+r4[t2][2]+r4[t2][3];
    if(blk==0) accW[0]=rw[0]+rw[1]+rw[2]+rw[3];
  }
}

__global__ __launch_bounds__(64) void k3b(
    const float* __restrict__ acc4, const float* __restrict__ accW, float* __restrict__ out)
{
  const int t=threadIdx.x;
  const int cdx=t>>4, i=t&15;
  __shared__ float tot[4];
  float v=acc4[i*4+cdx];
  #pragma unroll
  for(int m=1;m<16;m<<=1) v+=__shfl_xor(v,m,64);
  if(i==0) tot[cdx]=v;
  __syncthreads();
  if(t==0){
    out[0]=tot[2]/(4096.f*4.f);          // loss
    out[1]=tot[0]/4096.f + accW[0];      // loss_reg
    out[2]=-tot[1]/(50.f*4096.f);        // loss_entropy
    out[3]=tot[3]/4096.f;                // loss_con
  }
}

extern "C" void kernel_launch(void* const* d_in, const int* in_sizes, int n_in,
                              void* d_out, int out_size, void* d_ws, size_t ws_size,
                              hipStream_t stream)
{
  const float* emb     =(const float*)d_in[0];
  const float* Wpe     =(const float*)d_in[1];
  const float* Wpred   =(const float*)d_in[2];
  const float* Wgat    =(const float*)d_in[3];
  const float* a_src   =(const float*)d_in[4];
  const float* a_dst   =(const float*)d_in[5];
  const float* Wo      =(const float*)d_in[6];
  const float* Wassign =(const float*)d_in[7];
  const float* adj     =(const float*)d_in[8];
  const int* history  =(const int*)d_in[9];
  const int* timestp  =(const int*)d_in[10];
  const int* pos_id   =(const int*)d_in[11];
  const int* neg_id   =(const int*)d_in[12];
  const int* stp      =(const int*)d_in[13];
  float* out=(float*)d_out;

  char* ws=(char*)d_ws;
  float* reg_part =(float*)(ws+0);
  float* ent_part =(float*)(ws+16384);
  float* loss_part=(float*)(ws+32768);
  float* con_part =(float*)(ws+49152);
  float* acc4     =(float*)(ws+65536);
  float* accW     =(float*)(ws+65792);
  float* pewt     =(float*)(ws+66048);           // 512*64 f32 -> ends 197120
  short* wgb      =(short*)(ws+197120);          // 32768 B
  short* wob      =(short*)(ws+229888);          // 32768 B
  short* asb      =(short*)(ws+262656);          // 8192 B
  short* wab      =(short*)(ws+270848);          // 2048 B
  short* wpb      =(short*)(ws+272896);          // 16384 B -> ends 289280

  k_pe<<<512,64,0,stream>>>(Wpe,pewt);
  k_prep<<<64,256,0,stream>>>(Wgat,Wo,a_src,a_dst,Wassign,Wpred,wgb,wob,asb,wab,wpb);
  kmain<<<4096,256,0,stream>>>(emb,pewt,history,timestp,pos_id,neg_id,stp,adj,
                               wgb,wob,asb,wab,wpb,reg_part,ent_part,loss_part,con_part);
  k3a<<<16,256,0,stream>>>(Wpred,Wpe,reg_part,ent_part,loss_part,con_part,acc4,accW);
  k3b<<<1,64,0,stream>>>(acc4,accW,out);
}

// Round 9
// 486.585 us; speedup vs baseline: 4.3693x; 1.2247x over previous
//
#include <hip/hip_runtime.h>
#include <hip/hip_bf16.h>
#include <math.h>

typedef __hip_bfloat16 bf16;
typedef __attribute__((ext_vector_type(8))) short sv8;   // 8 bf16 = 4 VGPR (MFMA A/B frag)
typedef __attribute__((ext_vector_type(4))) short sv4;   // 4 bf16 = 2 VGPR
typedef __attribute__((ext_vector_type(4))) float fv4;   // MFMA C/D frag

__device__ __forceinline__ float b2f(bf16 v){ return __bfloat162float(v); }
__device__ __forceinline__ bf16  f2b(float v){ return __float2bfloat16(v); }
__device__ __forceinline__ short f2bs(float v){ bf16 h=__float2bfloat16(v); short s; __builtin_memcpy(&s,&h,2); return s; }
__device__ __forceinline__ float bs2f(short s){ bf16 h; __builtin_memcpy(&h,&s,2); return __bfloat162float(h); }
__device__ __forceinline__ fv4 MFMA(sv8 a, sv8 b, fv4 c){
  return __builtin_amdgcn_mfma_f32_16x16x32_bf16(a,b,c,0,0,0);
}
__device__ __forceinline__ int pk2(float a, float b){
  unsigned sa=(unsigned short)f2bs(a);
  unsigned sb=((unsigned)(unsigned short)f2bs(b))<<16;
  return (int)(sa|sb);
}
__device__ __forceinline__ int pk2s(short a, short b){
  return (int)(((unsigned short)a) | (((unsigned)(unsigned short)b)<<16));
}
union U8 { int i[4]; sv8 v; };

// ---------------------------------------------------------------------------
// k_pe: pew_table[t][d] = (pe[t] @ W_PE)[d] for all 512 timestamps.
// ---------------------------------------------------------------------------
__global__ __launch_bounds__(64) void k_pe(const float* __restrict__ Wpe, float* __restrict__ pewt)
{
  const int t=blockIdx.x, d=threadIdx.x;
  __shared__ float pr[64];
  const float c0 = -logf(10000.f)/32.f;
  float ang = (float)t * expf((float)(d>>1)*c0);
  pr[d] = (d&1)? cosf(ang) : sinf(ang);
  __syncthreads();
  float a=0.f;
  #pragma unroll 8
  for(int j=0;j<64;j++) a += pr[j]*Wpe[j*64+d];
  pewt[t*64+d]=a;
}

// ---------------------------------------------------------------------------
// k_prep: pre-pack Wgat / Wo / a_src,a_dst / Wassign / Wpred into bf16
// MFMA B-frag layouts.
// ---------------------------------------------------------------------------
__global__ __launch_bounds__(256) void k_prep(
    const float* __restrict__ Wg, const float* __restrict__ Wo,
    const float* __restrict__ as_, const float* __restrict__ ad_,
    const float* __restrict__ Wassign, const float* __restrict__ Wpred,
    short* __restrict__ wgb, short* __restrict__ wob, short* __restrict__ asb,
    short* __restrict__ wab, short* __restrict__ wpb)
{
  int i = blockIdx.x*256+threadIdx.x;           // 0..16383
  {
    int j=i&7, lane=(i>>3)&63, ks=(i>>9)&1, nt=(i>>10)&3, h=(i>>12)&3;
    int c=lane&15, q=lane>>4;
    int k=ks*32+q*8+j;
    wgb[i] = f2bs(Wg[h*4096 + k*64 + nt*16 + c]);
    wob[i] = f2bs(Wo[(size_t)(h*64 + k)*64 + nt*16 + c]);
  }
  if(i<4096){
    int j=i&7, lane=(i>>3)&63, ks=(i>>9)&1, h=(i>>10)&3;
    int c=lane&15, q=lane>>4; int k=ks*32+q*8+j;
    float v = (c==0)? as_[h*64+k] : (c==1? ad_[h*64+k] : 0.f);
    asb[i]=f2bs(v);
  }
  if(i<1024){   // W_assign B-frag: 64x10 (cols padded to 16)
    int j=i&7, lane=(i>>3)&63, ks=(i>>9)&1;
    int c=lane&15, q=lane>>4; int k=ks*32+q*8+j;
    wab[i] = (c<10)? f2bs(Wassign[k*10+c]) : (short)0;
  }
  if(i<8192){   // W_pred B-frag: 128x64, [nt][ks=0..3][lane][8]
    int j=i&7, lane=(i>>3)&63, ks=(i>>9)&3, nt=(i>>11)&3;
    int c=lane&15, q=lane>>4; int k=ks*32+q*8+j;
    wpb[i] = f2bs(Wpred[k*64 + nt*16 + c]);
  }
}

// ---------------------------------------------------------------------------
// kmain: whole per-batch chain. wave = head. Arena 36864 B -> 4 blocks/CU.
//  [0..28800)     PP[4] stride 7200 (50 rows x 144 B)
//                 overlays pre-GAT: sbF 2000B @0 ; xs_s 7200B @14400
//                 overlays loss:    xnl 12800 @0 ; lF @12800 ; lI @13000 ;
//                                   ubA 4352 @14400 ; xnlb 7200 @18752
//  [28800..31872) es/ed/inv per head (768 each)
//  [31872..33152) cndF f32[320]
//  [33152..35712) xplF f32[640]
//  [35712..35968) uFvec[64]   [35968..36224) uacc[64]
//  [36224..36864) ints + ph[4] + sc/sIv/sFv/cnv/un
// ---------------------------------------------------------------------------
__global__ __launch_bounds__(256,4) void kmain(
    const float* __restrict__ emb, const float* __restrict__ pewt,
    const int* __restrict__ history, const int* __restrict__ timestp,
    const int* __restrict__ pos_id, const int* __restrict__ neg_id, const int* __restrict__ stp,
    const float* __restrict__ adj,
    const short* __restrict__ wgb, const short* __restrict__ wob, const short* __restrict__ asb,
    const short* __restrict__ wab, const short* __restrict__ wpb,
    float* __restrict__ reg_part, float* __restrict__ ent_part,
    float* __restrict__ loss_part, float* __restrict__ con_part)
{
  const int b=blockIdx.x, tid=threadIdx.x;
  const int h=tid>>6, lane=tid&63;
  const int c=lane&15, q=lane>>4;

  __shared__ __align__(16) char arena[36864];
  char*  PP    = arena + h*7200;
  short* xs_s  = (short*)(arena+14400);          // overlay on PP h2
  float* es_f  = (float*)(arena+28800 + h*768);
  float* ed_f  = es_f + 64;
  float* inv_f = es_f + 128;
  float* cndF  = (float*)(arena+31872);
  float* xplF  = (float*)(arena+33152);
  float* uFvec = (float*)(arena+35712);
  float* uacc  = (float*)(arena+35968);
  int*   hist  = (int*)(arena+36224);
  int*   tvals = (int*)(arena+36424);
  int*   ids   = (int*)(arena+36624);
  int*   stv   = (int*)(arena+36644);
  float* ph    = (float*)(arena+36648);          // 4 floats
  float* scF   = (float*)(arena+36664);
  float* sIv   = scF+5;
  float* sFv   = scF+10;
  float* cnv   = scF+15;
  float* un    = scF+20;
  float* sbF   = (float*)arena;                  // 500 f32 overlay on PP h0

  // ---- P0: int loads + adj ballot masks ----
  if (tid < 50) hist[tid] = history[b*50+tid];
  if (tid >= 64 && tid < 114) tvals[tid-64] = timestp[b*50+(tid-64)];
  if (tid == 128) stv[0] = stp[b];
  if (tid == 129) ids[0] = pos_id[b];
  if (tid >= 130 && tid < 134) ids[tid-129] = neg_id[b*4+(tid-130)];

  unsigned long long mymask=0ULL;
  {
    const float* adjb = adj + (size_t)b*2500;
    for(int n=0;n<50;n++){
      float av = (lane<50)? adjb[n*50+lane] : 0.f;
      unsigned long long mk = __ballot(av>0.f);
      if(lane==n) mymask = mk;
    }
  }
  __syncthreads();                               // A0: ints ready

  // ---- P1: gather -> xs bf16 (stride 72), cnd f32; reg partial ----
  float regp=0.f;
  for (int i=tid;i<3200;i+=256){
    int n=i>>6, d=i&63;
    float ev=emb[(size_t)hist[n]*64 + d];
    regp += ev*ev;
    float v = (hist[n]>0) ? (ev + pewt[tvals[n]*64+d]) : 0.f;
    xs_s[n*72+d]=f2bs(v);
  }
  for (int i=tid;i<320;i+=256){
    int cc=i>>6, d=i&63;
    float ev=emb[(size_t)ids[cc]*64+d];
    regp += ev*ev;
    cndF[i]=ev + pewt[stv[0]*64+d];
  }
  #pragma unroll
  for(int m=1;m<64;m<<=1) regp += __shfl_xor(regp,m,64);
  if(lane==0) ph[h]=regp;
  __syncthreads();                               // A: xs/cnd ready

  // ---- P2: A-frags of X + logits MFMA (wave h -> row tile h) ----
  sv8 af[4][2];
  #pragma unroll
  for(int mt=0;mt<4;mt++){
    int r = mt*16 + c; if(r>=50) r=0;
    #pragma unroll
    for(int ks=0;ks<2;ks++)
      af[mt][ks] = *(const sv8*)(xs_s + r*72 + ks*32 + q*8);
  }
  {
    sv8 wa0 = *(const sv8*)(wab + (0*64+lane)*8);
    sv8 wa1 = *(const sv8*)(wab + (1*64+lane)*8);
    fv4 acc={0.f,0.f,0.f,0.f};
    acc = MFMA(af[h][0], wa0, acc);
    acc = MFMA(af[h][1], wa1, acc);
    #pragma unroll
    for(int reg=0;reg<4;reg++){
      int n=16*h+4*q+reg;
      if(n<50 && c<10) sbF[n*10+c]=acc[reg];
    }
  }
  __syncthreads();                               // B: sbF ready
  if(tid==0) reg_part[b]=ph[0]+ph[1]+ph[2]+ph[3];

  // ---- P3a: softmax s (k=10) + entropy ----
  float entp=0.f;
  if (tid<50){
    float mx=-1e30f;
    for(int k=0;k<10;k++) mx=fmaxf(mx, sbF[tid*10+k]);
    float e[10], sm=0.f;
    for(int k=0;k<10;k++){ e[k]=expf(sbF[tid*10+k]-mx); sm+=e[k]; }
    float inv=1.f/sm;
    for(int k=0;k<10;k++){ float sv=e[k]*inv; sbF[tid*10+k]=sv; entp += sv*logf(sv); }
  }
  if(h==0){
    #pragma unroll
    for(int m=1;m<64;m<<=1) entp += __shfl_xor(entp,m,64);
    if(lane==0) ent_part[b]=entp;
  }
  __syncthreads();                               // C: s normalized

  // ---- P3b: x_parent MFMA (wave h -> col tile h) ----
  {
    sv8 sa[2], sxb[2];
    #pragma unroll
    for(int ks=0;ks<2;ks++){
      U8 ua, ub_;
      #pragma unroll
      for(int t2=0;t2<4;t2++){
        int n0=32*ks+8*q+2*t2, n1=n0+1;
        short lo=(n0<50 && c<10)? f2bs(sbF[n0*10+c]) : (short)0;
        short hi=(n1<50 && c<10)? f2bs(sbF[n1*10+c]) : (short)0;
        ua.i[t2]=pk2s(lo,hi);
        short lo2=(n0<50)? xs_s[n0*72+16*h+c] : (short)0;
        short hi2=(n1<50)? xs_s[n1*72+16*h+c] : (short)0;
        ub_.i[t2]=pk2s(lo2,hi2);
      }
      sa[ks]=ua.v; sxb[ks]=ub_.v;
    }
    fv4 acc={0.f,0.f,0.f,0.f};
    acc = MFMA(sa[0], sxb[0], acc);
    acc = MFMA(sa[1], sxb[1], acc);
    #pragma unroll
    for(int reg=0;reg<4;reg++){
      int k=4*q+reg;
      if(k<10) xplF[k*64+16*h+c]=acc[reg];
    }
  }
  __syncthreads();                               // D: xpl ready; sbF/xs_s dead
  if(tid<64){
    float a=0.f;
    for(int k=0;k<10;k++) a += xplF[(k<<6)+tid];
    uFvec[tid]=a*0.1f;
  }

  // ---- P4: GAT ----
  int wh_pk[4][4][2];
  #pragma unroll
  for(int nt=0;nt<4;nt++){
    sv8 b0 = *(const sv8*)(wgb + (((h*4+nt)*2+0)*64 + lane)*8);
    sv8 b1 = *(const sv8*)(wgb + (((h*4+nt)*2+1)*64 + lane)*8);
    #pragma unroll
    for(int mt=0;mt<4;mt++){
      fv4 acc={0.f,0.f,0.f,0.f};
      acc = MFMA(af[mt][0], b0, acc);
      acc = MFMA(af[mt][1], b1, acc);
      wh_pk[mt][nt][0]=pk2(acc[0],acc[1]);
      wh_pk[mt][nt][1]=pk2(acc[2],acc[3]);
    }
  }
  {
    sv8 a5b0 = *(const sv8*)(asb + ((h*2+0)*64 + lane)*8);
    sv8 a5b1 = *(const sv8*)(asb + ((h*2+1)*64 + lane)*8);
    #pragma unroll
    for(int mt=0;mt<4;mt++){
      fv4 acc={0.f,0.f,0.f,0.f};
      acc = MFMA(af[mt][0], a5b0, acc);
      acc = MFMA(af[mt][1], a5b1, acc);
      if(c==0){
        #pragma unroll
        for(int reg=0;reg<4;reg++) es_f[mt*16+4*q+reg]=acc[reg];
      } else if(c==1){
        #pragma unroll
        for(int reg=0;reg<4;reg++) ed_f[mt*16+4*q+reg]=acc[reg];
      }
    }
  }
  // single-pass per-lane softmax (row = lane<50): raw exp into PP, invsum
  {
    float es_n = es_f[lane];
    float sum=0.f;
    #pragma unroll
    for(int mb=0;mb<48;mb+=4){
      sv4 wv;
      #pragma unroll
      for(int jj=0;jj<4;jj++){
        int m=mb+jj;
        float z = es_n + ed_f[m];
        float lr = (z>0.f)? z : 0.2f*z;
        float p = ((mymask>>m)&1ULL)? expf(lr) : 0.f;
        wv[jj]=f2bs(p); sum+=p;
      }
      if(lane<50) *(sv4*)(PP + lane*144 + mb*2) = wv;
    }
    {
      sv4 wv={0,0,0,0};
      #pragma unroll
      for(int jj=0;jj<2;jj++){
        int m=48+jj;
        float z = es_n + ed_f[m];
        float lr = (z>0.f)? z : 0.2f*z;
        float p = ((mymask>>m)&1ULL)? expf(lr) : 0.f;
        wv[jj]=f2bs(p); sum+=p;
      }
      if(lane<50){
        *(sv4*)(PP + lane*144 + 48*2) = wv;        // m 48,49 + zero 50,51
        sv4 zz={0,0,0,0};
        *(sv4*)(PP + lane*144 + 52*2) = zz;
        *(sv4*)(PP + lane*144 + 56*2) = zz;
        *(sv4*)(PP + lane*144 + 60*2) = zz;
      }
    }
    inv_f[lane] = (lane<50)? 1.f/sum : 0.f;
  }
  // matmul2: O = Praw @ Wh (Wh B-frags via shuffle transpose), rows<50 written
  {
    sv8 ap[4][2];
    #pragma unroll
    for(int mt=0;mt<4;mt++){
      int r = mt*16+c; if(r>=50) r=0;
      #pragma unroll
      for(int ks=0;ks<2;ks++)
        ap[mt][ks] = *(const sv8*)(PP + r*144 + (ks*32+q*8)*2);
    }
    float invr[16];
    #pragma unroll
    for(int mt=0;mt<4;mt++)
      #pragma unroll
      for(int reg=0;reg<4;reg++) invr[mt*4+reg]=inv_f[mt*16+4*q+reg];

    const int L = c + ((q&1)<<5);
    const bool hi = (q>>1)!=0;
    #pragma unroll
    for(int nt=0;nt<4;nt++){
      sv8 bfr[2];
      #pragma unroll
      for(int ks=0;ks<2;ks++){
        int a0=__shfl(wh_pk[2*ks+0][nt][0],L,64), b0=__shfl(wh_pk[2*ks+1][nt][0],L,64);
        int a1=__shfl(wh_pk[2*ks+0][nt][1],L,64), b1=__shfl(wh_pk[2*ks+1][nt][1],L,64);
        int a2=__shfl(wh_pk[2*ks+0][nt][0],L+16,64), b2=__shfl(wh_pk[2*ks+1][nt][0],L+16,64);
        int a3=__shfl(wh_pk[2*ks+0][nt][1],L+16,64), b3=__shfl(wh_pk[2*ks+1][nt][1],L+16,64);
        U8 u;
        u.i[0]=hi?b0:a0; u.i[1]=hi?b1:a1; u.i[2]=hi?b2:a2; u.i[3]=hi?b3:a3;
        bfr[ks]=u.v;
      }
      #pragma unroll
      for(int mt=0;mt<4;mt++){
        fv4 acc={0.f,0.f,0.f,0.f};
        acc = MFMA(ap[mt][0], bfr[0], acc);
        acc = MFMA(ap[mt][1], bfr[1], acc);
        #pragma unroll
        for(int reg=0;reg<4;reg++){
          int row=mt*16+4*q+reg;
          if(row<50)
            *(short*)(PP + row*144 + (nt*16+c)*2) = f2bs(acc[reg]*invr[mt*4+reg]);
        }
      }
    }
  }
  // matmul3: partial = O @ Wo_h, rows<50 written
  {
    sv8 ao[4][2];
    #pragma unroll
    for(int mt=0;mt<4;mt++){
      int r = mt*16+c; if(r>=50) r=0;
      #pragma unroll
      for(int ks=0;ks<2;ks++)
        ao[mt][ks] = *(const sv8*)(PP + r*144 + (ks*32+q*8)*2);
    }
    #pragma unroll
    for(int nt=0;nt<4;nt++){
      sv8 bfr[2];
      #pragma unroll
      for(int ks=0;ks<2;ks++)
        bfr[ks] = *(const sv8*)(wob + (((h*4+nt)*2+ks)*64 + lane)*8);
      #pragma unroll
      for(int mt=0;mt<4;mt++){
        fv4 acc={0.f,0.f,0.f,0.f};
        acc = MFMA(ao[mt][0], bfr[0], acc);
        acc = MFMA(ao[mt][1], bfr[1], acc);
        #pragma unroll
        for(int reg=0;reg<4;reg++){
          int row=mt*16+4*q+reg;
          if(row<50)
            *(short*)(PP + row*144 + (nt*16+c)*2) = f2bs(acc[reg]);
        }
      }
    }
  }
  __syncthreads();                               // E: partials ready

  // ---- P5a: cross-head sum -> elu (regs) ----
  float ve[13];
  {
    int ii=0;
    for(int i=tid;i<3200;i+=256,ii++){
      int n=i>>6, d=i&63;
      float v=0.f;
      #pragma unroll
      for(int hh=0;hh<4;hh++)
        v += bs2f(*(const short*)(arena + hh*7200 + n*144 + d*2));
      v = (v>0.f)? v : expm1f(v);
      ve[ii]=v;
    }
  }
  __syncthreads();                               // F: PP reads done

  // ---- loss overlays ----
  float* xnl =(float*)arena;                     // 3200 f32
  float* lF  =(float*)(arena+12800);             // 50
  float* lI  =(float*)(arena+13000);             // 250
  short* ubA =(short*)(arena+14400);             // 16 rows x 136 shorts
  short* xnlb=(short*)(arena+18752);             // 50 rows x 72 shorts

  {
    int ii=0;
    for(int i=tid;i<3200;i+=256,ii++){
      int n=i>>6, d=i&63;
      xnl[i]=ve[ii];
      xnlb[n*72+d]=f2bs(ve[ii]);
    }
  }
  __syncthreads();                               // G: xnl/xnlb ready

  if(tid<64){
    float a=0.f;
    #pragma unroll 10
    for(int n=0;n<50;n++) a += xnl[(n<<6)+tid];
    uacc[tid]=a*0.02f;
  }
  // lF: 50 wave-dots
  for(int idx=h; idx<50; idx+=4){
    int k=idx%10, cc=idx/10;
    float s = xplF[(k<<6)+lane]*cndF[(cc<<6)+lane];
    #pragma unroll
    for(int m=32;m>0;m>>=1) s += __shfl_xor(s,m,64);
    if(lane==0) lF[idx]=s;
  }
  // lI: MFMA  (wave h -> rows 16h..16h+15 of xnl @ cnd^T)
  {
    sv8 al[2], bl[2];
    int r = 16*h + c; if(r>=50) r=0;
    #pragma unroll
    for(int ks=0;ks<2;ks++){
      al[ks] = *(const sv8*)(xnlb + r*72 + ks*32 + q*8);
      U8 u;
      #pragma unroll
      for(int t2=0;t2<4;t2++){
        int k0=ks*32+q*8+2*t2, k1=k0+1;
        short lo=(c<5)? f2bs(cndF[c*64+k0]) : (short)0;
        short hi=(c<5)? f2bs(cndF[c*64+k1]) : (short)0;
        u.i[t2]=pk2s(lo,hi);
      }
      bl[ks]=u.v;
    }
    fv4 acc={0.f,0.f,0.f,0.f};
    acc = MFMA(al[0], bl[0], acc);
    acc = MFMA(al[1], bl[1], acc);
    #pragma unroll
    for(int reg=0;reg<4;reg++){
      int row=16*h+4*q+reg;
      if(row<50 && c<5) lI[c*50+row]=acc[reg];
    }
  }
  __syncthreads();                               // H: logits ready

  // wave-parallel softmax of lF/lI rows
  for(int cc=h; cc<5; cc+=4){
    float v = (lane<50)? lI[cc*50+lane] : -1e30f;
    float mx=v;
    #pragma unroll
    for(int m=32;m>0;m>>=1) mx=fmaxf(mx,__shfl_xor(mx,m,64));
    float e=(lane<50)? expf(v-mx):0.f;
    float sm=e;
    #pragma unroll
    for(int m=32;m>0;m>>=1) sm+=__shfl_xor(sm,m,64);
    if(lane<50) lI[cc*50+lane]=e/sm;
    float v2=(lane<10)? lF[cc*10+lane] : -1e30f;
    float mx2=v2;
    #pragma unroll
    for(int m=32;m>0;m>>=1) mx2=fmaxf(mx2,__shfl_xor(mx2,m,64));
    float e2=(lane<10)? expf(v2-mx2):0.f;
    float sm2=e2;
    #pragma unroll
    for(int m=32;m>0;m>>=1) sm2+=__shfl_xor(sm2,m,64);
    if(lane<10) lF[cc*10+lane]=e2/sm2;
  }
  __syncthreads();                               // I: attn normalized

  // uF/uI aggregate -> ubA (bf16 A-layout rows cc, K=128)
  for(int i=tid;i<320;i+=256){
    int cc=i>>6, d=i&63;
    float a=0.f;
    for(int k=0;k<10;k++) a += lF[cc*10+k]*xplF[(k<<6)+d];
    float a2=0.f;
    for(int n2=0;n2<50;n2++) a2 += lI[cc*50+n2]*xnl[(n2<<6)+d];
    ubA[cc*136+d]=f2bs(a);
    ubA[cc*136+64+d]=f2bs(a2);
  }
  for(int i=tid;i<1496;i+=256){                   // zero rows 5..15
    int row=5+i/136, col=i-136*(i/136);
    ubA[row*136+col]=0;
  }
  __syncthreads();                               // J: ubA ready

  if(h==0){
    // wave0: ub = [uF|uI] @ Wpred via MFMA, scores straight from D-layout
    sv8 ua[4];
    #pragma unroll
    for(int ks=0;ks<4;ks++)
      ua[ks] = *(const sv8*)(ubA + c*136 + ks*32 + q*8);
    float pr[4]={0.f,0.f,0.f,0.f};
    #pragma unroll
    for(int nt=0;nt<4;nt++){
      fv4 acc={0.f,0.f,0.f,0.f};
      #pragma unroll
      for(int ks=0;ks<4;ks++)
        acc = MFMA(ua[ks], *(const sv8*)(wpb + ((nt*4+ks)*64+lane)*8), acc);
      #pragma unroll
      for(int reg=0;reg<4;reg++){
        int cc=4*q+reg;
        if(cc<5) pr[reg] += acc[reg]*cndF[cc*64+16*nt+c];
      }
    }
    #pragma unroll
    for(int reg=0;reg<4;reg++){
      #pragma unroll
      for(int m=1;m<16;m<<=1) pr[reg]+=__shfl_xor(pr[reg],m,64);
    }
    if(c==0){
      #pragma unroll
      for(int reg=0;reg<4;reg++){
        int cc=4*q+reg;
        if(cc<5) scF[cc]=pr[reg];
      }
    }
  } else {
    // waves 1-3: the 17 small dots
    for(int idx=4+h; idx<22; idx+=3){
      float va, vb;
      if(idx<10){ int cc=idx-5; va=cndF[(cc<<6)+lane]; vb=uacc[lane]; }
      else if(idx<15){ int cc=idx-10; va=cndF[(cc<<6)+lane]; vb=uFvec[lane]; }
      else if(idx<20){ int cc=idx-15; va=cndF[(cc<<6)+lane]; vb=va; }
      else if(idx==20){ va=uacc[lane]; vb=va; }
      else { va=uFvec[lane]; vb=va; }
      float s=va*vb;
      #pragma unroll
      for(int m=32;m>0;m>>=1) s += __shfl_xor(s,m,64);
      if(lane==0){
        if(idx<10) sIv[idx-5]=s;
        else if(idx<15) sFv[idx-10]=s;
        else if(idx<20) cnv[idx-15]=sqrtf(s);
        else un[idx-20]=sqrtf(s);
      }
    }
  }
  __syncthreads();                               // K

  if(tid==0){
    float lp=0.f;
    for(int cc=1;cc<5;cc++){
      float z=scF[cc]-scF[0];
      lp += fmaxf(z,0.f)+log1pf(expf(-fabsf(z)));
    }
    int indF[5], indI[5];
    { bool used[5]={0,0,0,0,0};
      for(int p=0;p<5;p++){ int best=0; float bv=-3e38f;
        for(int cc=0;cc<5;cc++) if(!used[cc]&&sFv[cc]>bv){bv=sFv[cc];best=cc;}
        used[best]=true; indF[p]=best; } }
    { bool used[5]={0,0,0,0,0};
      for(int p=0;p<5;p++){ int best=0; float bv=-3e38f;
        for(int cc=0;cc<5;cc++) if(!used[cc]&&sIv[cc]>bv){bv=sIv[cc];best=cc;}
        used[best]=true; indI[p]=best; } }
    float t1,t2;
    {
      float inv=2.f/un[0];
      float ps=expf(sIv[indF[0]]/cnv[indF[0]]*inv)+expf(sIv[indF[1]]/cnv[indF[1]]*inv);
      float ns=expf(sIv[indF[2]]/cnv[indF[2]]*inv)+expf(sIv[indF[3]]/cnv[indF[3]]*inv);
      t1=log1pf(ns/ps);
    }
    {
      float inv=2.f/un[1];
      float ps=expf(sFv[indI[0]]/cnv[indI[0]]*inv)+expf(sFv[indI[1]]/cnv[indI[1]]*inv);
      float ns=expf(sFv[indI[2]]/cnv[indI[2]]*inv)+expf(sFv[indI[3]]/cnv[indI[3]]*inv);
      t2=log1pf(ns/ps);
    }
    loss_part[b]=lp;
    con_part[b]=t1+t2;
  }
}

// ---------------------------------------------------------------------------
// k3: single-block final reduction -> 4 f32 outputs
// ---------------------------------------------------------------------------
__global__ __launch_bounds__(256) void k3(
    const float* __restrict__ Wpred, const float* __restrict__ Wpe,
    const float* __restrict__ reg_part, const float* __restrict__ ent_part,
    const float* __restrict__ loss_part, const float* __restrict__ con_part,
    float* __restrict__ out)
{
  const int tid=threadIdx.x, h=tid>>6, lane=tid&63;
  __shared__ float r5[5][4];
  float s[5]={0.f,0.f,0.f,0.f,0.f};
  for(int i=tid;i<4096;i+=256){
    s[0]+=reg_part[i]; s[1]+=ent_part[i]; s[2]+=loss_part[i]; s[3]+=con_part[i];
  }
  for(int i=tid;i<8192;i+=256){ float w=Wpred[i]; s[4]+=w*w; }
  for(int i=tid;i<4096;i+=256){ float w=Wpe[i]; s[4]+=w*w; }
  #pragma unroll
  for(int t2=0;t2<5;t2++){
    float v=s[t2];
    #pragma unroll
    for(int m=1;m<64;m<<=1) v+=__shfl_xor(v,m,64);
    if(lane==0) r5[t2][h]=v;
  }
  __syncthreads();
  if(tid==0){
    float tot[5];
    for(int t2=0;t2<5;t2++) tot[t2]=r5[t2][0]+r5[t2][1]+r5[t2][2]+r5[t2][3];
    out[0]=tot[2]/(4096.f*4.f);          // loss
    out[1]=tot[0]/4096.f + tot[4];       // loss_reg
    out[2]=-tot[1]/(50.f*4096.f);        // loss_entropy
    out[3]=tot[3]/4096.f;                // loss_con
  }
}

extern "C" void kernel_launch(void* const* d_in, const int* in_sizes, int n_in,
                              void* d_out, int out_size, void* d_ws, size_t ws_size,
                              hipStream_t stream)
{
  const float* emb     =(const float*)d_in[0];
  const float* Wpe     =(const float*)d_in[1];
  const float* Wpred   =(const float*)d_in[2];
  const float* Wgat    =(const float*)d_in[3];
  const float* a_src   =(const float*)d_in[4];
  const float* a_dst   =(const float*)d_in[5];
  const float* Wo      =(const float*)d_in[6];
  const float* Wassign =(const float*)d_in[7];
  const float* adj     =(const float*)d_in[8];
  const int* history  =(const int*)d_in[9];
  const int* timestp  =(const int*)d_in[10];
  const int* pos_id   =(const int*)d_in[11];
  const int* neg_id   =(const int*)d_in[12];
  const int* stp      =(const int*)d_in[13];
  float* out=(float*)d_out;

  char* ws=(char*)d_ws;
  float* reg_part =(float*)(ws+0);
  float* ent_part =(float*)(ws+16384);
  float* loss_part=(float*)(ws+32768);
  float* con_part =(float*)(ws+49152);
  float* pewt     =(float*)(ws+65536);           // 512*64 f32 -> ends 196608
  short* wgb      =(short*)(ws+196608);          // 32768 B
  short* wob      =(short*)(ws+229376);          // 32768 B
  short* asb      =(short*)(ws+262144);          // 8192 B
  short* wab      =(short*)(ws+270336);          // 2048 B
  short* wpb      =(short*)(ws+272384);          // 16384 B -> ends 288768

  k_pe<<<512,64,0,stream>>>(Wpe,pewt);
  k_prep<<<64,256,0,stream>>>(Wgat,Wo,a_src,a_dst,Wassign,Wpred,wgb,wob,asb,wab,wpb);
  kmain<<<4096,256,0,stream>>>(emb,pewt,history,timestp,pos_id,neg_id,stp,adj,
                               wgb,wob,asb,wab,wpb,reg_part,ent_part,loss_part,con_part);
  k3<<<1,256,0,stream>>>(Wpred,Wpe,reg_part,ent_part,loss_part,con_part,out);
}

// Round 10
// 437.008 us; speedup vs baseline: 4.8650x; 1.1134x over previous
//
#include <hip/hip_runtime.h>
#include <hip/hip_bf16.h>
#include <math.h>

typedef __hip_bfloat16 bf16;
typedef __attribute__((ext_vector_type(8))) short sv8;   // 8 bf16 = 4 VGPR (MFMA A/B frag)
typedef __attribute__((ext_vector_type(4))) short sv4;   // 4 bf16 = 2 VGPR
typedef __attribute__((ext_vector_type(4))) float fv4;   // MFMA C/D frag

__device__ __forceinline__ float b2f(bf16 v){ return __bfloat162float(v); }
__device__ __forceinline__ bf16  f2b(float v){ return __float2bfloat16(v); }
__device__ __forceinline__ short f2bs(float v){ bf16 h=__float2bfloat16(v); short s; __builtin_memcpy(&s,&h,2); return s; }
__device__ __forceinline__ float bs2f(short s){ bf16 h; __builtin_memcpy(&h,&s,2); return __bfloat162float(h); }
__device__ __forceinline__ fv4 MFMA(sv8 a, sv8 b, fv4 c){
  return __builtin_amdgcn_mfma_f32_16x16x32_bf16(a,b,c,0,0,0);
}
__device__ __forceinline__ int pk2(float a, float b){
  unsigned sa=(unsigned short)f2bs(a);
  unsigned sb=((unsigned)(unsigned short)f2bs(b))<<16;
  return (int)(sa|sb);
}
__device__ __forceinline__ int pk2s(short a, short b){
  return (int)(((unsigned short)a) | (((unsigned)(unsigned short)b)<<16));
}
union U8 { int i[4]; sv8 v; };

// ---------------------------------------------------------------------------
// k_pre: blocks 0..127 -> pew table (wave w owns t=blk*4+w);
//        blocks 128..191 -> weight pre-pack into MFMA B-frag layouts.
// ---------------------------------------------------------------------------
__global__ __launch_bounds__(256) void k_pre(
    const float* __restrict__ Wpe, const float* __restrict__ Wg, const float* __restrict__ Wo,
    const float* __restrict__ as_, const float* __restrict__ ad_,
    const float* __restrict__ Wassign, const float* __restrict__ Wpred,
    float* __restrict__ pewt, short* __restrict__ wgb, short* __restrict__ wob,
    short* __restrict__ asb, short* __restrict__ wab, short* __restrict__ wpb)
{
  const int blk=blockIdx.x, tid=threadIdx.x;
  if(blk<128){
    __shared__ float pr[4][64];
    int w=tid>>6, d=tid&63;
    int t=blk*4+w;
    const float c0 = -logf(10000.f)/32.f;
    float ang=(float)t*expf((float)(d>>1)*c0);
    pr[w][d]=(d&1)? cosf(ang) : sinf(ang);
    __syncthreads();
    float a=0.f;
    #pragma unroll 8
    for(int j=0;j<64;j++) a += pr[w][j]*Wpe[j*64+d];
    pewt[t*64+d]=a;
  } else {
    int i=(blk-128)*256+tid;            // 0..16383
    {
      int j=i&7, lane=(i>>3)&63, ks=(i>>9)&1, nt=(i>>10)&3, h=(i>>12)&3;
      int c=lane&15, q=lane>>4;
      int k=ks*32+q*8+j;
      wgb[i] = f2bs(Wg[h*4096 + k*64 + nt*16 + c]);
      wob[i] = f2bs(Wo[(size_t)(h*64 + k)*64 + nt*16 + c]);
    }
    if(i<4096){
      int j=i&7, lane=(i>>3)&63, ks=(i>>9)&1, h=(i>>10)&3;
      int c=lane&15, q=lane>>4; int k=ks*32+q*8+j;
      float v = (c==0)? as_[h*64+k] : (c==1? ad_[h*64+k] : 0.f);
      asb[i]=f2bs(v);
    }
    if(i<1024){   // W_assign B-frag: 64x10 (cols padded to 16)
      int j=i&7, lane=(i>>3)&63, ks=(i>>9)&1;
      int c=lane&15, q=lane>>4; int k=ks*32+q*8+j;
      wab[i] = (c<10)? f2bs(Wassign[k*10+c]) : (short)0;
    }
    if(i<8192){   // W_pred B-frag: 128x64
      int j=i&7, lane=(i>>3)&63, ks=(i>>9)&3, nt=(i>>11)&3;
      int c=lane&15, q=lane>>4; int k=ks*32+q*8+j;
      wpb[i] = f2bs(Wpred[k*64 + nt*16 + c]);
    }
  }
}

// ---------------------------------------------------------------------------
// kmain: whole per-batch chain. wave = head. Arena 36864 B -> 4 blocks/CU.
// P4 reordered (softmax before matmul1) + matmul1/matmul2 fused per nt to
// keep Wh tiles at 8 live regs (R9's 32-reg wh_pk spilled to scratch).
// ---------------------------------------------------------------------------
__global__ __launch_bounds__(256,4) void kmain(
    const float* __restrict__ emb, const float* __restrict__ pewt,
    const int* __restrict__ history, const int* __restrict__ timestp,
    const int* __restrict__ pos_id, const int* __restrict__ neg_id, const int* __restrict__ stp,
    const float* __restrict__ adj,
    const short* __restrict__ wgb, const short* __restrict__ wob, const short* __restrict__ asb,
    const short* __restrict__ wab, const short* __restrict__ wpb,
    float* __restrict__ reg_part, float* __restrict__ ent_part,
    float* __restrict__ loss_part, float* __restrict__ con_part)
{
  const int b=blockIdx.x, tid=threadIdx.x;
  const int h=tid>>6, lane=tid&63;
  const int c=lane&15, q=lane>>4;

  __shared__ __align__(16) char arena[36864];
  char*  PP    = arena + h*7200;
  short* xs_s  = (short*)(arena+14400);          // overlay on PP h2
  float* es_f  = (float*)(arena+28800 + h*768);
  float* ed_f  = es_f + 64;
  float* inv_f = es_f + 128;
  float* cndF  = (float*)(arena+31872);
  float* xplF  = (float*)(arena+33152);
  float* uFvec = (float*)(arena+35712);
  float* uacc  = (float*)(arena+35968);
  int*   hist  = (int*)(arena+36224);
  int*   tvals = (int*)(arena+36424);
  int*   ids   = (int*)(arena+36624);
  int*   stv   = (int*)(arena+36644);
  float* ph    = (float*)(arena+36648);          // 4 floats
  float* scF   = (float*)(arena+36664);
  float* sIv   = scF+5;
  float* sFv   = scF+10;
  float* cnv   = scF+15;
  float* un    = scF+20;
  float* sbF   = (float*)arena;                  // 500 f32 overlay on PP h0

  // ---- P0: int loads + adj ballot masks ----
  if (tid < 50) hist[tid] = history[b*50+tid];
  if (tid >= 64 && tid < 114) tvals[tid-64] = timestp[b*50+(tid-64)];
  if (tid == 128) stv[0] = stp[b];
  if (tid == 129) ids[0] = pos_id[b];
  if (tid >= 130 && tid < 134) ids[tid-129] = neg_id[b*4+(tid-130)];

  unsigned long long mymask=0ULL;
  {
    const float* adjb = adj + (size_t)b*2500;
    for(int n=0;n<50;n++){
      float av = (lane<50)? adjb[n*50+lane] : 0.f;
      unsigned long long mk = __ballot(av>0.f);
      if(lane==n) mymask = mk;
    }
  }
  __syncthreads();                               // A0: ints ready

  // ---- P1: gather -> xs bf16 (stride 72), cnd f32; reg partial ----
  float regp=0.f;
  for (int i=tid;i<3200;i+=256){
    int n=i>>6, d=i&63;
    float ev=emb[(size_t)hist[n]*64 + d];
    regp += ev*ev;
    float v = (hist[n]>0) ? (ev + pewt[tvals[n]*64+d]) : 0.f;
    xs_s[n*72+d]=f2bs(v);
  }
  for (int i=tid;i<320;i+=256){
    int cc=i>>6, d=i&63;
    float ev=emb[(size_t)ids[cc]*64+d];
    regp += ev*ev;
    cndF[i]=ev + pewt[stv[0]*64+d];
  }
  #pragma unroll
  for(int m=1;m<64;m<<=1) regp += __shfl_xor(regp,m,64);
  if(lane==0) ph[h]=regp;
  __syncthreads();                               // A: xs/cnd ready

  // ---- P2: A-frags of X + logits MFMA (wave h -> row tile h) ----
  sv8 af[4][2];
  #pragma unroll
  for(int mt=0;mt<4;mt++){
    int r = mt*16 + c; if(r>=50) r=0;
    #pragma unroll
    for(int ks=0;ks<2;ks++)
      af[mt][ks] = *(const sv8*)(xs_s + r*72 + ks*32 + q*8);
  }
  {
    sv8 wa0 = *(const sv8*)(wab + (0*64+lane)*8);
    sv8 wa1 = *(const sv8*)(wab + (1*64+lane)*8);
    fv4 acc={0.f,0.f,0.f,0.f};
    acc = MFMA(af[h][0], wa0, acc);
    acc = MFMA(af[h][1], wa1, acc);
    #pragma unroll
    for(int reg=0;reg<4;reg++){
      int n=16*h+4*q+reg;
      if(n<50 && c<10) sbF[n*10+c]=acc[reg];
    }
  }
  __syncthreads();                               // B: sbF ready
  if(tid==0) reg_part[b]=ph[0]+ph[1]+ph[2]+ph[3];

  // ---- P3a: softmax s (k=10) + entropy ----
  float entp=0.f;
  if (tid<50){
    float mx=-1e30f;
    for(int k=0;k<10;k++) mx=fmaxf(mx, sbF[tid*10+k]);
    float e[10], sm=0.f;
    for(int k=0;k<10;k++){ e[k]=expf(sbF[tid*10+k]-mx); sm+=e[k]; }
    float inv=1.f/sm;
    for(int k=0;k<10;k++){ float sv=e[k]*inv; sbF[tid*10+k]=sv; entp += sv*logf(sv); }
  }
  if(h==0){
    #pragma unroll
    for(int m=1;m<64;m<<=1) entp += __shfl_xor(entp,m,64);
    if(lane==0) ent_part[b]=entp;
  }
  __syncthreads();                               // C: s normalized

  // ---- P3b: x_parent MFMA (wave h -> col tile h) ----
  {
    sv8 sa[2], sxb[2];
    #pragma unroll
    for(int ks=0;ks<2;ks++){
      U8 ua, ub_;
      #pragma unroll
      for(int t2=0;t2<4;t2++){
        int n0=32*ks+8*q+2*t2, n1=n0+1;
        short lo=(n0<50 && c<10)? f2bs(sbF[n0*10+c]) : (short)0;
        short hi=(n1<50 && c<10)? f2bs(sbF[n1*10+c]) : (short)0;
        ua.i[t2]=pk2s(lo,hi);
        short lo2=(n0<50)? xs_s[n0*72+16*h+c] : (short)0;
        short hi2=(n1<50)? xs_s[n1*72+16*h+c] : (short)0;
        ub_.i[t2]=pk2s(lo2,hi2);
      }
      sa[ks]=ua.v; sxb[ks]=ub_.v;
    }
    fv4 acc={0.f,0.f,0.f,0.f};
    acc = MFMA(sa[0], sxb[0], acc);
    acc = MFMA(sa[1], sxb[1], acc);
    #pragma unroll
    for(int reg=0;reg<4;reg++){
      int k=4*q+reg;
      if(k<10) xplF[k*64+16*h+c]=acc[reg];
    }
  }
  __syncthreads();                               // D: xpl ready; sbF/xs_s dead
  if(tid<64){
    float a=0.f;
    for(int k=0;k<10;k++) a += xplF[(k<<6)+tid];
    uFvec[tid]=a*0.1f;
  }

  // ---- P4: GAT (reordered: es/ed -> softmax -> fused matmul1+2 -> matmul3) --
  // es/ed tile (B cols: 0=a_src, 1=a_dst)
  {
    sv8 a5b0 = *(const sv8*)(asb + ((h*2+0)*64 + lane)*8);
    sv8 a5b1 = *(const sv8*)(asb + ((h*2+1)*64 + lane)*8);
    #pragma unroll
    for(int mt=0;mt<4;mt++){
      fv4 acc={0.f,0.f,0.f,0.f};
      acc = MFMA(af[mt][0], a5b0, acc);
      acc = MFMA(af[mt][1], a5b1, acc);
      if(c==0){
        #pragma unroll
        for(int reg=0;reg<4;reg++) es_f[mt*16+4*q+reg]=acc[reg];
      } else if(c==1){
        #pragma unroll
        for(int reg=0;reg<4;reg++) ed_f[mt*16+4*q+reg]=acc[reg];
      }
    }
  }
  // single-pass per-lane softmax (row = lane<50): raw exp into PP, invsum
  {
    float es_n = es_f[lane];
    float sum=0.f;
    #pragma unroll
    for(int mb=0;mb<48;mb+=4){
      sv4 wv;
      #pragma unroll
      for(int jj=0;jj<4;jj++){
        int m=mb+jj;
        float z = es_n + ed_f[m];
        float lr = (z>0.f)? z : 0.2f*z;
        float p = ((mymask>>m)&1ULL)? expf(lr) : 0.f;
        wv[jj]=f2bs(p); sum+=p;
      }
      if(lane<50) *(sv4*)(PP + lane*144 + mb*2) = wv;
    }
    {
      sv4 wv={0,0,0,0};
      #pragma unroll
      for(int jj=0;jj<2;jj++){
        int m=48+jj;
        float z = es_n + ed_f[m];
        float lr = (z>0.f)? z : 0.2f*z;
        float p = ((mymask>>m)&1ULL)? expf(lr) : 0.f;
        wv[jj]=f2bs(p); sum+=p;
      }
      if(lane<50){
        *(sv4*)(PP + lane*144 + 48*2) = wv;        // m 48,49 + zero 50,51
        sv4 zz={0,0,0,0};
        *(sv4*)(PP + lane*144 + 52*2) = zz;
        *(sv4*)(PP + lane*144 + 56*2) = zz;
        *(sv4*)(PP + lane*144 + 60*2) = zz;
      }
    }
    inv_f[lane] = (lane<50)? 1.f/sum : 0.f;
  }
  // fused matmul1+matmul2: per col-tile nt, Wh tiles live only 8 regs
  {
    sv8 ap[4][2];
    #pragma unroll
    for(int mt=0;mt<4;mt++){
      int r = mt*16+c; if(r>=50) r=0;
      #pragma unroll
      for(int ks=0;ks<2;ks++)
        ap[mt][ks] = *(const sv8*)(PP + r*144 + (ks*32+q*8)*2);
    }
    float invr[16];
    #pragma unroll
    for(int mt=0;mt<4;mt++)
      #pragma unroll
      for(int reg=0;reg<4;reg++) invr[mt*4+reg]=inv_f[mt*16+4*q+reg];

    const int L = c + ((q&1)<<5);
    const bool hi = (q>>1)!=0;
    #pragma unroll
    for(int nt=0;nt<4;nt++){
      int wt[4][2];
      {
        sv8 b0 = *(const sv8*)(wgb + (((h*4+nt)*2+0)*64 + lane)*8);
        sv8 b1 = *(const sv8*)(wgb + (((h*4+nt)*2+1)*64 + lane)*8);
        #pragma unroll
        for(int mt=0;mt<4;mt++){
          fv4 acc={0.f,0.f,0.f,0.f};
          acc = MFMA(af[mt][0], b0, acc);
          acc = MFMA(af[mt][1], b1, acc);
          wt[mt][0]=pk2(acc[0],acc[1]);
          wt[mt][1]=pk2(acc[2],acc[3]);
        }
      }
      sv8 bfr[2];
      #pragma unroll
      for(int ks=0;ks<2;ks++){
        int a0=__shfl(wt[2*ks+0][0],L,64), b0=__shfl(wt[2*ks+1][0],L,64);
        int a1=__shfl(wt[2*ks+0][1],L,64), b1=__shfl(wt[2*ks+1][1],L,64);
        int a2=__shfl(wt[2*ks+0][0],L+16,64), b2=__shfl(wt[2*ks+1][0],L+16,64);
        int a3=__shfl(wt[2*ks+0][1],L+16,64), b3=__shfl(wt[2*ks+1][1],L+16,64);
        U8 u;
        u.i[0]=hi?b0:a0; u.i[1]=hi?b1:a1; u.i[2]=hi?b2:a2; u.i[3]=hi?b3:a3;
        bfr[ks]=u.v;
      }
      #pragma unroll
      for(int mt=0;mt<4;mt++){
        fv4 acc={0.f,0.f,0.f,0.f};
        acc = MFMA(ap[mt][0], bfr[0], acc);
        acc = MFMA(ap[mt][1], bfr[1], acc);
        #pragma unroll
        for(int reg=0;reg<4;reg++){
          int row=mt*16+4*q+reg;
          if(row<50)
            *(short*)(PP + row*144 + (nt*16+c)*2) = f2bs(acc[reg]*invr[mt*4+reg]);
        }
      }
    }
  }
  // matmul3: partial = O @ Wo_h, rows<50 written
  {
    sv8 ao[4][2];
    #pragma unroll
    for(int mt=0;mt<4;mt++){
      int r = mt*16+c; if(r>=50) r=0;
      #pragma unroll
      for(int ks=0;ks<2;ks++)
        ao[mt][ks] = *(const sv8*)(PP + r*144 + (ks*32+q*8)*2);
    }
    #pragma unroll
    for(int nt=0;nt<4;nt++){
      sv8 bfr[2];
      #pragma unroll
      for(int ks=0;ks<2;ks++)
        bfr[ks] = *(const sv8*)(wob + (((h*4+nt)*2+ks)*64 + lane)*8);
      #pragma unroll
      for(int mt=0;mt<4;mt++){
        fv4 acc={0.f,0.f,0.f,0.f};
        acc = MFMA(ao[mt][0], bfr[0], acc);
        acc = MFMA(ao[mt][1], bfr[1], acc);
        #pragma unroll
        for(int reg=0;reg<4;reg++){
          int row=mt*16+4*q+reg;
          if(row<50)
            *(short*)(PP + row*144 + (nt*16+c)*2) = f2bs(acc[reg]);
        }
      }
    }
  }
  __syncthreads();                               // E: partials ready

  // ---- P5a: cross-head sum -> elu (regs) ----
  float ve[13];
  {
    int ii=0;
    for(int i=tid;i<3200;i+=256,ii++){
      int n=i>>6, d=i&63;
      float v=0.f;
      #pragma unroll
      for(int hh=0;hh<4;hh++)
        v += bs2f(*(const short*)(arena + hh*7200 + n*144 + d*2));
      v = (v>0.f)? v : expm1f(v);
      ve[ii]=v;
    }
  }
  __syncthreads();                               // F: PP reads done

  // ---- loss overlays ----
  float* xnl =(float*)arena;                     // 3200 f32
  float* lF  =(float*)(arena+12800);             // 50
  float* lI  =(float*)(arena+13000);             // 250
  short* ubA =(short*)(arena+14400);             // 16 rows x 136 shorts
  short* xnlb=(short*)(arena+18752);             // 50 rows x 72 shorts

  {
    int ii=0;
    for(int i=tid;i<3200;i+=256,ii++){
      int n=i>>6, d=i&63;
      xnl[i]=ve[ii];
      xnlb[n*72+d]=f2bs(ve[ii]);
    }
  }
  __syncthreads();                               // G: xnl/xnlb ready

  if(tid<64){
    float a=0.f;
    #pragma unroll 10
    for(int n=0;n<50;n++) a += xnl[(n<<6)+tid];
    uacc[tid]=a*0.02f;
  }
  // lF: 50 wave-dots
  for(int idx=h; idx<50; idx+=4){
    int k=idx%10, cc=idx/10;
    float s = xplF[(k<<6)+lane]*cndF[(cc<<6)+lane];
    #pragma unroll
    for(int m=32;m>0;m>>=1) s += __shfl_xor(s,m,64);
    if(lane==0) lF[idx]=s;
  }
  // lI: MFMA  (wave h -> rows 16h..16h+15 of xnl @ cnd^T)
  {
    sv8 al[2], bl[2];
    int r = 16*h + c; if(r>=50) r=0;
    #pragma unroll
    for(int ks=0;ks<2;ks++){
      al[ks] = *(const sv8*)(xnlb + r*72 + ks*32 + q*8);
      U8 u;
      #pragma unroll
      for(int t2=0;t2<4;t2++){
        int k0=ks*32+q*8+2*t2, k1=k0+1;
        short lo=(c<5)? f2bs(cndF[c*64+k0]) : (short)0;
        short hi=(c<5)? f2bs(cndF[c*64+k1]) : (short)0;
        u.i[t2]=pk2s(lo,hi);
      }
      bl[ks]=u.v;
    }
    fv4 acc={0.f,0.f,0.f,0.f};
    acc = MFMA(al[0], bl[0], acc);
    acc = MFMA(al[1], bl[1], acc);
    #pragma unroll
    for(int reg=0;reg<4;reg++){
      int row=16*h+4*q+reg;
      if(row<50 && c<5) lI[c*50+row]=acc[reg];
    }
  }
  __syncthreads();                               // H: logits ready

  // wave-parallel softmax of lF/lI rows
  for(int cc=h; cc<5; cc+=4){
    float v = (lane<50)? lI[cc*50+lane] : -1e30f;
    float mx=v;
    #pragma unroll
    for(int m=32;m>0;m>>=1) mx=fmaxf(mx,__shfl_xor(mx,m,64));
    float e=(lane<50)? expf(v-mx):0.f;
    float sm=e;
    #pragma unroll
    for(int m=32;m>0;m>>=1) sm+=__shfl_xor(sm,m,64);
    if(lane<50) lI[cc*50+lane]=e/sm;
    float v2=(lane<10)? lF[cc*10+lane] : -1e30f;
    float mx2=v2;
    #pragma unroll
    for(int m=32;m>0;m>>=1) mx2=fmaxf(mx2,__shfl_xor(mx2,m,64));
    float e2=(lane<10)? expf(v2-mx2):0.f;
    float sm2=e2;
    #pragma unroll
    for(int m=32;m>0;m>>=1) sm2+=__shfl_xor(sm2,m,64);
    if(lane<10) lF[cc*10+lane]=e2/sm2;
  }
  __syncthreads();                               // I: attn normalized

  // uF/uI aggregate -> ubA (bf16 A-layout rows cc, K=128)
  for(int i=tid;i<320;i+=256){
    int cc=i>>6, d=i&63;
    float a=0.f;
    for(int k=0;k<10;k++) a += lF[cc*10+k]*xplF[(k<<6)+d];
    float a2=0.f;
    for(int n2=0;n2<50;n2++) a2 += lI[cc*50+n2]*xnl[(n2<<6)+d];
    ubA[cc*136+d]=f2bs(a);
    ubA[cc*136+64+d]=f2bs(a2);
  }
  for(int i=tid;i<1496;i+=256){                   // zero rows 5..15
    int row=5+i/136, col=i-136*(i/136);
    ubA[row*136+col]=0;
  }
  __syncthreads();                               // J: ubA ready

  if(h==0){
    // wave0: ub = [uF|uI] @ Wpred via MFMA, scores straight from D-layout
    sv8 ua[4];
    #pragma unroll
    for(int ks=0;ks<4;ks++)
      ua[ks] = *(const sv8*)(ubA + c*136 + ks*32 + q*8);
    float pr[4]={0.f,0.f,0.f,0.f};
    #pragma unroll
    for(int nt=0;nt<4;nt++){
      fv4 acc={0.f,0.f,0.f,0.f};
      #pragma unroll
      for(int ks=0;ks<4;ks++)
        acc = MFMA(ua[ks], *(const sv8*)(wpb + ((nt*4+ks)*64+lane)*8), acc);
      #pragma unroll
      for(int reg=0;reg<4;reg++){
        int cc=4*q+reg;
        if(cc<5) pr[reg] += acc[reg]*cndF[cc*64+16*nt+c];
      }
    }
    #pragma unroll
    for(int reg=0;reg<4;reg++){
      #pragma unroll
      for(int m=1;m<16;m<<=1) pr[reg]+=__shfl_xor(pr[reg],m,64);
    }
    if(c==0){
      #pragma unroll
      for(int reg=0;reg<4;reg++){
        int cc=4*q+reg;
        if(cc<5) scF[cc]=pr[reg];
      }
    }
  } else {
    // waves 1-3: the 17 small dots
    for(int idx=4+h; idx<22; idx+=3){
      float va, vb;
      if(idx<10){ int cc=idx-5; va=cndF[(cc<<6)+lane]; vb=uacc[lane]; }
      else if(idx<15){ int cc=idx-10; va=cndF[(cc<<6)+lane]; vb=uFvec[lane]; }
      else if(idx<20){ int cc=idx-15; va=cndF[(cc<<6)+lane]; vb=va; }
      else if(idx==20){ va=uacc[lane]; vb=va; }
      else { va=uFvec[lane]; vb=va; }
      float s=va*vb;
      #pragma unroll
      for(int m=32;m>0;m>>=1) s += __shfl_xor(s,m,64);
      if(lane==0){
        if(idx<10) sIv[idx-5]=s;
        else if(idx<15) sFv[idx-10]=s;
        else if(idx<20) cnv[idx-15]=sqrtf(s);
        else un[idx-20]=sqrtf(s);
      }
    }
  }
  __syncthreads();                               // K

  if(tid==0){
    float lp=0.f;
    for(int cc=1;cc<5;cc++){
      float z=scF[cc]-scF[0];
      lp += fmaxf(z,0.f)+log1pf(expf(-fabsf(z)));
    }
    int indF[5], indI[5];
    { bool used[5]={0,0,0,0,0};
      for(int p=0;p<5;p++){ int best=0; float bv=-3e38f;
        for(int cc=0;cc<5;cc++) if(!used[cc]&&sFv[cc]>bv){bv=sFv[cc];best=cc;}
        used[best]=true; indF[p]=best; } }
    { bool used[5]={0,0,0,0,0};
      for(int p=0;p<5;p++){ int best=0; float bv=-3e38f;
        for(int cc=0;cc<5;cc++) if(!used[cc]&&sIv[cc]>bv){bv=sIv[cc];best=cc;}
        used[best]=true; indI[p]=best; } }
    float t1,t2;
    {
      float inv=2.f/un[0];
      float ps=expf(sIv[indF[0]]/cnv[indF[0]]*inv)+expf(sIv[indF[1]]/cnv[indF[1]]*inv);
      float ns=expf(sIv[indF[2]]/cnv[indF[2]]*inv)+expf(sIv[indF[3]]/cnv[indF[3]]*inv);
      t1=log1pf(ns/ps);
    }
    {
      float inv=2.f/un[1];
      float ps=expf(sFv[indI[0]]/cnv[indI[0]]*inv)+expf(sFv[indI[1]]/cnv[indI[1]]*inv);
      float ns=expf(sFv[indI[2]]/cnv[indI[2]]*inv)+expf(sFv[indI[3]]/cnv[indI[3]]*inv);
      t2=log1pf(ns/ps);
    }
    loss_part[b]=lp;
    con_part[b]=t1+t2;
  }
}

// ---------------------------------------------------------------------------
// k3: single-block final reduction -> 4 f32 outputs
// ---------------------------------------------------------------------------
__global__ __launch_bounds__(256) void k3(
    const float* __restrict__ Wpred, const float* __restrict__ Wpe,
    const float* __restrict__ reg_part, const float* __restrict__ ent_part,
    const float* __restrict__ loss_part, const float* __restrict__ con_part,
    float* __restrict__ out)
{
  const int tid=threadIdx.x, h=tid>>6, lane=tid&63;
  __shared__ float r5[5][4];
  float s[5]={0.f,0.f,0.f,0.f,0.f};
  for(int i=tid;i<4096;i+=256){
    s[0]+=reg_part[i]; s[1]+=ent_part[i]; s[2]+=loss_part[i]; s[3]+=con_part[i];
  }
  for(int i=tid;i<8192;i+=256){ float w=Wpred[i]; s[4]+=w*w; }
  for(int i=tid;i<4096;i+=256){ float w=Wpe[i]; s[4]+=w*w; }
  #pragma unroll
  for(int t2=0;t2<5;t2++){
    float v=s[t2];
    #pragma unroll
    for(int m=1;m<64;m<<=1) v+=__shfl_xor(v,m,64);
    if(lane==0) r5[t2][h]=v;
  }
  __syncthreads();
  if(tid==0){
    float tot[5];
    for(int t2=0;t2<5;t2++) tot[t2]=r5[t2][0]+r5[t2][1]+r5[t2][2]+r5[t2][3];
    out[0]=tot[2]/(4096.f*4.f);          // loss
    out[1]=tot[0]/4096.f + tot[4];       // loss_reg
    out[2]=-tot[1]/(50.f*4096.f);        // loss_entropy
    out[3]=tot[3]/4096.f;                // loss_con
  }
}

extern "C" void kernel_launch(void* const* d_in, const int* in_sizes, int n_in,
                              void* d_out, int out_size, void* d_ws, size_t ws_size,
                              hipStream_t stream)
{
  const float* emb     =(const float*)d_in[0];
  const float* Wpe     =(const float*)d_in[1];
  const float* Wpred   =(const float*)d_in[2];
  const float* Wgat    =(const float*)d_in[3];
  const float* a_src   =(const float*)d_in[4];
  const float* a_dst   =(const float*)d_in[5];
  const float* Wo      =(const float*)d_in[6];
  const float* Wassign =(const float*)d_in[7];
  const float* adj     =(const float*)d_in[8];
  const int* history  =(const int*)d_in[9];
  const int* timestp  =(const int*)d_in[10];
  const int* pos_id   =(const int*)d_in[11];
  const int* neg_id   =(const int*)d_in[12];
  const int* stp      =(const int*)d_in[13];
  float* out=(float*)d_out;

  char* ws=(char*)d_ws;
  float* reg_part =(float*)(ws+0);
  float* ent_part =(float*)(ws+16384);
  float* loss_part=(float*)(ws+32768);
  float* con_part =(float*)(ws+49152);
  float* pewt     =(float*)(ws+65536);           // 512*64 f32 -> ends 196608
  short* wgb      =(short*)(ws+196608);          // 32768 B
  short* wob      =(short*)(ws+229376);          // 32768 B
  short* asb      =(short*)(ws+262144);          // 8192 B
  short* wab      =(short*)(ws+270336);          // 2048 B
  short* wpb      =(short*)(ws+272384);          // 16384 B -> ends 288768

  k_pre<<<192,256,0,stream>>>(Wpe,Wgat,Wo,a_src,a_dst,Wassign,Wpred,
                              pewt,wgb,wob,asb,wab,wpb);
  kmain<<<4096,256,0,stream>>>(emb,pewt,history,timestp,pos_id,neg_id,stp,adj,
                               wgb,wob,asb,wab,wpb,reg_part,ent_part,loss_part,con_part);
  k3<<<1,256,0,stream>>>(Wpred,Wpe,reg_part,ent_part,loss_part,con_part,out);
}